// Round 2
// baseline (5128.375 us; speedup 1.0000x reference)
//
#include <hip/hip_runtime.h>

#define HDIM 32

static constexpr int NU   = 500000;
static constexpr int NPOI = 200000;
static constexpr int NC   = 100;
static constexpr int E_UP = 500000;
static constexpr int E_PP = 1000000;

static constexpr int NLISTS = 8;
static constexpr int TOT_E  = 6 * E_UP + NPOI + E_PP;   // 4,200,000
static constexpr int TOT_R  = 3 * NU + 5 * NPOI;        // 2,500,000

struct EArgs {
    const int* ei[NLISTS];
    int E[NLISTS];
    int eoff[NLISTS];
    int roff[NLISTS];
};

// ---------------------------------------------------------------------------
__global__ void zero_kernel(int* __restrict__ p, int n) {
    int i = blockIdx.x * blockDim.x + threadIdx.x;
    int stride = gridDim.x * blockDim.x;
    for (; i < n; i += stride) p[i] = 0;
}

// ---------------------------------------------------------------------------
__global__ void init_nodes(const float* __restrict__ x, int fin,
                           const float* __restrict__ W, const float* __restrict__ b,
                           const float* __restrict__ emb,
                           float* __restrict__ h, int n) {
    int idx = blockIdx.x * blockDim.x + threadIdx.x;
    if (idx >= n * HDIM) return;
    int i = idx >> 5, f = idx & 31;
    float r = b[f];
    for (int k = 0; k < fin; ++k) r += x[i * fin + k] * W[k * HDIM + f];
    r = fmaxf(r, 0.0f);
    if (emb) r += emb[idx];
    h[idx] = r;
}

// ---------------------------------------------------------------------------
// CSR build: histogram of dst counts into R
__global__ void hist_k(EArgs L, int* __restrict__ R, int total) {
    int g = blockIdx.x * blockDim.x + threadIdx.x;
    if (g >= total) return;
    int l = 0;
    while (l < NLISTS - 1 && g >= L.eoff[l] + L.E[l]) ++l;
    int e = g - L.eoff[l];
    int d = L.ei[l][L.E[l] + e];        // dst row of ei ([2,E] layout)
    atomicAdd(&R[L.roff[l] + d], 1);
}

// ---------------------------------------------------------------------------
// 3-pass exclusive scan of R (2.5M ints)
#define SCAN_T 256
#define SCAN_ELEMS 4
#define SCAN_CHUNK (SCAN_T * SCAN_ELEMS)

__global__ void scan1(int* __restrict__ R, int N, int* __restrict__ part) {
    __shared__ int lds[SCAN_T];
    int base = blockIdx.x * SCAN_CHUNK + threadIdx.x * SCAN_ELEMS;
    int v[SCAN_ELEMS]; int s = 0;
#pragma unroll
    for (int k = 0; k < SCAN_ELEMS; ++k) { int i = base + k; v[k] = (i < N) ? R[i] : 0; s += v[k]; }
    lds[threadIdx.x] = s; __syncthreads();
    for (int off = 1; off < SCAN_T; off <<= 1) {
        int t = (threadIdx.x >= off) ? lds[threadIdx.x - off] : 0;
        __syncthreads(); lds[threadIdx.x] += t; __syncthreads();
    }
    int incl = lds[threadIdx.x];
    int total = lds[SCAN_T - 1];
    int run = incl - s;
#pragma unroll
    for (int k = 0; k < SCAN_ELEMS; ++k) { int i = base + k; if (i < N) R[i] = run; run += v[k]; }
    if (threadIdx.x == 0) part[blockIdx.x] = total;
}

__global__ void scan2(int* __restrict__ part, int nb) {
    __shared__ int lds[SCAN_T];
    __shared__ int carry;
    if (threadIdx.x == 0) carry = 0;
    __syncthreads();
    for (int base = 0; base < nb; base += SCAN_T) {
        int i = base + threadIdx.x;
        int v = (i < nb) ? part[i] : 0;
        lds[threadIdx.x] = v; __syncthreads();
        for (int off = 1; off < SCAN_T; off <<= 1) {
            int t = (threadIdx.x >= off) ? lds[threadIdx.x - off] : 0;
            __syncthreads(); lds[threadIdx.x] += t; __syncthreads();
        }
        int incl = lds[threadIdx.x]; int tot = lds[SCAN_T - 1];
        if (i < nb) part[i] = carry + incl - v;
        __syncthreads();
        if (threadIdx.x == 0) carry += tot;
        __syncthreads();
    }
}

__global__ void scan3(int* __restrict__ R, int N, const int* __restrict__ part) {
    int base = blockIdx.x * SCAN_CHUNK + threadIdx.x * SCAN_ELEMS;
    int add = part[blockIdx.x];
#pragma unroll
    for (int k = 0; k < SCAN_ELEMS; ++k) { int i = base + k; if (i < N) R[i] += add; }
}

// ---------------------------------------------------------------------------
// fill: place local edge index into perm at its CSR slot; R[roff+d] becomes end
__global__ void fill_k(EArgs L, int* __restrict__ R, int* __restrict__ perm, int total) {
    int g = blockIdx.x * blockDim.x + threadIdx.x;
    if (g >= total) return;
    int l = 0;
    while (l < NLISTS - 1 && g >= L.eoff[l] + L.E[l]) ++l;
    int e = g - L.eoff[l];
    int d = L.ei[l][L.E[l] + e];
    int pos = atomicAdd(&R[L.roff[l] + d], 1);
    perm[pos] = e;
}

// ---------------------------------------------------------------------------
// Fused gather-prop over THREE edge lists sharing src, W, b, dst.
// 32 lanes per dst node; lane f owns feature f.
__global__ void gather3(float* __restrict__ dst, const float* __restrict__ src,
                        const int* __restrict__ R, const int* __restrict__ perm,
                        int roff0, int roff1, int roff2,
                        int eoff0, int eoff1, int eoff2,
                        const int* __restrict__ ei0, const int* __restrict__ ei1,
                        const int* __restrict__ ei2,
                        const float* __restrict__ ea0, const float* __restrict__ ea1,
                        const float* __restrict__ ea2,
                        const float* __restrict__ W, const float* __restrict__ b, int n) {
    __shared__ float Ws[HDIM * HDIM];
    for (int i = threadIdx.x; i < HDIM * HDIM; i += blockDim.x) Ws[i] = W[i];
    __syncthreads();
    int gid = blockIdx.x * blockDim.x + threadIdx.x;
    int d = gid >> 5;
    if (d >= n) return;
    int f = gid & 31;
    float bf = b[f];
    float res = 0.0f;
    const int roffs[3]   = {roff0, roff1, roff2};
    const int eoffs[3]   = {eoff0, eoff1, eoff2};
    const int* eis[3]    = {ei0, ei1, ei2};
    const float* eas[3]  = {ea0, ea1, ea2};
#pragma unroll
    for (int li = 0; li < 3; ++li) {
        int start = (d == 0) ? eoffs[li] : R[roffs[li] + d - 1];
        int end   = R[roffs[li] + d];
        float acc = 0.0f, t = 0.0f;
        for (int j = start; j < end; ++j) {
            int e = perm[j];
            float w = eas[li][e];
            int s = eis[li][e];
            acc += w * src[(size_t)s * HDIM + f];
            t += w;
        }
        float r = t * bf;
#pragma unroll
        for (int k = 0; k < HDIM; ++k) r += __shfl(acc, k, 32) * Ws[k * HDIM + f];
        r /= fmaxf((float)(end - start), 1.0f);
        res += fmaxf(r, 0.0f);
    }
    dst[(size_t)d * HDIM + f] += res;
}

// ---------------------------------------------------------------------------
// Single-list gather-prop (ea may be null -> weight 1)
__global__ void gather1(float* __restrict__ dst, const float* __restrict__ src,
                        const int* __restrict__ R, const int* __restrict__ perm,
                        int roff, int eoff,
                        const int* __restrict__ ei, const float* __restrict__ ea,
                        const float* __restrict__ W, const float* __restrict__ b, int n) {
    __shared__ float Ws[HDIM * HDIM];
    for (int i = threadIdx.x; i < HDIM * HDIM; i += blockDim.x) Ws[i] = W[i];
    __syncthreads();
    int gid = blockIdx.x * blockDim.x + threadIdx.x;
    int d = gid >> 5;
    if (d >= n) return;
    int f = gid & 31;
    float bf = b[f];
    int start = (d == 0) ? eoff : R[roff + d - 1];
    int end   = R[roff + d];
    float acc = 0.0f, t = 0.0f;
    for (int j = start; j < end; ++j) {
        int e = perm[j];
        float w = ea ? ea[e] : 1.0f;
        int s = ei[e];
        acc += w * src[(size_t)s * HDIM + f];
        t += w;
    }
    float r = t * bf;
#pragma unroll
    for (int k = 0; k < HDIM; ++k) r += __shfl(acc, k, 32) * Ws[k * HDIM + f];
    r /= fmaxf((float)(end - start), 1.0f);
    dst[(size_t)d * HDIM + f] += fmaxf(r, 0.0f);
}

// ---------------------------------------------------------------------------
__global__ void copy4(const float4* __restrict__ src, float4* __restrict__ dst, int n4) {
    int i = blockIdx.x * blockDim.x + threadIdx.x;
    int stride = gridDim.x * blockDim.x;
    for (; i < n4; i += stride) dst[i] = src[i];
}

// ---------------------------------------------------------------------------
extern "C" void kernel_launch(void* const* d_in, const int* in_sizes, int n_in,
                              void* d_out, int out_size, void* d_ws, size_t ws_size,
                              hipStream_t stream) {
    const float* x_user = (const float*)d_in[0];
    const float* x_poi  = (const float*)d_in[1];
    const float* x_cate = (const float*)d_in[2];
    const float* ulw    = (const float*)d_in[3];
    const float* ulb    = (const float*)d_in[4];
    const float* plw    = (const float*)d_in[5];
    const float* plb    = (const float*)d_in[6];
    const float* clw    = (const float*)d_in[7];
    const float* clb    = (const float*)d_in[8];
    const float* W1u_w  = (const float*)d_in[9];   const float* W1u_b  = (const float*)d_in[10];
    const float* W1p_w  = (const float*)d_in[11];  const float* W1p_b  = (const float*)d_in[12];
    const float* W1c_w  = (const float*)d_in[13];  const float* W1c_b  = (const float*)d_in[14];
    const float* W1pp_w = (const float*)d_in[15];  const float* W1pp_b = (const float*)d_in[16];
    const float* W2u_w  = (const float*)d_in[17];  const float* W2u_b  = (const float*)d_in[18];
    const float* W2p_w  = (const float*)d_in[19];  const float* W2p_b  = (const float*)d_in[20];
    const float* W2c_w  = (const float*)d_in[21];  const float* W2c_b  = (const float*)d_in[22];
    const float* W2pp_w = (const float*)d_in[23];  const float* W2pp_b = (const float*)d_in[24];
    const float* cate_emb = (const float*)d_in[25];
    const int* ei_pv        = (const int*)d_in[26];
    const int* ei_mc        = (const int*)d_in[27];
    const int* ei_order     = (const int*)d_in[28];
    const int* ei_rev_pv    = (const int*)d_in[29];
    const int* ei_rev_mc    = (const int*)d_in[30];
    const int* ei_rev_order = (const int*)d_in[31];
    const int* ei_belongs   = (const int*)d_in[32];
    const int* ei_pp        = (const int*)d_in[33];
    const float* ea_pv        = (const float*)d_in[34];
    const float* ea_mc        = (const float*)d_in[35];
    const float* ea_order     = (const float*)d_in[36];
    const float* ea_rev_pv    = (const float*)d_in[37];
    const float* ea_rev_mc    = (const float*)d_in[38];
    const float* ea_rev_order = (const float*)d_in[39];
    const float* ea_pp        = (const float*)d_in[40];

    float* user_h = (float*)d_out;
    float* poi_h  = user_h + (size_t)NU * HDIM;
    float* cate_h = poi_h + (size_t)NPOI * HDIM;

    // workspace layout
    int*   R     = (int*)d_ws;                       // [TOT_R]        10.0 MB
    int*   perm  = R + TOT_R;                        // [TOT_E]        16.8 MB
    int*   part  = perm + TOT_E;                     // [4096]
    float* snap  = (float*)(part + 4096);            // [NPOI*32]      25.6 MB

    // list order: rev_pv, rev_mc, rev_order, pv, mc, order, belongs, pp
    EArgs L;
    const int* eis[NLISTS] = {ei_rev_pv, ei_rev_mc, ei_rev_order,
                              ei_pv, ei_mc, ei_order, ei_belongs, ei_pp};
    const int  Es[NLISTS]  = {E_UP, E_UP, E_UP, E_UP, E_UP, E_UP, NPOI, E_PP};
    const int  ns[NLISTS]  = {NU, NU, NU, NPOI, NPOI, NPOI, NPOI, NPOI};
    int eo = 0, ro = 0;
    int eoff[NLISTS], roff[NLISTS];
    for (int l = 0; l < NLISTS; ++l) {
        L.ei[l] = eis[l]; L.E[l] = Es[l];
        L.eoff[l] = eo; L.roff[l] = ro;
        eoff[l] = eo; roff[l] = ro;
        eo += Es[l]; ro += ns[l];
    }

    // --- CSR build (once; reused by both layers) ---
    hipLaunchKernelGGL(zero_kernel, dim3(2048), dim3(256), 0, stream, R, TOT_R);
    hipLaunchKernelGGL(hist_k, dim3((TOT_E + 255) / 256), dim3(256), 0, stream, L, R, TOT_E);
    int nb = (TOT_R + SCAN_CHUNK - 1) / SCAN_CHUNK;
    hipLaunchKernelGGL(scan1, dim3(nb), dim3(SCAN_T), 0, stream, R, TOT_R, part);
    hipLaunchKernelGGL(scan2, dim3(1), dim3(SCAN_T), 0, stream, part, nb);
    hipLaunchKernelGGL(scan3, dim3(nb), dim3(SCAN_T), 0, stream, R, TOT_R, part);
    hipLaunchKernelGGL(fill_k, dim3((TOT_E + 255) / 256), dim3(256), 0, stream, L, R, perm, TOT_E);

    // --- init node states ---
    hipLaunchKernelGGL(init_nodes, dim3((NU * HDIM + 255) / 256), dim3(256), 0, stream,
                       x_user, 2, ulw, ulb, (const float*)nullptr, user_h, NU);
    hipLaunchKernelGGL(init_nodes, dim3((NPOI * HDIM + 255) / 256), dim3(256), 0, stream,
                       x_poi, 3, plw, plb, (const float*)nullptr, poi_h, NPOI);
    hipLaunchKernelGGL(init_nodes, dim3((NC * HDIM + 255) / 256), dim3(256), 0, stream,
                       x_cate, 1, clw, clb, cate_emb, cate_h, NC);

    dim3 blk(256);
    dim3 gu((NU * 32 + 255) / 256);
    dim3 gp((NPOI * 32 + 255) / 256);
    int n4 = NPOI * HDIM / 4;

    for (int layer = 0; layer < 2; ++layer) {
        const float* Wp  = layer ? W2p_w  : W1p_w;   const float* bp  = layer ? W2p_b  : W1p_b;
        const float* Wu  = layer ? W2u_w  : W1u_w;   const float* bu  = layer ? W2u_b  : W1u_b;
        const float* Wc  = layer ? W2c_w  : W1c_w;   const float* bc  = layer ? W2c_b  : W1c_b;
        const float* Wpp = layer ? W2pp_w : W1pp_w;  const float* bpp = layer ? W2pp_b : W1pp_b;

        // 3 rev props fused: user_h += sum relu(...) from poi_h
        hipLaunchKernelGGL(gather3, gu, blk, 0, stream,
                           user_h, poi_h, R, perm,
                           roff[0], roff[1], roff[2], eoff[0], eoff[1], eoff[2],
                           ei_rev_pv, ei_rev_mc, ei_rev_order,
                           ea_rev_pv, ea_rev_mc, ea_rev_order,
                           Wp, bp, NU);
        // 3 fwd props fused: poi_h += sum relu(...) from user_h
        hipLaunchKernelGGL(gather3, gp, blk, 0, stream,
                           poi_h, user_h, R, perm,
                           roff[3], roff[4], roff[5], eoff[3], eoff[4], eoff[5],
                           ei_pv, ei_mc, ei_order,
                           ea_pv, ea_mc, ea_order,
                           Wu, bu, NPOI);
        // belongs: poi_h += relu(...) from cate_h (ea = None)
        hipLaunchKernelGGL(gather1, gp, blk, 0, stream,
                           poi_h, cate_h, R, perm, roff[6], eoff[6],
                           ei_belongs, (const float*)nullptr, Wc, bc, NPOI);
        // pp self-prop: snapshot poi_h, then gather from snapshot
        hipLaunchKernelGGL(copy4, dim3(4096), blk, 0, stream,
                           (const float4*)poi_h, (float4*)snap, n4);
        hipLaunchKernelGGL(gather1, gp, blk, 0, stream,
                           poi_h, snap, R, perm, roff[7], eoff[7],
                           ei_pp, ea_pp, Wpp, bpp, NPOI);
    }
}

// Round 3
// 1972.999 us; speedup vs baseline: 2.5993x; 2.5993x over previous
//
#include <hip/hip_runtime.h>

#define HDIM 32

static constexpr int NU   = 500000;
static constexpr int NPOI = 200000;
static constexpr int NC   = 100;
static constexpr int E_UP = 500000;
static constexpr int E_PP = 1000000;

static constexpr int NLISTS = 8;
static constexpr int TOT_E  = 6 * E_UP + NPOI + E_PP;   // 4,200,000
static constexpr int TOT_R  = 3 * NU + 5 * NPOI;        // 2,500,000

// ---------------------------------------------------------------------------
__global__ void zero_kernel(int* __restrict__ p, int n) {
    int i = blockIdx.x * blockDim.x + threadIdx.x;
    int stride = gridDim.x * blockDim.x;
    for (; i < n; i += stride) p[i] = 0;
}

// ---------------------------------------------------------------------------
__global__ void init_nodes(const float* __restrict__ x, int fin,
                           const float* __restrict__ W, const float* __restrict__ b,
                           const float* __restrict__ emb,
                           float* __restrict__ h, int n) {
    int idx = blockIdx.x * blockDim.x + threadIdx.x;
    if (idx >= n * HDIM) return;
    int i = idx >> 5, f = idx & 31;
    float r = b[f];
    for (int k = 0; k < fin; ++k) r += x[i * fin + k] * W[k * HDIM + f];
    r = fmaxf(r, 0.0f);
    if (emb) r += emb[idx];
    h[idx] = r;
}

// ---------------------------------------------------------------------------
// per-list histogram: Rl[d] += 1   (Rl = R + roff_l)
__global__ void hist1(const int* __restrict__ ei_dst, int E, int* __restrict__ Rl) {
    int e = blockIdx.x * blockDim.x + threadIdx.x;
    if (e < E) atomicAdd(&Rl[ei_dst[e]], 1);
}

// ---------------------------------------------------------------------------
// 3-pass exclusive scan of R (2.5M ints) -- verified in round 2
#define SCAN_T 256
#define SCAN_ELEMS 4
#define SCAN_CHUNK (SCAN_T * SCAN_ELEMS)

__global__ void scan1(int* __restrict__ R, int N, int* __restrict__ part) {
    __shared__ int lds[SCAN_T];
    int base = blockIdx.x * SCAN_CHUNK + threadIdx.x * SCAN_ELEMS;
    int v[SCAN_ELEMS]; int s = 0;
#pragma unroll
    for (int k = 0; k < SCAN_ELEMS; ++k) { int i = base + k; v[k] = (i < N) ? R[i] : 0; s += v[k]; }
    lds[threadIdx.x] = s; __syncthreads();
    for (int off = 1; off < SCAN_T; off <<= 1) {
        int t = (threadIdx.x >= off) ? lds[threadIdx.x - off] : 0;
        __syncthreads(); lds[threadIdx.x] += t; __syncthreads();
    }
    int incl = lds[threadIdx.x];
    int total = lds[SCAN_T - 1];
    int run = incl - s;
#pragma unroll
    for (int k = 0; k < SCAN_ELEMS; ++k) { int i = base + k; if (i < N) R[i] = run; run += v[k]; }
    if (threadIdx.x == 0) part[blockIdx.x] = total;
}

__global__ void scan2(int* __restrict__ part, int nb) {
    __shared__ int lds[SCAN_T];
    __shared__ int carry;
    if (threadIdx.x == 0) carry = 0;
    __syncthreads();
    for (int base = 0; base < nb; base += SCAN_T) {
        int i = base + threadIdx.x;
        int v = (i < nb) ? part[i] : 0;
        lds[threadIdx.x] = v; __syncthreads();
        for (int off = 1; off < SCAN_T; off <<= 1) {
            int t = (threadIdx.x >= off) ? lds[threadIdx.x - off] : 0;
            __syncthreads(); lds[threadIdx.x] += t; __syncthreads();
        }
        int incl = lds[threadIdx.x]; int tot = lds[SCAN_T - 1];
        if (i < nb) part[i] = carry + incl - v;
        __syncthreads();
        if (threadIdx.x == 0) carry += tot;
        __syncthreads();
    }
}

__global__ void scan3(int* __restrict__ R, int N, const int* __restrict__ part) {
    int base = blockIdx.x * SCAN_CHUNK + threadIdx.x * SCAN_ELEMS;
    int add = part[blockIdx.x];
#pragma unroll
    for (int k = 0; k < SCAN_ELEMS; ++k) { int i = base + k; if (i < N) R[i] += add; }
}

// ---------------------------------------------------------------------------
// per-list fill: dst-sorted edge streams es (src idx) and ew (edge weight).
// Positions from R are GLOBAL (scan over concatenated histograms); after this
// kernel R[roff+d] = end(d).
__global__ void fill1(const int* __restrict__ ei, const float* __restrict__ ea,
                      int E, int* __restrict__ Rl,
                      int* __restrict__ es, float* __restrict__ ew) {
    int e = blockIdx.x * blockDim.x + threadIdx.x;
    if (e >= E) return;
    int d = ei[E + e];
    int pos = atomicAdd(&Rl[d], 1);
    es[pos] = ei[e];
    ew[pos] = ea ? ea[e] : 1.0f;
}

// ---------------------------------------------------------------------------
// Dense per-node transform: out[i,:] = src[i,:] @ W + b
// lane f computes feature f; src row shared via __shfl within the 32-group.
__global__ __launch_bounds__(256) void transform_k(const float* __restrict__ src,
                                                   const float* __restrict__ W,
                                                   const float* __restrict__ b,
                                                   float* __restrict__ out, int n) {
    int idx = blockIdx.x * blockDim.x + threadIdx.x;
    if (idx >= n * HDIM) return;
    int f = idx & 31;
    float Wc[HDIM];
#pragma unroll
    for (int k = 0; k < HDIM; ++k) Wc[k] = W[k * HDIM + f];
    float x = src[idx];
    float r = b[f];
#pragma unroll
    for (int k = 0; k < HDIM; ++k) r += __shfl(x, k, 32) * Wc[k];
    out[idx] = r;
}

// ---------------------------------------------------------------------------
__global__ void copy4(const float4* __restrict__ src, float4* __restrict__ dst, int n4) {
    int i = blockIdx.x * blockDim.x + threadIdx.x;
    int stride = gridDim.x * blockDim.x;
    for (; i < n4; i += stride) dst[i] = src[i];
}

// ---------------------------------------------------------------------------
// Row-chunked fused propagation over NL lists sharing (src table, W, b, dst).
// Each 32-lane group OWNS 32 consecutive dst rows: walks each row's contiguous
// CSR edge range per list, accumulates in registers, finalizes per (row,list),
// single dst read-modify-write per active row. No atomics, no scratch arrays.
// PRET: src is pre-transformed (b folded in) -> no matvec needed here.
template<int NL, bool PRET>
__global__ __launch_bounds__(256) void row_prop(
    float* __restrict__ dst, const float* __restrict__ src,
    const int* __restrict__ R, const int* __restrict__ es,
    const float* __restrict__ ew,
    int ro0, int ro1, int ro2, int eo0, int eo1, int eo2,
    const float* __restrict__ W, const float* __restrict__ b, int n) {
    __shared__ float Ws[HDIM * HDIM];
    if (!PRET) {
        for (int i = threadIdx.x; i < HDIM * HDIM; i += blockDim.x) Ws[i] = W[i];
        __syncthreads();
    }
    int gid = blockIdx.x * (blockDim.x >> 5) + (threadIdx.x >> 5);
    int f = threadIdx.x & 31;
    int r0 = gid * 32;
    if (r0 >= n) return;
    int r1 = min(n, r0 + 32);
    float bf = PRET ? 0.0f : b[f];
    // running CSR cursors (start of row r0 per list); R holds absolute ends
    int j0 = (r0 == 0) ? eo0 : R[ro0 + r0 - 1];
    int j1 = (NL > 1) ? ((r0 == 0) ? eo1 : R[ro1 + r0 - 1]) : 0;
    int j2 = (NL > 2) ? ((r0 == 0) ? eo2 : R[ro2 + r0 - 1]) : 0;

    for (int r = r0; r < r1; ++r) {
        float res = 0.0f;
        int ctot = 0;
#pragma unroll
        for (int l = 0; l < NL; ++l) {
            int ro = (l == 0) ? ro0 : (l == 1) ? ro1 : ro2;
            int jcur = (l == 0) ? j0 : (l == 1) ? j1 : j2;
            int jend = R[ro + r];
            int c = jend - jcur;
            float acc = 0.0f, t = 0.0f;
            for (int j = jcur; j < jend; ++j) {
                float w = ew[j];
                acc += w * src[(size_t)es[j] * HDIM + f];
                if (!PRET) t += w;
            }
            if (l == 0) j0 = jend; else if (l == 1) j1 = jend; else j2 = jend;
            ctot += c;
            float rl;
            if (PRET) {
                rl = acc / fmaxf((float)c, 1.0f);
            } else {
                rl = t * bf;
#pragma unroll
                for (int k = 0; k < HDIM; ++k) rl += __shfl(acc, k, 32) * Ws[k * HDIM + f];
                rl /= fmaxf((float)c, 1.0f);
            }
            res += fmaxf(rl, 0.0f);
        }
        if (ctot > 0) dst[(size_t)r * HDIM + f] += res;
    }
}

// ---------------------------------------------------------------------------
extern "C" void kernel_launch(void* const* d_in, const int* in_sizes, int n_in,
                              void* d_out, int out_size, void* d_ws, size_t ws_size,
                              hipStream_t stream) {
    const float* x_user = (const float*)d_in[0];
    const float* x_poi  = (const float*)d_in[1];
    const float* x_cate = (const float*)d_in[2];
    const float* ulw    = (const float*)d_in[3];
    const float* ulb    = (const float*)d_in[4];
    const float* plw    = (const float*)d_in[5];
    const float* plb    = (const float*)d_in[6];
    const float* clw    = (const float*)d_in[7];
    const float* clb    = (const float*)d_in[8];
    const float* W1u_w  = (const float*)d_in[9];   const float* W1u_b  = (const float*)d_in[10];
    const float* W1p_w  = (const float*)d_in[11];  const float* W1p_b  = (const float*)d_in[12];
    const float* W1c_w  = (const float*)d_in[13];  const float* W1c_b  = (const float*)d_in[14];
    const float* W1pp_w = (const float*)d_in[15];  const float* W1pp_b = (const float*)d_in[16];
    const float* W2u_w  = (const float*)d_in[17];  const float* W2u_b  = (const float*)d_in[18];
    const float* W2p_w  = (const float*)d_in[19];  const float* W2p_b  = (const float*)d_in[20];
    const float* W2c_w  = (const float*)d_in[21];  const float* W2c_b  = (const float*)d_in[22];
    const float* W2pp_w = (const float*)d_in[23];  const float* W2pp_b = (const float*)d_in[24];
    const float* cate_emb = (const float*)d_in[25];
    const int* ei_pv        = (const int*)d_in[26];
    const int* ei_mc        = (const int*)d_in[27];
    const int* ei_order     = (const int*)d_in[28];
    const int* ei_rev_pv    = (const int*)d_in[29];
    const int* ei_rev_mc    = (const int*)d_in[30];
    const int* ei_rev_order = (const int*)d_in[31];
    const int* ei_belongs   = (const int*)d_in[32];
    const int* ei_pp        = (const int*)d_in[33];
    const float* ea_pv        = (const float*)d_in[34];
    const float* ea_mc        = (const float*)d_in[35];
    const float* ea_order     = (const float*)d_in[36];
    const float* ea_rev_pv    = (const float*)d_in[37];
    const float* ea_rev_mc    = (const float*)d_in[38];
    const float* ea_rev_order = (const float*)d_in[39];
    const float* ea_pp        = (const float*)d_in[40];

    float* user_h = (float*)d_out;
    float* poi_h  = user_h + (size_t)NU * HDIM;
    float* cate_h = poi_h + (size_t)NPOI * HDIM;

    // ---- workspace layout ----
    int*   R    = (int*)d_ws;                  // [TOT_R]   10.0 MB
    int*   es   = R + TOT_R;                   // [TOT_E]   16.8 MB
    float* ew   = (float*)(es + TOT_E);        // [TOT_E]   16.8 MB
    int*   part = (int*)(ew + TOT_E);          // [4096]
    float* tail = (float*)(part + 4096);

    size_t base_b = ((size_t)TOT_R + 2 * (size_t)TOT_E + 4096) * 4;
    size_t need_A = base_b + ((size_t)NU + NPOI + NC) * HDIM * 4;   // ~133 MB
    bool pret = (ws_size >= need_A);

    float* userT = tail;                        // [NU*32]   64 MB   (path A)
    float* poiT  = userT + (size_t)NU * HDIM;   // [NPOI*32] 25.6 MB (path A)
    float* cateT = poiT + (size_t)NPOI * HDIM;  // [NC*32]           (path A)
    float* snap  = tail;                        // [NPOI*32] 25.6 MB (path B)

    const int* eis[NLISTS] = {ei_rev_pv, ei_rev_mc, ei_rev_order,
                              ei_pv, ei_mc, ei_order, ei_belongs, ei_pp};
    const float* eas[NLISTS] = {ea_rev_pv, ea_rev_mc, ea_rev_order,
                                ea_pv, ea_mc, ea_order, nullptr, ea_pp};
    const int Es[NLISTS] = {E_UP, E_UP, E_UP, E_UP, E_UP, E_UP, NPOI, E_PP};
    const int ns[NLISTS] = {NU, NU, NU, NPOI, NPOI, NPOI, NPOI, NPOI};
    int eoff[NLISTS], roff[NLISTS];
    { int eo = 0, ro = 0;
      for (int l = 0; l < NLISTS; ++l) { eoff[l] = eo; roff[l] = ro; eo += Es[l]; ro += ns[l]; } }

    dim3 blk(256);

    // ---- CSR build (once; reused by both layers) ----
    hipLaunchKernelGGL(zero_kernel, dim3(2048), blk, 0, stream, R, TOT_R);
    for (int l = 0; l < NLISTS; ++l)
        hipLaunchKernelGGL(hist1, dim3((Es[l] + 255) / 256), blk, 0, stream,
                           eis[l] + Es[l], Es[l], R + roff[l]);
    int nb = (TOT_R + SCAN_CHUNK - 1) / SCAN_CHUNK;
    hipLaunchKernelGGL(scan1, dim3(nb), dim3(SCAN_T), 0, stream, R, TOT_R, part);
    hipLaunchKernelGGL(scan2, dim3(1), dim3(SCAN_T), 0, stream, part, nb);
    hipLaunchKernelGGL(scan3, dim3(nb), dim3(SCAN_T), 0, stream, R, TOT_R, part);
    for (int l = 0; l < NLISTS; ++l)
        hipLaunchKernelGGL(fill1, dim3((Es[l] + 255) / 256), blk, 0, stream,
                           eis[l], eas[l], Es[l], R + roff[l], es, ew);

    // ---- init node states ----
    hipLaunchKernelGGL(init_nodes, dim3((NU * HDIM + 255) / 256), blk, 0, stream,
                       x_user, 2, ulw, ulb, (const float*)nullptr, user_h, NU);
    hipLaunchKernelGGL(init_nodes, dim3((NPOI * HDIM + 255) / 256), blk, 0, stream,
                       x_poi, 3, plw, plb, (const float*)nullptr, poi_h, NPOI);
    hipLaunchKernelGGL(init_nodes, dim3((NC * HDIM + 255) / 256), blk, 0, stream,
                       x_cate, 1, clw, clb, cate_emb, cate_h, NC);

    dim3 gu(((NU + 31) / 32 + 7) / 8);      // groups of 32 rows, 8 groups/block
    dim3 gp(((NPOI + 31) / 32 + 7) / 8);
    dim3 gtu((NU * HDIM + 255) / 256);
    dim3 gtp((NPOI * HDIM + 255) / 256);
    dim3 gtc((NC * HDIM + 255) / 256);
    int n4 = NPOI * HDIM / 4;

    for (int layer = 0; layer < 2; ++layer) {
        const float* Wp  = layer ? W2p_w  : W1p_w;   const float* bp  = layer ? W2p_b  : W1p_b;
        const float* Wu  = layer ? W2u_w  : W1u_w;   const float* bu  = layer ? W2u_b  : W1u_b;
        const float* Wc  = layer ? W2c_w  : W1c_w;   const float* bc  = layer ? W2c_b  : W1c_b;
        const float* Wpp = layer ? W2pp_w : W1pp_w;  const float* bpp = layer ? W2pp_b : W1pp_b;

        if (pret) {
            // rev x3: user_h += sum_l relu(mean(poiT gather))
            hipLaunchKernelGGL(transform_k, gtp, blk, 0, stream, poi_h, Wp, bp, poiT, NPOI);
            hipLaunchKernelGGL((row_prop<3, true>), gu, blk, 0, stream,
                               user_h, poiT, R, es, ew,
                               roff[0], roff[1], roff[2], eoff[0], eoff[1], eoff[2],
                               Wp, bp, NU);
            // fwd x3
            hipLaunchKernelGGL(transform_k, gtu, blk, 0, stream, user_h, Wu, bu, userT, NU);
            hipLaunchKernelGGL((row_prop<3, true>), gp, blk, 0, stream,
                               poi_h, userT, R, es, ew,
                               roff[3], roff[4], roff[5], eoff[3], eoff[4], eoff[5],
                               Wu, bu, NPOI);
            // belongs
            hipLaunchKernelGGL(transform_k, gtc, blk, 0, stream, cate_h, Wc, bc, cateT, NC);
            hipLaunchKernelGGL((row_prop<1, true>), gp, blk, 0, stream,
                               poi_h, cateT, R, es, ew,
                               roff[6], 0, 0, eoff[6], 0, 0, Wc, bc, NPOI);
            // pp: poiT doubles as the race-free snapshot
            hipLaunchKernelGGL(transform_k, gtp, blk, 0, stream, poi_h, Wpp, bpp, poiT, NPOI);
            hipLaunchKernelGGL((row_prop<1, true>), gp, blk, 0, stream,
                               poi_h, poiT, R, es, ew,
                               roff[7], 0, 0, eoff[7], 0, 0, Wpp, bpp, NPOI);
        } else {
            hipLaunchKernelGGL((row_prop<3, false>), gu, blk, 0, stream,
                               user_h, poi_h, R, es, ew,
                               roff[0], roff[1], roff[2], eoff[0], eoff[1], eoff[2],
                               Wp, bp, NU);
            hipLaunchKernelGGL((row_prop<3, false>), gp, blk, 0, stream,
                               poi_h, user_h, R, es, ew,
                               roff[3], roff[4], roff[5], eoff[3], eoff[4], eoff[5],
                               Wu, bu, NPOI);
            hipLaunchKernelGGL((row_prop<1, false>), gp, blk, 0, stream,
                               poi_h, cate_h, R, es, ew,
                               roff[6], 0, 0, eoff[6], 0, 0, Wc, bc, NPOI);
            hipLaunchKernelGGL(copy4, dim3(4096), blk, 0, stream,
                               (const float4*)poi_h, (float4*)snap, n4);
            hipLaunchKernelGGL((row_prop<1, false>), gp, blk, 0, stream,
                               poi_h, snap, R, es, ew,
                               roff[7], 0, 0, eoff[7], 0, 0, Wpp, bpp, NPOI);
        }
    }
}

// Round 4
// 1553.532 us; speedup vs baseline: 3.3011x; 1.2700x over previous
//
#include <hip/hip_runtime.h>

#define HDIM 32

static constexpr int NU   = 500000;
static constexpr int NPOI = 200000;
static constexpr int NC   = 100;
static constexpr int E_UP = 500000;
static constexpr int E_PP = 1000000;

static constexpr int NLISTS = 8;
static constexpr int TOT_E  = 6 * E_UP + NPOI + E_PP;   // 4,200,000
static constexpr int TOT_R  = 3 * NU + 5 * NPOI;        // 2,500,000

// ---------------------------------------------------------------------------
__global__ void zero_kernel(int* __restrict__ p, int n) {
    int i = blockIdx.x * blockDim.x + threadIdx.x;
    int stride = gridDim.x * blockDim.x;
    for (; i < n; i += stride) p[i] = 0;
}

// ---------------------------------------------------------------------------
__global__ void init_nodes(const float* __restrict__ x, int fin,
                           const float* __restrict__ W, const float* __restrict__ b,
                           const float* __restrict__ emb,
                           float* __restrict__ h, int n) {
    int idx = blockIdx.x * blockDim.x + threadIdx.x;
    if (idx >= n * HDIM) return;
    int i = idx >> 5, f = idx & 31;
    float r = b[f];
    for (int k = 0; k < fin; ++k) r += x[i * fin + k] * W[k * HDIM + f];
    r = fmaxf(r, 0.0f);
    if (emb) r += emb[idx];
    h[idx] = r;
}

// ---------------------------------------------------------------------------
// per-list histogram: Rl[d] += 1   (Rl = R + roff_l)
__global__ void hist1(const int* __restrict__ ei_dst, int E, int* __restrict__ Rl) {
    int e = blockIdx.x * blockDim.x + threadIdx.x;
    if (e < E) atomicAdd(&Rl[ei_dst[e]], 1);
}

// ---------------------------------------------------------------------------
// 3-pass exclusive scan of R (2.5M ints)
#define SCAN_T 256
#define SCAN_ELEMS 4
#define SCAN_CHUNK (SCAN_T * SCAN_ELEMS)

__global__ void scan1(int* __restrict__ R, int N, int* __restrict__ part) {
    __shared__ int lds[SCAN_T];
    int base = blockIdx.x * SCAN_CHUNK + threadIdx.x * SCAN_ELEMS;
    int v[SCAN_ELEMS]; int s = 0;
#pragma unroll
    for (int k = 0; k < SCAN_ELEMS; ++k) { int i = base + k; v[k] = (i < N) ? R[i] : 0; s += v[k]; }
    lds[threadIdx.x] = s; __syncthreads();
    for (int off = 1; off < SCAN_T; off <<= 1) {
        int t = (threadIdx.x >= off) ? lds[threadIdx.x - off] : 0;
        __syncthreads(); lds[threadIdx.x] += t; __syncthreads();
    }
    int incl = lds[threadIdx.x];
    int total = lds[SCAN_T - 1];
    int run = incl - s;
#pragma unroll
    for (int k = 0; k < SCAN_ELEMS; ++k) { int i = base + k; if (i < N) R[i] = run; run += v[k]; }
    if (threadIdx.x == 0) part[blockIdx.x] = total;
}

__global__ void scan2(int* __restrict__ part, int nb) {
    __shared__ int lds[SCAN_T];
    __shared__ int carry;
    if (threadIdx.x == 0) carry = 0;
    __syncthreads();
    for (int base = 0; base < nb; base += SCAN_T) {
        int i = base + threadIdx.x;
        int v = (i < nb) ? part[i] : 0;
        lds[threadIdx.x] = v; __syncthreads();
        for (int off = 1; off < SCAN_T; off <<= 1) {
            int t = (threadIdx.x >= off) ? lds[threadIdx.x - off] : 0;
            __syncthreads(); lds[threadIdx.x] += t; __syncthreads();
        }
        int incl = lds[threadIdx.x]; int tot = lds[SCAN_T - 1];
        if (i < nb) part[i] = carry + incl - v;
        __syncthreads();
        if (threadIdx.x == 0) carry += tot;
        __syncthreads();
    }
}

__global__ void scan3(int* __restrict__ R, int N, const int* __restrict__ part) {
    int base = blockIdx.x * SCAN_CHUNK + threadIdx.x * SCAN_ELEMS;
    int add = part[blockIdx.x];
#pragma unroll
    for (int k = 0; k < SCAN_ELEMS; ++k) { int i = base + k; if (i < N) R[i] += add; }
}

// ---------------------------------------------------------------------------
// per-list fill: dst-sorted packed edge stream esw = {src, weight_bits}.
// After this kernel R[roff+d] = end(d).
__global__ void fill1(const int* __restrict__ ei, const float* __restrict__ ea,
                      int E, int* __restrict__ Rl, int2* __restrict__ esw) {
    int e = blockIdx.x * blockDim.x + threadIdx.x;
    if (e >= E) return;
    int d = ei[E + e];
    int pos = atomicAdd(&Rl[d], 1);
    float w = ea ? ea[e] : 1.0f;
    esw[pos] = make_int2(ei[e], __float_as_int(w));
}

// ---------------------------------------------------------------------------
// Dense per-node transform: out[i,:] = src[i,:] @ W + b
__global__ __launch_bounds__(256) void transform_k(const float* __restrict__ src,
                                                   const float* __restrict__ W,
                                                   const float* __restrict__ b,
                                                   float* __restrict__ out, int n) {
    int idx = blockIdx.x * blockDim.x + threadIdx.x;
    if (idx >= n * HDIM) return;
    int f = idx & 31;
    float Wc[HDIM];
#pragma unroll
    for (int k = 0; k < HDIM; ++k) Wc[k] = W[k * HDIM + f];
    float x = src[idx];
    float r = b[f];
#pragma unroll
    for (int k = 0; k < HDIM; ++k) r += __shfl(x, k, 32) * Wc[k];
    out[idx] = r;
}

// ---------------------------------------------------------------------------
__global__ void copy4(const float4* __restrict__ src, float4* __restrict__ dst, int n4) {
    int i = blockIdx.x * blockDim.x + threadIdx.x;
    int stride = gridDim.x * blockDim.x;
    for (; i < n4; i += stride) dst[i] = src[i];
}

// ---------------------------------------------------------------------------
// One 32-lane group per dst row (lane = feature). Walks the row's contiguous
// CSR range per list: one int2 broadcast load + one coalesced 128B row gather
// per edge. 8 rows per 256-thread block -> ~100k waves, full occupancy.
// PRET: src is pre-transformed (W,b folded) -> no matvec here.
template<int NL, bool PRET>
__global__ __launch_bounds__(256) void row_prop(
    float* __restrict__ dst, const float* __restrict__ src,
    const int* __restrict__ R, const int2* __restrict__ esw,
    int ro0, int ro1, int ro2, int eo0, int eo1, int eo2,
    const float* __restrict__ W, const float* __restrict__ b, int n) {
    __shared__ float Ws[HDIM * HDIM];
    if (!PRET) {
        for (int i = threadIdx.x; i < HDIM * HDIM; i += blockDim.x) Ws[i] = W[i];
        __syncthreads();
    }
    int r = blockIdx.x * (blockDim.x >> 5) + (threadIdx.x >> 5);
    if (r >= n) return;
    int f = threadIdx.x & 31;
    float bf = PRET ? 0.0f : b[f];
    float res = 0.0f;
    int ctot = 0;
#pragma unroll
    for (int l = 0; l < NL; ++l) {
        int ro = (l == 0) ? ro0 : (l == 1) ? ro1 : ro2;
        int eo = (l == 0) ? eo0 : (l == 1) ? eo1 : eo2;
        int jcur = (r == 0) ? eo : R[ro + r - 1];
        int jend = R[ro + r];
        int c = jend - jcur;
        float acc = 0.0f, t = 0.0f;
        for (int j = jcur; j < jend; ++j) {
            int2 e = esw[j];
            float w = __int_as_float(e.y);
            acc += w * src[(size_t)e.x * HDIM + f];
            if (!PRET) t += w;
        }
        ctot += c;
        float rl;
        if (PRET) {
            rl = acc / fmaxf((float)c, 1.0f);
        } else {
            rl = t * bf;
#pragma unroll
            for (int k = 0; k < HDIM; ++k) rl += __shfl(acc, k, 32) * Ws[k * HDIM + f];
            rl /= fmaxf((float)c, 1.0f);
        }
        res += fmaxf(rl, 0.0f);
    }
    if (ctot > 0) dst[(size_t)r * HDIM + f] += res;
}

// ---------------------------------------------------------------------------
extern "C" void kernel_launch(void* const* d_in, const int* in_sizes, int n_in,
                              void* d_out, int out_size, void* d_ws, size_t ws_size,
                              hipStream_t stream) {
    const float* x_user = (const float*)d_in[0];
    const float* x_poi  = (const float*)d_in[1];
    const float* x_cate = (const float*)d_in[2];
    const float* ulw    = (const float*)d_in[3];
    const float* ulb    = (const float*)d_in[4];
    const float* plw    = (const float*)d_in[5];
    const float* plb    = (const float*)d_in[6];
    const float* clw    = (const float*)d_in[7];
    const float* clb    = (const float*)d_in[8];
    const float* W1u_w  = (const float*)d_in[9];   const float* W1u_b  = (const float*)d_in[10];
    const float* W1p_w  = (const float*)d_in[11];  const float* W1p_b  = (const float*)d_in[12];
    const float* W1c_w  = (const float*)d_in[13];  const float* W1c_b  = (const float*)d_in[14];
    const float* W1pp_w = (const float*)d_in[15];  const float* W1pp_b = (const float*)d_in[16];
    const float* W2u_w  = (const float*)d_in[17];  const float* W2u_b  = (const float*)d_in[18];
    const float* W2p_w  = (const float*)d_in[19];  const float* W2p_b  = (const float*)d_in[20];
    const float* W2c_w  = (const float*)d_in[21];  const float* W2c_b  = (const float*)d_in[22];
    const float* W2pp_w = (const float*)d_in[23];  const float* W2pp_b = (const float*)d_in[24];
    const float* cate_emb = (const float*)d_in[25];
    const int* ei_pv        = (const int*)d_in[26];
    const int* ei_mc        = (const int*)d_in[27];
    const int* ei_order     = (const int*)d_in[28];
    const int* ei_rev_pv    = (const int*)d_in[29];
    const int* ei_rev_mc    = (const int*)d_in[30];
    const int* ei_rev_order = (const int*)d_in[31];
    const int* ei_belongs   = (const int*)d_in[32];
    const int* ei_pp        = (const int*)d_in[33];
    const float* ea_pv        = (const float*)d_in[34];
    const float* ea_mc        = (const float*)d_in[35];
    const float* ea_order     = (const float*)d_in[36];
    const float* ea_rev_pv    = (const float*)d_in[37];
    const float* ea_rev_mc    = (const float*)d_in[38];
    const float* ea_rev_order = (const float*)d_in[39];
    const float* ea_pp        = (const float*)d_in[40];

    float* user_h = (float*)d_out;
    float* poi_h  = user_h + (size_t)NU * HDIM;
    float* cate_h = poi_h + (size_t)NPOI * HDIM;

    // ---- workspace layout ----
    int*   R    = (int*)d_ws;                  // [TOT_R]        10.0 MB
    int2*  esw  = (int2*)(R + TOT_R);          // [TOT_E] int2   33.6 MB
    int*   part = (int*)(esw + TOT_E);         // [4096]
    float* tail = (float*)(part + 4096);

    size_t base_b = ((size_t)TOT_R + 2 * (size_t)TOT_E + 4096) * 4;
    size_t need_A = base_b + ((size_t)NU + NPOI + NC) * HDIM * 4;   // ~134 MB
    bool pret = (ws_size >= need_A);

    float* userT = tail;                        // [NU*32]   64 MB   (path A)
    float* poiT  = userT + (size_t)NU * HDIM;   // [NPOI*32] 25.6 MB (path A)
    float* cateT = poiT + (size_t)NPOI * HDIM;  // [NC*32]           (path A)
    float* snap  = tail;                        // [NPOI*32] 25.6 MB (path B)

    const int* eis[NLISTS] = {ei_rev_pv, ei_rev_mc, ei_rev_order,
                              ei_pv, ei_mc, ei_order, ei_belongs, ei_pp};
    const float* eas[NLISTS] = {ea_rev_pv, ea_rev_mc, ea_rev_order,
                                ea_pv, ea_mc, ea_order, nullptr, ea_pp};
    const int Es[NLISTS] = {E_UP, E_UP, E_UP, E_UP, E_UP, E_UP, NPOI, E_PP};
    const int ns[NLISTS] = {NU, NU, NU, NPOI, NPOI, NPOI, NPOI, NPOI};
    int eoff[NLISTS], roff[NLISTS];
    { int eo = 0, ro = 0;
      for (int l = 0; l < NLISTS; ++l) { eoff[l] = eo; roff[l] = ro; eo += Es[l]; ro += ns[l]; } }

    dim3 blk(256);

    // ---- CSR build (once; reused by both layers) ----
    hipLaunchKernelGGL(zero_kernel, dim3(2048), blk, 0, stream, R, TOT_R);
    for (int l = 0; l < NLISTS; ++l)
        hipLaunchKernelGGL(hist1, dim3((Es[l] + 255) / 256), blk, 0, stream,
                           eis[l] + Es[l], Es[l], R + roff[l]);
    int nb = (TOT_R + SCAN_CHUNK - 1) / SCAN_CHUNK;
    hipLaunchKernelGGL(scan1, dim3(nb), dim3(SCAN_T), 0, stream, R, TOT_R, part);
    hipLaunchKernelGGL(scan2, dim3(1), dim3(SCAN_T), 0, stream, part, nb);
    hipLaunchKernelGGL(scan3, dim3(nb), dim3(SCAN_T), 0, stream, R, TOT_R, part);
    for (int l = 0; l < NLISTS; ++l)
        hipLaunchKernelGGL(fill1, dim3((Es[l] + 255) / 256), blk, 0, stream,
                           eis[l], eas[l], Es[l], R + roff[l], esw);

    // ---- init node states ----
    hipLaunchKernelGGL(init_nodes, dim3((NU * HDIM + 255) / 256), blk, 0, stream,
                       x_user, 2, ulw, ulb, (const float*)nullptr, user_h, NU);
    hipLaunchKernelGGL(init_nodes, dim3((NPOI * HDIM + 255) / 256), blk, 0, stream,
                       x_poi, 3, plw, plb, (const float*)nullptr, poi_h, NPOI);
    hipLaunchKernelGGL(init_nodes, dim3((NC * HDIM + 255) / 256), blk, 0, stream,
                       x_cate, 1, clw, clb, cate_emb, cate_h, NC);

    dim3 gu((NU + 7) / 8);                 // 1 row per 32-lane group, 8/block
    dim3 gp((NPOI + 7) / 8);
    dim3 gtu((NU * HDIM + 255) / 256);
    dim3 gtp((NPOI * HDIM + 255) / 256);
    dim3 gtc((NC * HDIM + 255) / 256);
    int n4 = NPOI * HDIM / 4;

    for (int layer = 0; layer < 2; ++layer) {
        const float* Wp  = layer ? W2p_w  : W1p_w;   const float* bp  = layer ? W2p_b  : W1p_b;
        const float* Wu  = layer ? W2u_w  : W1u_w;   const float* bu  = layer ? W2u_b  : W1u_b;
        const float* Wc  = layer ? W2c_w  : W1c_w;   const float* bc  = layer ? W2c_b  : W1c_b;
        const float* Wpp = layer ? W2pp_w : W1pp_w;  const float* bpp = layer ? W2pp_b : W1pp_b;

        if (pret) {
            // rev x3: user_h += sum_l relu(mean(poiT gather))
            hipLaunchKernelGGL(transform_k, gtp, blk, 0, stream, poi_h, Wp, bp, poiT, NPOI);
            hipLaunchKernelGGL((row_prop<3, true>), gu, blk, 0, stream,
                               user_h, poiT, R, esw,
                               roff[0], roff[1], roff[2], eoff[0], eoff[1], eoff[2],
                               Wp, bp, NU);
            // fwd x3
            hipLaunchKernelGGL(transform_k, gtu, blk, 0, stream, user_h, Wu, bu, userT, NU);
            hipLaunchKernelGGL((row_prop<3, true>), gp, blk, 0, stream,
                               poi_h, userT, R, esw,
                               roff[3], roff[4], roff[5], eoff[3], eoff[4], eoff[5],
                               Wu, bu, NPOI);
            // belongs
            hipLaunchKernelGGL(transform_k, gtc, blk, 0, stream, cate_h, Wc, bc, cateT, NC);
            hipLaunchKernelGGL((row_prop<1, true>), gp, blk, 0, stream,
                               poi_h, cateT, R, esw,
                               roff[6], 0, 0, eoff[6], 0, 0, Wc, bc, NPOI);
            // pp: poiT doubles as the race-free snapshot
            hipLaunchKernelGGL(transform_k, gtp, blk, 0, stream, poi_h, Wpp, bpp, poiT, NPOI);
            hipLaunchKernelGGL((row_prop<1, true>), gp, blk, 0, stream,
                               poi_h, poiT, R, esw,
                               roff[7], 0, 0, eoff[7], 0, 0, Wpp, bpp, NPOI);
        } else {
            hipLaunchKernelGGL((row_prop<3, false>), gu, blk, 0, stream,
                               user_h, poi_h, R, esw,
                               roff[0], roff[1], roff[2], eoff[0], eoff[1], eoff[2],
                               Wp, bp, NU);
            hipLaunchKernelGGL((row_prop<3, false>), gp, blk, 0, stream,
                               poi_h, user_h, R, esw,
                               roff[3], roff[4], roff[5], eoff[3], eoff[4], eoff[5],
                               Wu, bu, NPOI);
            hipLaunchKernelGGL((row_prop<1, false>), gp, blk, 0, stream,
                               poi_h, cate_h, R, esw,
                               roff[6], 0, 0, eoff[6], 0, 0, Wc, bc, NPOI);
            hipLaunchKernelGGL(copy4, dim3(4096), blk, 0, stream,
                               (const float4*)poi_h, (float4*)snap, n4);
            hipLaunchKernelGGL((row_prop<1, false>), gp, blk, 0, stream,
                               poi_h, snap, R, esw,
                               roff[7], 0, 0, eoff[7], 0, 0, Wpp, bpp, NPOI);
        }
    }
}

// Round 5
// 967.689 us; speedup vs baseline: 5.2996x; 1.6054x over previous
//
#include <hip/hip_runtime.h>

#define HDIM 32

static constexpr int NU   = 500000;
static constexpr int NPOI = 200000;
static constexpr int NC   = 100;
static constexpr int E_UP = 500000;
static constexpr int E_PP = 1000000;

static constexpr int NLISTS = 8;
static constexpr int TOT_E  = 6 * E_UP + NPOI + E_PP;   // 4,200,000
static constexpr int TOT_R4 = 4 * NU + 6 * NPOI;        // 3,200,000 (padded int4 layout)
static constexpr int TOT_R1 = 3 * NU + 5 * NPOI;        // 2,500,000 (scalar fallback layout)

// ---------------------------------------------------------------------------
__global__ void zero_kernel(int* __restrict__ p, int n) {
    int i = blockIdx.x * blockDim.x + threadIdx.x;
    int stride = gridDim.x * blockDim.x;
    for (; i < n; i += stride) p[i] = 0;
}

// ---------------------------------------------------------------------------
__global__ void init_nodes(const float* __restrict__ x, int fin,
                           const float* __restrict__ W, const float* __restrict__ b,
                           const float* __restrict__ emb,
                           float* __restrict__ h, int n) {
    int idx = blockIdx.x * blockDim.x + threadIdx.x;
    if (idx >= n * HDIM) return;
    int i = idx >> 5, f = idx & 31;
    float r = b[f];
    for (int k = 0; k < fin; ++k) r += x[i * fin + k] * W[k * HDIM + f];
    r = fmaxf(r, 0.0f);
    if (emb) r += emb[idx];
    h[idx] = r;
}

// ---------------------------------------------------------------------------
// histogram with layout params: R[base + d*stride + slot] += 1
__global__ void hist1(const int* __restrict__ ei_dst, int E, int* __restrict__ R,
                      int base, int stride, int slot) {
    int e = blockIdx.x * blockDim.x + threadIdx.x;
    if (e < E) atomicAdd(&R[base + ei_dst[e] * stride + slot], 1);
}

// ---------------------------------------------------------------------------
// 3-pass exclusive scan (zeros in pad slots are prefix-neutral)
#define SCAN_T 256
#define SCAN_ELEMS 4
#define SCAN_CHUNK (SCAN_T * SCAN_ELEMS)

__global__ void scan1(int* __restrict__ R, int N, int* __restrict__ part) {
    __shared__ int lds[SCAN_T];
    int base = blockIdx.x * SCAN_CHUNK + threadIdx.x * SCAN_ELEMS;
    int v[SCAN_ELEMS]; int s = 0;
#pragma unroll
    for (int k = 0; k < SCAN_ELEMS; ++k) { int i = base + k; v[k] = (i < N) ? R[i] : 0; s += v[k]; }
    lds[threadIdx.x] = s; __syncthreads();
    for (int off = 1; off < SCAN_T; off <<= 1) {
        int t = (threadIdx.x >= off) ? lds[threadIdx.x - off] : 0;
        __syncthreads(); lds[threadIdx.x] += t; __syncthreads();
    }
    int incl = lds[threadIdx.x];
    int total = lds[SCAN_T - 1];
    int run = incl - s;
#pragma unroll
    for (int k = 0; k < SCAN_ELEMS; ++k) { int i = base + k; if (i < N) R[i] = run; run += v[k]; }
    if (threadIdx.x == 0) part[blockIdx.x] = total;
}

__global__ void scan2(int* __restrict__ part, int nb) {
    __shared__ int lds[SCAN_T];
    __shared__ int carry;
    if (threadIdx.x == 0) carry = 0;
    __syncthreads();
    for (int base = 0; base < nb; base += SCAN_T) {
        int i = base + threadIdx.x;
        int v = (i < nb) ? part[i] : 0;
        lds[threadIdx.x] = v; __syncthreads();
        for (int off = 1; off < SCAN_T; off <<= 1) {
            int t = (threadIdx.x >= off) ? lds[threadIdx.x - off] : 0;
            __syncthreads(); lds[threadIdx.x] += t; __syncthreads();
        }
        int incl = lds[threadIdx.x]; int tot = lds[SCAN_T - 1];
        if (i < nb) part[i] = carry + incl - v;
        __syncthreads();
        if (threadIdx.x == 0) carry += tot;
        __syncthreads();
    }
}

__global__ void scan3(int* __restrict__ R, int N, const int* __restrict__ part) {
    int base = blockIdx.x * SCAN_CHUNK + threadIdx.x * SCAN_ELEMS;
    int add = part[blockIdx.x];
#pragma unroll
    for (int k = 0; k < SCAN_ELEMS; ++k) { int i = base + k; if (i < N) R[i] += add; }
}

// ---------------------------------------------------------------------------
// fill: dst-sorted packed edge stream esw = {src BYTE offset, weight bits}.
// After this kernel the R slot = end(d, list).
__global__ void fill1(const int* __restrict__ ei, const float* __restrict__ ea,
                      int E, int* __restrict__ R, int base, int stride, int slot,
                      int2* __restrict__ esw) {
    int e = blockIdx.x * blockDim.x + threadIdx.x;
    if (e >= E) return;
    int d = ei[E + e];
    int pos = atomicAdd(&R[base + d * stride + slot], 1);
    float w = ea ? ea[e] : 1.0f;
    esw[pos] = make_int2(ei[e] << 7, __float_as_int(w));   // 128 B/row
}

// ---------------------------------------------------------------------------
// Dense per-node transform: out[i,:] = src[i,:] @ W + b (32 lanes/row)
__global__ __launch_bounds__(256) void transform_k(const float* __restrict__ src,
                                                   const float* __restrict__ W,
                                                   const float* __restrict__ b,
                                                   float* __restrict__ out, int n) {
    int idx = blockIdx.x * blockDim.x + threadIdx.x;
    if (idx >= n * HDIM) return;
    int f = idx & 31;
    float Wc[HDIM];
#pragma unroll
    for (int k = 0; k < HDIM; ++k) Wc[k] = W[k * HDIM + f];
    float x = src[idx];
    float r = b[f];
#pragma unroll
    for (int k = 0; k < HDIM; ++k) r += __shfl(x, k, 32) * Wc[k];
    out[idx] = r;
}

// ---------------------------------------------------------------------------
__global__ void copy4(const float4* __restrict__ src, float4* __restrict__ dst, int n4) {
    int i = blockIdx.x * blockDim.x + threadIdx.x;
    int stride = gridDim.x * blockDim.x;
    for (; i < n4; i += stride) dst[i] = src[i];
}

// ---------------------------------------------------------------------------
// PRET prop: 8 lanes per dst row (lane owns 4 features as float4), 8 rows/wave,
// 32 rows per 256-block. NL=3 uses the padded int4 CSR row (2 loads for all 6
// boundaries). EPI: fused epilogue transform of the updated dst row into dstT
// (saves a full-table read pass of a separate transform kernel).
template<int NL, bool EPI>
__global__ __launch_bounds__(256) void row_prop4(
    float4* __restrict__ dst4, const char* __restrict__ srcB,
    const int* __restrict__ Rb, const int2* __restrict__ esw, int eo,
    const float4* __restrict__ WT4, const float4* __restrict__ bT4,
    float4* __restrict__ dstT4, int n) {
    __shared__ float4 Ws4[HDIM][8];   // Ws4[k][j] = W[k][4j..4j+3]
    __shared__ float4 bTs[8];
    if (EPI) {
        int t = threadIdx.x;
        { int k = t >> 3, j = t & 7; Ws4[k][j] = WT4[k * 8 + j]; }
        if (t < 8) bTs[t] = bT4[t];
        __syncthreads();
    }
    int grp = threadIdx.x >> 3, lane8 = threadIdx.x & 7;
    int r = blockIdx.x * 32 + grp;
    if (r >= n) return;

    int js[3], je[3];
    if (NL == 3) {
        const int4* R4 = (const int4*)Rb;
        int rm = (r == 0) ? 0 : r - 1;
        int4 pv = R4[rm];
        int4 ev = R4[r];
        int s0 = (r == 0) ? eo : pv.z;
        js[0] = s0;   je[0] = ev.x;
        js[1] = ev.x; je[1] = ev.y;
        js[2] = ev.y; je[2] = ev.z;
    } else {
        int rm = (r == 0) ? 0 : r - 1;
        int s0 = (r == 0) ? eo : Rb[rm];
        js[0] = s0; je[0] = Rb[r];
    }

    float4 res = make_float4(0.f, 0.f, 0.f, 0.f);
    int ctot = 0;
#pragma unroll
    for (int l = 0; l < NL; ++l) {
        int jc = js[l], jend = je[l];
        int c = jend - jc;
        float4 acc = make_float4(0.f, 0.f, 0.f, 0.f);
        for (int j = jc; j < jend; ++j) {
            int2 e = esw[j];
            float w = __int_as_float(e.y);
            const float4* sr = (const float4*)(srcB + (size_t)(unsigned)e.x);
            float4 v = sr[lane8];
            acc.x += w * v.x; acc.y += w * v.y; acc.z += w * v.z; acc.w += w * v.w;
        }
        ctot += c;
        float inv = 1.0f / fmaxf((float)c, 1.0f);
        res.x += fmaxf(acc.x * inv, 0.0f);
        res.y += fmaxf(acc.y * inv, 0.0f);
        res.z += fmaxf(acc.z * inv, 0.0f);
        res.w += fmaxf(acc.w * inv, 0.0f);
    }

    float4* dp = dst4 + (size_t)r * 8 + lane8;
    float4 dv;
    if (EPI) {
        dv = *dp;
        if (ctot) { dv.x += res.x; dv.y += res.y; dv.z += res.z; dv.w += res.w; *dp = dv; }
    } else {
        if (ctot) {
            dv = *dp;
            dv.x += res.x; dv.y += res.y; dv.z += res.z; dv.w += res.w;
            *dp = dv;
        }
    }

    if (EPI) {
        float4 to = bTs[lane8];
#pragma unroll
        for (int sl = 0; sl < 8; ++sl) {
            float ux = __shfl(dv.x, sl, 8);
            float uy = __shfl(dv.y, sl, 8);
            float uz = __shfl(dv.z, sl, 8);
            float uw = __shfl(dv.w, sl, 8);
            float4 w0 = Ws4[sl * 4 + 0][lane8];
            to.x += ux * w0.x; to.y += ux * w0.y; to.z += ux * w0.z; to.w += ux * w0.w;
            float4 w1 = Ws4[sl * 4 + 1][lane8];
            to.x += uy * w1.x; to.y += uy * w1.y; to.z += uy * w1.z; to.w += uy * w1.w;
            float4 w2 = Ws4[sl * 4 + 2][lane8];
            to.x += uz * w2.x; to.y += uz * w2.y; to.z += uz * w2.z; to.w += uz * w2.w;
            float4 w3 = Ws4[sl * 4 + 3][lane8];
            to.x += uw * w3.x; to.y += uw * w3.y; to.z += uw * w3.z; to.w += uw * w3.w;
        }
        dstT4[(size_t)r * 8 + lane8] = to;
    }
}

// ---------------------------------------------------------------------------
// Fallback prop (non-pret): 32 lanes/row, in-kernel shfl matvec; scalar CSR
// layout; esw.x is a byte offset.
template<int NL>
__global__ __launch_bounds__(256) void row_prop_fb(
    float* __restrict__ dst, const char* __restrict__ srcB,
    const int* __restrict__ R, const int2* __restrict__ esw,
    int ro0, int ro1, int ro2, int eo0, int eo1, int eo2,
    const float* __restrict__ W, const float* __restrict__ b, int n) {
    __shared__ float Ws[HDIM * HDIM];
    for (int i = threadIdx.x; i < HDIM * HDIM; i += blockDim.x) Ws[i] = W[i];
    __syncthreads();
    int r = blockIdx.x * (blockDim.x >> 5) + (threadIdx.x >> 5);
    if (r >= n) return;
    int f = threadIdx.x & 31;
    float bf = b[f];
    float res = 0.0f;
    int ctot = 0;
#pragma unroll
    for (int l = 0; l < NL; ++l) {
        int ro = (l == 0) ? ro0 : (l == 1) ? ro1 : ro2;
        int eo = (l == 0) ? eo0 : (l == 1) ? eo1 : eo2;
        int jcur = (r == 0) ? eo : R[ro + r - 1];
        int jend = R[ro + r];
        int c = jend - jcur;
        float acc = 0.0f, t = 0.0f;
        for (int j = jcur; j < jend; ++j) {
            int2 e = esw[j];
            float w = __int_as_float(e.y);
            acc += w * ((const float*)(srcB + (size_t)(unsigned)e.x))[f];
            t += w;
        }
        ctot += c;
        float rl = t * bf;
#pragma unroll
        for (int k = 0; k < HDIM; ++k) rl += __shfl(acc, k, 32) * Ws[k * HDIM + f];
        rl /= fmaxf((float)c, 1.0f);
        res += fmaxf(rl, 0.0f);
    }
    if (ctot > 0) dst[(size_t)r * HDIM + f] += res;
}

// ---------------------------------------------------------------------------
extern "C" void kernel_launch(void* const* d_in, const int* in_sizes, int n_in,
                              void* d_out, int out_size, void* d_ws, size_t ws_size,
                              hipStream_t stream) {
    const float* x_user = (const float*)d_in[0];
    const float* x_poi  = (const float*)d_in[1];
    const float* x_cate = (const float*)d_in[2];
    const float* ulw    = (const float*)d_in[3];
    const float* ulb    = (const float*)d_in[4];
    const float* plw    = (const float*)d_in[5];
    const float* plb    = (const float*)d_in[6];
    const float* clw    = (const float*)d_in[7];
    const float* clb    = (const float*)d_in[8];
    const float* W1u_w  = (const float*)d_in[9];   const float* W1u_b  = (const float*)d_in[10];
    const float* W1p_w  = (const float*)d_in[11];  const float* W1p_b  = (const float*)d_in[12];
    const float* W1c_w  = (const float*)d_in[13];  const float* W1c_b  = (const float*)d_in[14];
    const float* W1pp_w = (const float*)d_in[15];  const float* W1pp_b = (const float*)d_in[16];
    const float* W2u_w  = (const float*)d_in[17];  const float* W2u_b  = (const float*)d_in[18];
    const float* W2p_w  = (const float*)d_in[19];  const float* W2p_b  = (const float*)d_in[20];
    const float* W2c_w  = (const float*)d_in[21];  const float* W2c_b  = (const float*)d_in[22];
    const float* W2pp_w = (const float*)d_in[23];  const float* W2pp_b = (const float*)d_in[24];
    const float* cate_emb = (const float*)d_in[25];
    const int* ei_pv        = (const int*)d_in[26];
    const int* ei_mc        = (const int*)d_in[27];
    const int* ei_order     = (const int*)d_in[28];
    const int* ei_rev_pv    = (const int*)d_in[29];
    const int* ei_rev_mc    = (const int*)d_in[30];
    const int* ei_rev_order = (const int*)d_in[31];
    const int* ei_belongs   = (const int*)d_in[32];
    const int* ei_pp        = (const int*)d_in[33];
    const float* ea_pv        = (const float*)d_in[34];
    const float* ea_mc        = (const float*)d_in[35];
    const float* ea_order     = (const float*)d_in[36];
    const float* ea_rev_pv    = (const float*)d_in[37];
    const float* ea_rev_mc    = (const float*)d_in[38];
    const float* ea_rev_order = (const float*)d_in[39];
    const float* ea_pp        = (const float*)d_in[40];

    float* user_h = (float*)d_out;
    float* poi_h  = user_h + (size_t)NU * HDIM;
    float* cate_h = poi_h + (size_t)NPOI * HDIM;

    const int* eis[NLISTS] = {ei_rev_pv, ei_rev_mc, ei_rev_order,
                              ei_pv, ei_mc, ei_order, ei_belongs, ei_pp};
    const float* eas[NLISTS] = {ea_rev_pv, ea_rev_mc, ea_rev_order,
                                ea_pv, ea_mc, ea_order, nullptr, ea_pp};
    const int Es[NLISTS] = {E_UP, E_UP, E_UP, E_UP, E_UP, E_UP, NPOI, E_PP};

    dim3 blk(256);

    // path select
    size_t base_new = ((size_t)TOT_R4 + 2 * (size_t)TOT_E + 4096) * 4;
    size_t need_new = base_new + ((size_t)NU + NPOI + NC) * HDIM * 4;   // ~136 MB
    bool pret = (ws_size >= need_new);

    if (pret) {
        // ---- workspace (padded layout) ----
        int*   R    = (int*)d_ws;                   // [TOT_R4]  12.8 MB
        int2*  esw  = (int2*)(R + TOT_R4);          // [TOT_E]   33.6 MB
        int*   part = (int*)(esw + TOT_E);          // [4096]
        float* userT = (float*)(part + 4096);       // 64 MB
        float* poiT  = userT + (size_t)NU * HDIM;   // 25.6 MB
        float* cateT = poiT + (size_t)NPOI * HDIM;  // 12.8 KB

        // layout per list: {base, stride, slot, eoff}
        const int Lbase[NLISTS] = {0, 0, 0, 4 * NU, 4 * NU, 4 * NU,
                                   4 * NU + 4 * NPOI, 4 * NU + 5 * NPOI};
        const int Lstride[NLISTS] = {4, 4, 4, 4, 4, 4, 1, 1};
        const int Lslot[NLISTS]   = {0, 1, 2, 0, 1, 2, 0, 0};
        const int Leo[NLISTS] = {0, 0, 0, 3 * E_UP, 3 * E_UP, 3 * E_UP,
                                 6 * E_UP, 6 * E_UP + NPOI};

        // ---- CSR build ----
        hipLaunchKernelGGL(zero_kernel, dim3(2048), blk, 0, stream, R, TOT_R4);
        for (int l = 0; l < NLISTS; ++l)
            hipLaunchKernelGGL(hist1, dim3((Es[l] + 255) / 256), blk, 0, stream,
                               eis[l] + Es[l], Es[l], R, Lbase[l], Lstride[l], Lslot[l]);
        int nb = (TOT_R4 + SCAN_CHUNK - 1) / SCAN_CHUNK;
        hipLaunchKernelGGL(scan1, dim3(nb), dim3(SCAN_T), 0, stream, R, TOT_R4, part);
        hipLaunchKernelGGL(scan2, dim3(1), dim3(SCAN_T), 0, stream, part, nb);
        hipLaunchKernelGGL(scan3, dim3(nb), dim3(SCAN_T), 0, stream, R, TOT_R4, part);
        for (int l = 0; l < NLISTS; ++l)
            hipLaunchKernelGGL(fill1, dim3((Es[l] + 255) / 256), blk, 0, stream,
                               eis[l], eas[l], Es[l], R, Lbase[l], Lstride[l], Lslot[l], esw);

        // ---- init node states ----
        hipLaunchKernelGGL(init_nodes, dim3((NU * HDIM + 255) / 256), blk, 0, stream,
                           x_user, 2, ulw, ulb, (const float*)nullptr, user_h, NU);
        hipLaunchKernelGGL(init_nodes, dim3((NPOI * HDIM + 255) / 256), blk, 0, stream,
                           x_poi, 3, plw, plb, (const float*)nullptr, poi_h, NPOI);
        hipLaunchKernelGGL(init_nodes, dim3((NC * HDIM + 255) / 256), blk, 0, stream,
                           x_cate, 1, clw, clb, cate_emb, cate_h, NC);

        dim3 g_u((NU + 31) / 32), g_p((NPOI + 31) / 32);
        dim3 gtp((NPOI * HDIM + 255) / 256), gtc((NC * HDIM + 255) / 256);

        for (int layer = 0; layer < 2; ++layer) {
            const float* Wp  = layer ? W2p_w  : W1p_w;   const float* bp  = layer ? W2p_b  : W1p_b;
            const float* Wu  = layer ? W2u_w  : W1u_w;   const float* bu  = layer ? W2u_b  : W1u_b;
            const float* Wc  = layer ? W2c_w  : W1c_w;   const float* bc  = layer ? W2c_b  : W1c_b;
            const float* Wpp = layer ? W2pp_w : W1pp_w;  const float* bpp = layer ? W2pp_b : W1pp_b;

            // poiT = poi_h @ Wp + bp ; cateT = cate_h @ Wc + bc
            hipLaunchKernelGGL(transform_k, gtp, blk, 0, stream, poi_h, Wp, bp, poiT, NPOI);
            hipLaunchKernelGGL(transform_k, gtc, blk, 0, stream, cate_h, Wc, bc, cateT, NC);

            // rev3: user_h += ... ; EPI emits userT = user_h @ Wu + bu
            hipLaunchKernelGGL((row_prop4<3, true>), g_u, blk, 0, stream,
                               (float4*)user_h, (const char*)poiT, R, esw, Leo[0],
                               (const float4*)Wu, (const float4*)bu, (float4*)userT, NU);
            // fwd3: poi_h += ... from userT
            hipLaunchKernelGGL((row_prop4<3, false>), g_p, blk, 0, stream,
                               (float4*)poi_h, (const char*)userT, R + 4 * NU, esw, Leo[3],
                               (const float4*)nullptr, (const float4*)nullptr,
                               (float4*)nullptr, NPOI);
            // belongs: poi_h += ... from cateT ; EPI emits poiT = poi_h @ Wpp + bpp
            hipLaunchKernelGGL((row_prop4<1, true>), g_p, blk, 0, stream,
                               (float4*)poi_h, (const char*)cateT, R + 4 * NU + 4 * NPOI,
                               esw, Leo[6],
                               (const float4*)Wpp, (const float4*)bpp, (float4*)poiT, NPOI);
            // pp: poi_h += ... from poiT (poiT is the pre-update transform = snapshot)
            hipLaunchKernelGGL((row_prop4<1, false>), g_p, blk, 0, stream,
                               (float4*)poi_h, (const char*)poiT, R + 4 * NU + 5 * NPOI,
                               esw, Leo[7],
                               (const float4*)nullptr, (const float4*)nullptr,
                               (float4*)nullptr, NPOI);
        }
    } else {
        // ---- fallback: scalar layout, 32-lane props, in-kernel matvec ----
        int*   R    = (int*)d_ws;                   // [TOT_R1]  10 MB
        int2*  esw  = (int2*)(R + TOT_R1);          // 33.6 MB
        int*   part = (int*)(esw + TOT_E);
        float* snap = (float*)(part + 4096);        // 25.6 MB

        const int ns[NLISTS] = {NU, NU, NU, NPOI, NPOI, NPOI, NPOI, NPOI};
        int eoff[NLISTS], roff[NLISTS];
        { int eo = 0, ro = 0;
          for (int l = 0; l < NLISTS; ++l) { eoff[l] = eo; roff[l] = ro; eo += Es[l]; ro += ns[l]; } }

        hipLaunchKernelGGL(zero_kernel, dim3(2048), blk, 0, stream, R, TOT_R1);
        for (int l = 0; l < NLISTS; ++l)
            hipLaunchKernelGGL(hist1, dim3((Es[l] + 255) / 256), blk, 0, stream,
                               eis[l] + Es[l], Es[l], R, roff[l], 1, 0);
        int nb = (TOT_R1 + SCAN_CHUNK - 1) / SCAN_CHUNK;
        hipLaunchKernelGGL(scan1, dim3(nb), dim3(SCAN_T), 0, stream, R, TOT_R1, part);
        hipLaunchKernelGGL(scan2, dim3(1), dim3(SCAN_T), 0, stream, part, nb);
        hipLaunchKernelGGL(scan3, dim3(nb), dim3(SCAN_T), 0, stream, R, TOT_R1, part);
        for (int l = 0; l < NLISTS; ++l)
            hipLaunchKernelGGL(fill1, dim3((Es[l] + 255) / 256), blk, 0, stream,
                               eis[l], eas[l], Es[l], R, roff[l], 1, 0, esw);

        hipLaunchKernelGGL(init_nodes, dim3((NU * HDIM + 255) / 256), blk, 0, stream,
                           x_user, 2, ulw, ulb, (const float*)nullptr, user_h, NU);
        hipLaunchKernelGGL(init_nodes, dim3((NPOI * HDIM + 255) / 256), blk, 0, stream,
                           x_poi, 3, plw, plb, (const float*)nullptr, poi_h, NPOI);
        hipLaunchKernelGGL(init_nodes, dim3((NC * HDIM + 255) / 256), blk, 0, stream,
                           x_cate, 1, clw, clb, cate_emb, cate_h, NC);

        dim3 gu((NU + 7) / 8), gp((NPOI + 7) / 8);
        int n4 = NPOI * HDIM / 4;

        for (int layer = 0; layer < 2; ++layer) {
            const float* Wp  = layer ? W2p_w  : W1p_w;   const float* bp  = layer ? W2p_b  : W1p_b;
            const float* Wu  = layer ? W2u_w  : W1u_w;   const float* bu  = layer ? W2u_b  : W1u_b;
            const float* Wc  = layer ? W2c_w  : W1c_w;   const float* bc  = layer ? W2c_b  : W1c_b;
            const float* Wpp = layer ? W2pp_w : W1pp_w;  const float* bpp = layer ? W2pp_b : W1pp_b;

            hipLaunchKernelGGL((row_prop_fb<3>), gu, blk, 0, stream,
                               user_h, (const char*)poi_h, R, esw,
                               roff[0], roff[1], roff[2], eoff[0], eoff[1], eoff[2],
                               Wp, bp, NU);
            hipLaunchKernelGGL((row_prop_fb<3>), gp, blk, 0, stream,
                               poi_h, (const char*)user_h, R, esw,
                               roff[3], roff[4], roff[5], eoff[3], eoff[4], eoff[5],
                               Wu, bu, NPOI);
            hipLaunchKernelGGL((row_prop_fb<1>), gp, blk, 0, stream,
                               poi_h, (const char*)cate_h, R, esw,
                               roff[6], 0, 0, eoff[6], 0, 0, Wc, bc, NPOI);
            hipLaunchKernelGGL(copy4, dim3(4096), blk, 0, stream,
                               (const float4*)poi_h, (float4*)snap, n4);
            hipLaunchKernelGGL((row_prop_fb<1>), gp, blk, 0, stream,
                               poi_h, (const char*)snap, R, esw,
                               roff[7], 0, 0, eoff[7], 0, 0, Wpp, bpp, NPOI);
        }
    }
}

// Round 6
// 944.634 us; speedup vs baseline: 5.4290x; 1.0244x over previous
//
#include <hip/hip_runtime.h>

#define HDIM 32

typedef unsigned int uint32;

static constexpr int NU   = 500000;
static constexpr int NPOI = 200000;
static constexpr int NC   = 100;
static constexpr int E_UP = 500000;
static constexpr int E_PP = 1000000;

static constexpr int NLISTS = 8;
static constexpr int TOT_E  = 6 * E_UP + NPOI + E_PP;     // 4,200,000
static constexpr int TOT_R4 = 4 * NU + 8 * NPOI;          // 3,600,000 (all regions int4-padded)
static constexpr int TOT_R1 = 3 * NU + 5 * NPOI;          // fallback scalar layout

// ---------------------------------------------------------------------------
__global__ void zero_kernel(int* __restrict__ p, int n) {
    int i = blockIdx.x * blockDim.x + threadIdx.x;
    int stride = gridDim.x * blockDim.x;
    for (; i < n; i += stride) p[i] = 0;
}

// ---------------------------------------------------------------------------
__global__ void init_nodes(const float* __restrict__ x, int fin,
                           const float* __restrict__ W, const float* __restrict__ b,
                           const float* __restrict__ emb,
                           float* __restrict__ h, int n) {
    int idx = blockIdx.x * blockDim.x + threadIdx.x;
    if (idx >= n * HDIM) return;
    int i = idx >> 5, f = idx & 31;
    float r = b[f];
    for (int k = 0; k < fin; ++k) r += x[i * fin + k] * W[k * HDIM + f];
    r = fmaxf(r, 0.0f);
    if (emb) r += emb[idx];
    h[idx] = r;
}

// ---------------------------------------------------------------------------
__global__ void hist1(const int* __restrict__ ei_dst, int E, int* __restrict__ R,
                      int base, int stride, int slot) {
    int e = blockIdx.x * blockDim.x + threadIdx.x;
    if (e < E) atomicAdd(&R[base + ei_dst[e] * stride + slot], 1);
}

// ---------------------------------------------------------------------------
#define SCAN_T 256
#define SCAN_ELEMS 4
#define SCAN_CHUNK (SCAN_T * SCAN_ELEMS)

__global__ void scan1(int* __restrict__ R, int N, int* __restrict__ part) {
    __shared__ int lds[SCAN_T];
    int base = blockIdx.x * SCAN_CHUNK + threadIdx.x * SCAN_ELEMS;
    int v[SCAN_ELEMS]; int s = 0;
#pragma unroll
    for (int k = 0; k < SCAN_ELEMS; ++k) { int i = base + k; v[k] = (i < N) ? R[i] : 0; s += v[k]; }
    lds[threadIdx.x] = s; __syncthreads();
    for (int off = 1; off < SCAN_T; off <<= 1) {
        int t = (threadIdx.x >= off) ? lds[threadIdx.x - off] : 0;
        __syncthreads(); lds[threadIdx.x] += t; __syncthreads();
    }
    int incl = lds[threadIdx.x];
    int total = lds[SCAN_T - 1];
    int run = incl - s;
#pragma unroll
    for (int k = 0; k < SCAN_ELEMS; ++k) { int i = base + k; if (i < N) R[i] = run; run += v[k]; }
    if (threadIdx.x == 0) part[blockIdx.x] = total;
}

__global__ void scan2(int* __restrict__ part, int nb) {
    __shared__ int lds[SCAN_T];
    __shared__ int carry;
    if (threadIdx.x == 0) carry = 0;
    __syncthreads();
    for (int base = 0; base < nb; base += SCAN_T) {
        int i = base + threadIdx.x;
        int v = (i < nb) ? part[i] : 0;
        lds[threadIdx.x] = v; __syncthreads();
        for (int off = 1; off < SCAN_T; off <<= 1) {
            int t = (threadIdx.x >= off) ? lds[threadIdx.x - off] : 0;
            __syncthreads(); lds[threadIdx.x] += t; __syncthreads();
        }
        int incl = lds[threadIdx.x]; int tot = lds[SCAN_T - 1];
        if (i < nb) part[i] = carry + incl - v;
        __syncthreads();
        if (threadIdx.x == 0) carry += tot;
        __syncthreads();
    }
}

__global__ void scan3(int* __restrict__ R, int N, const int* __restrict__ part) {
    int base = blockIdx.x * SCAN_CHUNK + threadIdx.x * SCAN_ELEMS;
    int add = part[blockIdx.x];
#pragma unroll
    for (int k = 0; k < SCAN_ELEMS; ++k) { int i = base + k; if (i < N) R[i] += add; }
}

// ---------------------------------------------------------------------------
// fill: esw = {src BYTE offset (row size 1<<shift), weight bits}
__global__ void fill1(const int* __restrict__ ei, const float* __restrict__ ea,
                      int E, int* __restrict__ R, int base, int stride, int slot,
                      int shift, int2* __restrict__ esw) {
    int e = blockIdx.x * blockDim.x + threadIdx.x;
    if (e >= E) return;
    int d = ei[E + e];
    int pos = atomicAdd(&R[base + d * stride + slot], 1);
    float w = ea ? ea[e] : 1.0f;
    esw[pos] = make_int2(ei[e] << shift, __float_as_int(w));
}

// ---------------------------------------------------------------------------
__global__ __launch_bounds__(256) void transform_k(const float* __restrict__ src,
                                                   const float* __restrict__ W,
                                                   const float* __restrict__ b,
                                                   float* __restrict__ out, int n) {
    int idx = blockIdx.x * blockDim.x + threadIdx.x;
    if (idx >= n * HDIM) return;
    int f = idx & 31;
    float Wc[HDIM];
#pragma unroll
    for (int k = 0; k < HDIM; ++k) Wc[k] = W[k * HDIM + f];
    float x = src[idx];
    float r = b[f];
#pragma unroll
    for (int k = 0; k < HDIM; ++k) r += __shfl(x, k, 32) * Wc[k];
    out[idx] = r;
}

// ---------------------------------------------------------------------------
__global__ void copy4(const float4* __restrict__ src, float4* __restrict__ dst, int n4) {
    int i = blockIdx.x * blockDim.x + threadIdx.x;
    int stride = gridDim.x * blockDim.x;
    for (; i < n4; i += stride) dst[i] = src[i];
}

// ---------------------------------------------------------------------------
__device__ inline float4 ldrow_f32(const char* base, uint32 off, int lane8) {
    return ((const float4*)(base + off))[lane8];
}
__device__ inline float4 ldrow_bf16(const char* base, uint32 off, int lane8) {
    uint2 q = ((const uint2*)(base + off))[lane8];
    float4 v;
    v.x = __uint_as_float(q.x << 16);
    v.y = __uint_as_float(q.x & 0xffff0000u);
    v.z = __uint_as_float(q.y << 16);
    v.w = __uint_as_float(q.y & 0xffff0000u);
    return v;
}
__device__ inline unsigned short bf16rn(float f) {
    uint32 u = __float_as_uint(f);
    return (unsigned short)((u + 0x7fffu + ((u >> 16) & 1u)) >> 16);
}

// ---------------------------------------------------------------------------
// Merged-segment prop. 8 lanes per dst row (lane owns 4 features), 32 rows /
// 256-block. CSR region is int4-padded: R4[r] = {end0,end1,end2,end3-or-pad};
// pad slots inherit the prefix (= previous real end), so prev.w is always the
// row's start. The up-to-3 main segments are CONTIGUOUS in esw -> one loop,
// finalize (mean+relu) when j+1 hits a segment end. HASB adds a 4th segment
// (belongs) gathering from a second f32 table. EPI: fused epilogue transform
// of the updated dst row into dstT (bf16 or f32).
template<bool SRCBF16, bool HASB, bool EPI, bool EPIBF16>
__global__ __launch_bounds__(256) void prop_k(
    float4* __restrict__ dst4,
    const char* __restrict__ srcB,      // main gather table
    const char* __restrict__ srcB2,     // belongs table (f32), HASB only
    const int4* __restrict__ R4,        // region base
    const int2* __restrict__ esw,
    int eo,                             // region's first edge offset
    const float4* __restrict__ WT4, const float4* __restrict__ bT4,
    void* __restrict__ dstT, int n)
{
    __shared__ float4 Ws4[HDIM][8];
    __shared__ float4 bTs[8];
    if (EPI) {
        int t = threadIdx.x;
        { int k = t >> 3, j = t & 7; Ws4[k][j] = WT4[k * 8 + j]; }
        if (t < 8) bTs[t] = bT4[t];
        __syncthreads();
    }
    int grp = threadIdx.x >> 3, lane8 = threadIdx.x & 7;
    int r = blockIdx.x * 32 + grp;
    if (r >= n) return;

    int4 ev = R4[r];
    int s0 = (r == 0) ? eo : R4[r - 1].w;

    float4 acc = make_float4(0.f, 0.f, 0.f, 0.f);
    float4 res = make_float4(0.f, 0.f, 0.f, 0.f);
    int segs = s0;
    int zend = ev.z;
    for (int j = s0; j < zend; ++j) {
        int2 e = esw[j];
        float w = __int_as_float(e.y);
        float4 v = SRCBF16 ? ldrow_bf16(srcB, (uint32)e.x, lane8)
                           : ldrow_f32(srcB, (uint32)e.x, lane8);
        acc.x += w * v.x; acc.y += w * v.y; acc.z += w * v.z; acc.w += w * v.w;
        int j1 = j + 1;
        if ((j1 == ev.x) | (j1 == ev.y) | (j1 == ev.z)) {
            float inv = __builtin_amdgcn_rcpf((float)(j1 - segs));
            res.x += fmaxf(acc.x * inv, 0.f);
            res.y += fmaxf(acc.y * inv, 0.f);
            res.z += fmaxf(acc.z * inv, 0.f);
            res.w += fmaxf(acc.w * inv, 0.f);
            acc = make_float4(0.f, 0.f, 0.f, 0.f);
            segs = j1;
        }
    }
    int ctot = zend - s0;
    if (HASB) {
        int c2 = ev.w - ev.z;
        float4 a2 = make_float4(0.f, 0.f, 0.f, 0.f);
        for (int j = ev.z; j < ev.w; ++j) {
            int2 e = esw[j];
            float w = __int_as_float(e.y);
            float4 v = ldrow_f32(srcB2, (uint32)e.x, lane8);
            a2.x += w * v.x; a2.y += w * v.y; a2.z += w * v.z; a2.w += w * v.w;
        }
        if (c2 > 0) {
            float inv = __builtin_amdgcn_rcpf((float)c2);
            res.x += fmaxf(a2.x * inv, 0.f);
            res.y += fmaxf(a2.y * inv, 0.f);
            res.z += fmaxf(a2.z * inv, 0.f);
            res.w += fmaxf(a2.w * inv, 0.f);
        }
        ctot += c2;
    }

    float4* dp = dst4 + (size_t)r * 8 + lane8;
    float4 dv = *dp;
    if (ctot) {
        dv.x += res.x; dv.y += res.y; dv.z += res.z; dv.w += res.w;
        *dp = dv;
    }

    if (EPI) {
        float4 to = bTs[lane8];
#pragma unroll
        for (int sl = 0; sl < 8; ++sl) {
            float ux = __shfl(dv.x, sl, 8);
            float uy = __shfl(dv.y, sl, 8);
            float uz = __shfl(dv.z, sl, 8);
            float uw = __shfl(dv.w, sl, 8);
            float4 w0 = Ws4[sl * 4 + 0][lane8];
            to.x += ux * w0.x; to.y += ux * w0.y; to.z += ux * w0.z; to.w += ux * w0.w;
            float4 w1 = Ws4[sl * 4 + 1][lane8];
            to.x += uy * w1.x; to.y += uy * w1.y; to.z += uy * w1.z; to.w += uy * w1.w;
            float4 w2 = Ws4[sl * 4 + 2][lane8];
            to.x += uz * w2.x; to.y += uz * w2.y; to.z += uz * w2.z; to.w += uz * w2.w;
            float4 w3 = Ws4[sl * 4 + 3][lane8];
            to.x += uw * w3.x; to.y += uw * w3.y; to.z += uw * w3.z; to.w += uw * w3.w;
        }
        if (EPIBF16) {
            ushort4 h;
            h.x = bf16rn(to.x); h.y = bf16rn(to.y);
            h.z = bf16rn(to.z); h.w = bf16rn(to.w);
            ((ushort4*)dstT)[(size_t)r * 8 + lane8] = h;
        } else {
            ((float4*)dstT)[(size_t)r * 8 + lane8] = to;
        }
    }
}

// ---------------------------------------------------------------------------
// Fallback prop (small workspace): 32 lanes/row, in-kernel matvec, scalar CSR.
template<int NL>
__global__ __launch_bounds__(256) void row_prop_fb(
    float* __restrict__ dst, const char* __restrict__ srcB,
    const int* __restrict__ R, const int2* __restrict__ esw,
    int ro0, int ro1, int ro2, int eo0, int eo1, int eo2,
    const float* __restrict__ W, const float* __restrict__ b, int n) {
    __shared__ float Ws[HDIM * HDIM];
    for (int i = threadIdx.x; i < HDIM * HDIM; i += blockDim.x) Ws[i] = W[i];
    __syncthreads();
    int r = blockIdx.x * (blockDim.x >> 5) + (threadIdx.x >> 5);
    if (r >= n) return;
    int f = threadIdx.x & 31;
    float bf = b[f];
    float res = 0.0f;
    int ctot = 0;
#pragma unroll
    for (int l = 0; l < NL; ++l) {
        int ro = (l == 0) ? ro0 : (l == 1) ? ro1 : ro2;
        int eo = (l == 0) ? eo0 : (l == 1) ? eo1 : eo2;
        int jcur = (r == 0) ? eo : R[ro + r - 1];
        int jend = R[ro + r];
        int c = jend - jcur;
        float acc = 0.0f, t = 0.0f;
        for (int j = jcur; j < jend; ++j) {
            int2 e = esw[j];
            float w = __int_as_float(e.y);
            acc += w * ((const float*)(srcB + (size_t)(uint32)e.x))[f];
            t += w;
        }
        ctot += c;
        float rl = t * bf;
#pragma unroll
        for (int k = 0; k < HDIM; ++k) rl += __shfl(acc, k, 32) * Ws[k * HDIM + f];
        rl /= fmaxf((float)c, 1.0f);
        res += fmaxf(rl, 0.0f);
    }
    if (ctot > 0) dst[(size_t)r * HDIM + f] += res;
}

// ---------------------------------------------------------------------------
extern "C" void kernel_launch(void* const* d_in, const int* in_sizes, int n_in,
                              void* d_out, int out_size, void* d_ws, size_t ws_size,
                              hipStream_t stream) {
    const float* x_user = (const float*)d_in[0];
    const float* x_poi  = (const float*)d_in[1];
    const float* x_cate = (const float*)d_in[2];
    const float* ulw    = (const float*)d_in[3];
    const float* ulb    = (const float*)d_in[4];
    const float* plw    = (const float*)d_in[5];
    const float* plb    = (const float*)d_in[6];
    const float* clw    = (const float*)d_in[7];
    const float* clb    = (const float*)d_in[8];
    const float* W1u_w  = (const float*)d_in[9];   const float* W1u_b  = (const float*)d_in[10];
    const float* W1p_w  = (const float*)d_in[11];  const float* W1p_b  = (const float*)d_in[12];
    const float* W1c_w  = (const float*)d_in[13];  const float* W1c_b  = (const float*)d_in[14];
    const float* W1pp_w = (const float*)d_in[15];  const float* W1pp_b = (const float*)d_in[16];
    const float* W2u_w  = (const float*)d_in[17];  const float* W2u_b  = (const float*)d_in[18];
    const float* W2p_w  = (const float*)d_in[19];  const float* W2p_b  = (const float*)d_in[20];
    const float* W2c_w  = (const float*)d_in[21];  const float* W2c_b  = (const float*)d_in[22];
    const float* W2pp_w = (const float*)d_in[23];  const float* W2pp_b = (const float*)d_in[24];
    const float* cate_emb = (const float*)d_in[25];
    const int* ei_pv        = (const int*)d_in[26];
    const int* ei_mc        = (const int*)d_in[27];
    const int* ei_order     = (const int*)d_in[28];
    const int* ei_rev_pv    = (const int*)d_in[29];
    const int* ei_rev_mc    = (const int*)d_in[30];
    const int* ei_rev_order = (const int*)d_in[31];
    const int* ei_belongs   = (const int*)d_in[32];
    const int* ei_pp        = (const int*)d_in[33];
    const float* ea_pv        = (const float*)d_in[34];
    const float* ea_mc        = (const float*)d_in[35];
    const float* ea_order     = (const float*)d_in[36];
    const float* ea_rev_pv    = (const float*)d_in[37];
    const float* ea_rev_mc    = (const float*)d_in[38];
    const float* ea_rev_order = (const float*)d_in[39];
    const float* ea_pp        = (const float*)d_in[40];

    float* user_h = (float*)d_out;
    float* poi_h  = user_h + (size_t)NU * HDIM;
    float* cate_h = poi_h + (size_t)NPOI * HDIM;

    const int* eis[NLISTS] = {ei_rev_pv, ei_rev_mc, ei_rev_order,
                              ei_pv, ei_mc, ei_order, ei_belongs, ei_pp};
    const float* eas[NLISTS] = {ea_rev_pv, ea_rev_mc, ea_rev_order,
                                ea_pv, ea_mc, ea_order, nullptr, ea_pp};
    const int Es[NLISTS] = {E_UP, E_UP, E_UP, E_UP, E_UP, E_UP, NPOI, E_PP};

    dim3 blk(256);

    // new-path workspace need
    size_t need_new = ((size_t)TOT_R4 + 2 * (size_t)TOT_E + 4096) * 4   // R + esw + part
                    + (size_t)NU * HDIM * 2                              // userT bf16
                    + 2 * (size_t)NPOI * HDIM * 4                        // poiT A/B
                    + (size_t)NC * HDIM * 4;                             // cateT
    bool pret = (ws_size >= need_new);

    if (pret) {
        int*   R    = (int*)d_ws;                          // 14.4 MB
        int2*  esw  = (int2*)(R + TOT_R4);                 // 33.6 MB
        int*   part = (int*)(esw + TOT_E);                 // 16 KB
        unsigned short* userT = (unsigned short*)(part + 4096);      // 32 MB bf16
        float* poiTA = (float*)(userT + (size_t)NU * HDIM);          // 25.6 MB
        float* poiTB = poiTA + (size_t)NPOI * HDIM;                  // 25.6 MB
        float* cateT = poiTB + (size_t)NPOI * HDIM;                  // 12.8 KB

        // regions: user-rev [0,4NU) slots{pv,mc,order,pad}; poi-fwdB [4NU,+4NPOI)
        // slots{pv,mc,order,belongs}; poi-pp [4NU+4NPOI,+4NPOI) slot{pp,pad,pad,pad}
        const int BU = 0, BF = 4 * NU, BP = 4 * NU + 4 * NPOI;
        const int Lbase[NLISTS]  = {BU, BU, BU, BF, BF, BF, BF, BP};
        const int Lslot[NLISTS]  = {0, 1, 2, 0, 1, 2, 3, 0};
        const int Lshift[NLISTS] = {7, 7, 7, 6, 6, 6, 7, 7};   // src row bytes: poiT 128, userT 64
        const int EO_REV = 0, EO_FWD = 3 * E_UP, EO_PP = 6 * E_UP + NPOI;

        // ---- CSR build ----
        hipLaunchKernelGGL(zero_kernel, dim3(2048), blk, 0, stream, R, TOT_R4);
        for (int l = 0; l < NLISTS; ++l)
            hipLaunchKernelGGL(hist1, dim3((Es[l] + 255) / 256), blk, 0, stream,
                               eis[l] + Es[l], Es[l], R, Lbase[l], 4, Lslot[l]);
        int nb = (TOT_R4 + SCAN_CHUNK - 1) / SCAN_CHUNK;
        hipLaunchKernelGGL(scan1, dim3(nb), dim3(SCAN_T), 0, stream, R, TOT_R4, part);
        hipLaunchKernelGGL(scan2, dim3(1), dim3(SCAN_T), 0, stream, part, nb);
        hipLaunchKernelGGL(scan3, dim3(nb), dim3(SCAN_T), 0, stream, R, TOT_R4, part);
        for (int l = 0; l < NLISTS; ++l)
            hipLaunchKernelGGL(fill1, dim3((Es[l] + 255) / 256), blk, 0, stream,
                               eis[l], eas[l], Es[l], R, Lbase[l], 4, Lslot[l],
                               Lshift[l], esw);

        // ---- init node states ----
        hipLaunchKernelGGL(init_nodes, dim3((NU * HDIM + 255) / 256), blk, 0, stream,
                           x_user, 2, ulw, ulb, (const float*)nullptr, user_h, NU);
        hipLaunchKernelGGL(init_nodes, dim3((NPOI * HDIM + 255) / 256), blk, 0, stream,
                           x_poi, 3, plw, plb, (const float*)nullptr, poi_h, NPOI);
        hipLaunchKernelGGL(init_nodes, dim3((NC * HDIM + 255) / 256), blk, 0, stream,
                           x_cate, 1, clw, clb, cate_emb, cate_h, NC);

        dim3 g_u((NU + 31) / 32), g_p((NPOI + 31) / 32);
        dim3 gtp((NPOI * HDIM + 255) / 256), gtc((NC * HDIM + 255) / 256);

        // initial pre-transforms (f32): poiTA = poi_h@W1p+b; cateT = cate_h@W1c+b
        hipLaunchKernelGGL(transform_k, gtp, blk, 0, stream, poi_h, W1p_w, W1p_b, poiTA, NPOI);
        hipLaunchKernelGGL(transform_k, gtc, blk, 0, stream, cate_h, W1c_w, W1c_b, cateT, NC);

        // ======== layer 1 ========
        // rev3: user_h += ...; EPI -> userT = bf16(user_h @ W1u + b1u)
        hipLaunchKernelGGL((prop_k<false, false, true, true>), g_u, blk, 0, stream,
                           (float4*)user_h, (const char*)poiTA, (const char*)nullptr,
                           (const int4*)(R + BU), esw, EO_REV,
                           (const float4*)W1u_w, (const float4*)W1u_b, (void*)userT, NU);
        // fwd3+belongs: poi_h += ...; EPI -> poiTB = poi_h @ W1pp + b1pp
        hipLaunchKernelGGL((prop_k<true, true, true, false>), g_p, blk, 0, stream,
                           (float4*)poi_h, (const char*)userT, (const char*)cateT,
                           (const int4*)(R + BF), esw, EO_FWD,
                           (const float4*)W1pp_w, (const float4*)W1pp_b, (void*)poiTB, NPOI);
        // pp: poi_h += ... from poiTB; EPI -> poiTA = poi_h @ W2p + b2p (for L2 rev3)
        hipLaunchKernelGGL((prop_k<false, false, true, false>), g_p, blk, 0, stream,
                           (float4*)poi_h, (const char*)poiTB, (const char*)nullptr,
                           (const int4*)(R + BP), esw, EO_PP,
                           (const float4*)W2p_w, (const float4*)W2p_b, (void*)poiTA, NPOI);

        // ======== layer 2 ========
        hipLaunchKernelGGL(transform_k, gtc, blk, 0, stream, cate_h, W2c_w, W2c_b, cateT, NC);
        hipLaunchKernelGGL((prop_k<false, false, true, true>), g_u, blk, 0, stream,
                           (float4*)user_h, (const char*)poiTA, (const char*)nullptr,
                           (const int4*)(R + BU), esw, EO_REV,
                           (const float4*)W2u_w, (const float4*)W2u_b, (void*)userT, NU);
        hipLaunchKernelGGL((prop_k<true, true, true, false>), g_p, blk, 0, stream,
                           (float4*)poi_h, (const char*)userT, (const char*)cateT,
                           (const int4*)(R + BF), esw, EO_FWD,
                           (const float4*)W2pp_w, (const float4*)W2pp_b, (void*)poiTB, NPOI);
        hipLaunchKernelGGL((prop_k<false, false, false, false>), g_p, blk, 0, stream,
                           (float4*)poi_h, (const char*)poiTB, (const char*)nullptr,
                           (const int4*)(R + BP), esw, EO_PP,
                           (const float4*)nullptr, (const float4*)nullptr, (void*)nullptr, NPOI);
    } else {
        // ---- fallback: scalar CSR layout, 32-lane props, in-kernel matvec ----
        int*   R    = (int*)d_ws;
        int2*  esw  = (int2*)(R + TOT_R1);
        int*   part = (int*)(esw + TOT_E);
        float* snap = (float*)(part + 4096);

        const int ns[NLISTS] = {NU, NU, NU, NPOI, NPOI, NPOI, NPOI, NPOI};
        int eoff[NLISTS], roff[NLISTS];
        { int eo = 0, ro = 0;
          for (int l = 0; l < NLISTS; ++l) { eoff[l] = eo; roff[l] = ro; eo += Es[l]; ro += ns[l]; } }

        hipLaunchKernelGGL(zero_kernel, dim3(2048), blk, 0, stream, R, TOT_R1);
        for (int l = 0; l < NLISTS; ++l)
            hipLaunchKernelGGL(hist1, dim3((Es[l] + 255) / 256), blk, 0, stream,
                               eis[l] + Es[l], Es[l], R, roff[l], 1, 0);
        int nb = (TOT_R1 + SCAN_CHUNK - 1) / SCAN_CHUNK;
        hipLaunchKernelGGL(scan1, dim3(nb), dim3(SCAN_T), 0, stream, R, TOT_R1, part);
        hipLaunchKernelGGL(scan2, dim3(1), dim3(SCAN_T), 0, stream, part, nb);
        hipLaunchKernelGGL(scan3, dim3(nb), dim3(SCAN_T), 0, stream, R, TOT_R1, part);
        for (int l = 0; l < NLISTS; ++l)
            hipLaunchKernelGGL(fill1, dim3((Es[l] + 255) / 256), blk, 0, stream,
                               eis[l], eas[l], Es[l], R, roff[l], 1, 0, 7, esw);

        hipLaunchKernelGGL(init_nodes, dim3((NU * HDIM + 255) / 256), blk, 0, stream,
                           x_user, 2, ulw, ulb, (const float*)nullptr, user_h, NU);
        hipLaunchKernelGGL(init_nodes, dim3((NPOI * HDIM + 255) / 256), blk, 0, stream,
                           x_poi, 3, plw, plb, (const float*)nullptr, poi_h, NPOI);
        hipLaunchKernelGGL(init_nodes, dim3((NC * HDIM + 255) / 256), blk, 0, stream,
                           x_cate, 1, clw, clb, cate_emb, cate_h, NC);

        dim3 gu((NU + 7) / 8), gp((NPOI + 7) / 8);
        int n4 = NPOI * HDIM / 4;

        for (int layer = 0; layer < 2; ++layer) {
            const float* Wp  = layer ? W2p_w  : W1p_w;   const float* bp  = layer ? W2p_b  : W1p_b;
            const float* Wu  = layer ? W2u_w  : W1u_w;   const float* bu  = layer ? W2u_b  : W1u_b;
            const float* Wc  = layer ? W2c_w  : W1c_w;   const float* bc  = layer ? W2c_b  : W1c_b;
            const float* Wpp = layer ? W2pp_w : W1pp_w;  const float* bpp = layer ? W2pp_b : W1pp_b;

            hipLaunchKernelGGL((row_prop_fb<3>), gu, blk, 0, stream,
                               user_h, (const char*)poi_h, R, esw,
                               roff[0], roff[1], roff[2], eoff[0], eoff[1], eoff[2],
                               Wp, bp, NU);
            hipLaunchKernelGGL((row_prop_fb<3>), gp, blk, 0, stream,
                               poi_h, (const char*)user_h, R, esw,
                               roff[3], roff[4], roff[5], eoff[3], eoff[4], eoff[5],
                               Wu, bu, NPOI);
            hipLaunchKernelGGL((row_prop_fb<1>), gp, blk, 0, stream,
                               poi_h, (const char*)cate_h, R, esw,
                               roff[6], 0, 0, eoff[6], 0, 0, Wc, bc, NPOI);
            hipLaunchKernelGGL(copy4, dim3(4096), blk, 0, stream,
                               (const float4*)poi_h, (float4*)snap, n4);
            hipLaunchKernelGGL((row_prop_fb<1>), gp, blk, 0, stream,
                               poi_h, (const char*)snap, R, esw,
                               roff[7], 0, 0, eoff[7], 0, 0, Wpp, bpp, NPOI);
        }
    }
}

// Round 7
// 912.950 us; speedup vs baseline: 5.6174x; 1.0347x over previous
//
#include <hip/hip_runtime.h>

#define HDIM 32

typedef unsigned int uint32;

static constexpr int NU   = 500000;
static constexpr int NPOI = 200000;
static constexpr int NC   = 100;
static constexpr int E_UP = 500000;
static constexpr int E_PP = 1000000;

static constexpr int NLISTS = 8;
static constexpr int TOT_E  = 6 * E_UP + NPOI + E_PP;     // 4,200,000
static constexpr int TOT_R4 = 4 * NU + 8 * NPOI;          // 3,600,000 (int4-padded regions)
static constexpr int TOT_R1 = 3 * NU + 5 * NPOI;          // fallback scalar layout

// ---------------------------------------------------------------------------
__global__ void zero_kernel(int* __restrict__ p, int n) {
    int i = blockIdx.x * blockDim.x + threadIdx.x;
    int stride = gridDim.x * blockDim.x;
    for (; i < n; i += stride) p[i] = 0;
}

// ---------------------------------------------------------------------------
__global__ void init_nodes(const float* __restrict__ x, int fin,
                           const float* __restrict__ W, const float* __restrict__ b,
                           const float* __restrict__ emb,
                           float* __restrict__ h, int n) {
    int idx = blockIdx.x * blockDim.x + threadIdx.x;
    if (idx >= n * HDIM) return;
    int i = idx >> 5, f = idx & 31;
    float r = b[f];
    for (int k = 0; k < fin; ++k) r += x[i * fin + k] * W[k * HDIM + f];
    r = fmaxf(r, 0.0f);
    if (emb) r += emb[idx];
    h[idx] = r;
}

// ---------------------------------------------------------------------------
// scalar histogram (fallback path)
__global__ void hist1(const int* __restrict__ ei_dst, int E, int* __restrict__ R,
                      int base, int stride, int slot) {
    int e = blockIdx.x * blockDim.x + threadIdx.x;
    if (e < E) atomicAdd(&R[base + ei_dst[e] * stride + slot], 1);
}

// vectorized histogram: 4 edges/thread (E divisible by 4 for all lists)
__global__ void hist4(const int* __restrict__ ei_dst, int E, int* __restrict__ R,
                      int base, int slot) {
    int g = (blockIdx.x * blockDim.x + threadIdx.x) * 4;
    if (g >= E) return;
    int4 d = *(const int4*)(ei_dst + g);
    atomicAdd(&R[base + d.x * 4 + slot], 1);
    atomicAdd(&R[base + d.y * 4 + slot], 1);
    atomicAdd(&R[base + d.z * 4 + slot], 1);
    atomicAdd(&R[base + d.w * 4 + slot], 1);
}

// ---------------------------------------------------------------------------
#define SCAN_T 256
#define SCAN_ELEMS 4
#define SCAN_CHUNK (SCAN_T * SCAN_ELEMS)

__global__ void scan1(int* __restrict__ R, int N, int* __restrict__ part) {
    __shared__ int lds[SCAN_T];
    int base = blockIdx.x * SCAN_CHUNK + threadIdx.x * SCAN_ELEMS;
    int v[SCAN_ELEMS]; int s = 0;
#pragma unroll
    for (int k = 0; k < SCAN_ELEMS; ++k) { int i = base + k; v[k] = (i < N) ? R[i] : 0; s += v[k]; }
    lds[threadIdx.x] = s; __syncthreads();
    for (int off = 1; off < SCAN_T; off <<= 1) {
        int t = (threadIdx.x >= off) ? lds[threadIdx.x - off] : 0;
        __syncthreads(); lds[threadIdx.x] += t; __syncthreads();
    }
    int incl = lds[threadIdx.x];
    int total = lds[SCAN_T - 1];
    int run = incl - s;
#pragma unroll
    for (int k = 0; k < SCAN_ELEMS; ++k) { int i = base + k; if (i < N) R[i] = run; run += v[k]; }
    if (threadIdx.x == 0) part[blockIdx.x] = total;
}

__global__ void scan2(int* __restrict__ part, int nb) {
    __shared__ int lds[SCAN_T];
    __shared__ int carry;
    if (threadIdx.x == 0) carry = 0;
    __syncthreads();
    for (int base = 0; base < nb; base += SCAN_T) {
        int i = base + threadIdx.x;
        int v = (i < nb) ? part[i] : 0;
        lds[threadIdx.x] = v; __syncthreads();
        for (int off = 1; off < SCAN_T; off <<= 1) {
            int t = (threadIdx.x >= off) ? lds[threadIdx.x - off] : 0;
            __syncthreads(); lds[threadIdx.x] += t; __syncthreads();
        }
        int incl = lds[threadIdx.x]; int tot = lds[SCAN_T - 1];
        if (i < nb) part[i] = carry + incl - v;
        __syncthreads();
        if (threadIdx.x == 0) carry += tot;
        __syncthreads();
    }
}

__global__ void scan3(int* __restrict__ R, int N, const int* __restrict__ part) {
    int base = blockIdx.x * SCAN_CHUNK + threadIdx.x * SCAN_ELEMS;
    int add = part[blockIdx.x];
#pragma unroll
    for (int k = 0; k < SCAN_ELEMS; ++k) { int i = base + k; if (i < N) R[i] += add; }
}

// ---------------------------------------------------------------------------
// scalar fill (fallback path): esw = {src byte offset, weight bits}
__global__ void fill1(const int* __restrict__ ei, const float* __restrict__ ea,
                      int E, int* __restrict__ R, int base, int stride, int slot,
                      int shift, int2* __restrict__ esw) {
    int e = blockIdx.x * blockDim.x + threadIdx.x;
    if (e >= E) return;
    int d = ei[E + e];
    int pos = atomicAdd(&R[base + d * stride + slot], 1);
    float w = ea ? ea[e] : 1.0f;
    esw[pos] = make_int2(ei[e] << shift, __float_as_int(w));
}

// vectorized fill: 4 edges/thread
__global__ void fill4(const int* __restrict__ ei, const float* __restrict__ ea,
                      int E, int* __restrict__ R, int base, int slot,
                      int shift, int2* __restrict__ esw) {
    int g = (blockIdx.x * blockDim.x + threadIdx.x) * 4;
    if (g >= E) return;
    int4 s = *(const int4*)(ei + g);
    int4 d = *(const int4*)(ei + E + g);
    float4 w = ea ? *(const float4*)(ea + g) : make_float4(1.f, 1.f, 1.f, 1.f);
    int p0 = atomicAdd(&R[base + d.x * 4 + slot], 1);
    esw[p0] = make_int2(s.x << shift, __float_as_int(w.x));
    int p1 = atomicAdd(&R[base + d.y * 4 + slot], 1);
    esw[p1] = make_int2(s.y << shift, __float_as_int(w.y));
    int p2 = atomicAdd(&R[base + d.z * 4 + slot], 1);
    esw[p2] = make_int2(s.z << shift, __float_as_int(w.z));
    int p3 = atomicAdd(&R[base + d.w * 4 + slot], 1);
    esw[p3] = make_int2(s.w << shift, __float_as_int(w.w));
}

// ---------------------------------------------------------------------------
__device__ inline unsigned short bf16rn(float f) {
    uint32 u = __float_as_uint(f);
    return (unsigned short)((u + 0x7fffu + ((u >> 16) & 1u)) >> 16);
}

// f32 transform: out[i,:] = src[i,:] @ W + b
__global__ __launch_bounds__(256) void transform_k(const float* __restrict__ src,
                                                   const float* __restrict__ W,
                                                   const float* __restrict__ b,
                                                   float* __restrict__ out, int n) {
    int idx = blockIdx.x * blockDim.x + threadIdx.x;
    if (idx >= n * HDIM) return;
    int f = idx & 31;
    float Wc[HDIM];
#pragma unroll
    for (int k = 0; k < HDIM; ++k) Wc[k] = W[k * HDIM + f];
    float x = src[idx];
    float r = b[f];
#pragma unroll
    for (int k = 0; k < HDIM; ++k) r += __shfl(x, k, 32) * Wc[k];
    out[idx] = r;
}

// bf16-emitting transform
__global__ __launch_bounds__(256) void transform_bf16_k(const float* __restrict__ src,
                                                        const float* __restrict__ W,
                                                        const float* __restrict__ b,
                                                        unsigned short* __restrict__ out,
                                                        int n) {
    int idx = blockIdx.x * blockDim.x + threadIdx.x;
    if (idx >= n * HDIM) return;
    int f = idx & 31;
    float Wc[HDIM];
#pragma unroll
    for (int k = 0; k < HDIM; ++k) Wc[k] = W[k * HDIM + f];
    float x = src[idx];
    float r = b[f];
#pragma unroll
    for (int k = 0; k < HDIM; ++k) r += __shfl(x, k, 32) * Wc[k];
    out[idx] = bf16rn(r);
}

// ---------------------------------------------------------------------------
__global__ void copy4(const float4* __restrict__ src, float4* __restrict__ dst, int n4) {
    int i = blockIdx.x * blockDim.x + threadIdx.x;
    int stride = gridDim.x * blockDim.x;
    for (; i < n4; i += stride) dst[i] = src[i];
}

// ---------------------------------------------------------------------------
__device__ inline float4 ldrow_f32(const char* base, uint32 off, int lane8) {
    return ((const float4*)(base + off))[lane8];
}
__device__ inline float4 ldrow_bf16(const char* base, uint32 off, int lane8) {
    uint2 q = ((const uint2*)(base + off))[lane8];
    float4 v;
    v.x = __uint_as_float(q.x << 16);
    v.y = __uint_as_float(q.x & 0xffff0000u);
    v.z = __uint_as_float(q.y << 16);
    v.w = __uint_as_float(q.y & 0xffff0000u);
    return v;
}

// ---------------------------------------------------------------------------
// Merged-segment prop with depth-2 software pipeline. 8 lanes per dst row
// (lane owns 4 features), 32 rows per 256-block. CSR region int4-padded:
// R4[r]={end0,end1,end2,end3/pad}; prev.w is always the row's start.
// Addresses are linear in j (segments contiguous), so the gather of edge j+1
// and the esw load of edge j+2 are issued BEFORE the FMA that waits on edge
// j's gather -> one latency amortized over 2 iterations.
// HASB adds a belongs segment from a tiny f32 table. EPI: fused epilogue
// transform of the updated dst row into dstT (bf16 or f32).
template<bool SRCBF16, bool HASB, bool EPI, bool EPIBF16>
__global__ __launch_bounds__(256) void prop_k(
    float4* __restrict__ dst4,
    const char* __restrict__ srcB,      // main gather table
    const char* __restrict__ srcB2,     // belongs table (f32), HASB only
    const int4* __restrict__ R4,        // region base
    const int2* __restrict__ esw,
    int eo,                             // region's first edge offset
    const float4* __restrict__ WT4, const float4* __restrict__ bT4,
    void* __restrict__ dstT, int n)
{
    __shared__ float4 Ws4[HDIM][8];
    __shared__ float4 bTs[8];
    if (EPI) {
        int t = threadIdx.x;
        { int k = t >> 3, j = t & 7; Ws4[k][j] = WT4[k * 8 + j]; }
        if (t < 8) bTs[t] = bT4[t];
        __syncthreads();
    }
    int grp = threadIdx.x >> 3, lane8 = threadIdx.x & 7;
    int r = blockIdx.x * 32 + grp;
    if (r >= n) return;

    int4 ev = R4[r];
    int s0 = (r == 0) ? eo : R4[r - 1].w;
    int zend = ev.z;

    float4 acc = make_float4(0.f, 0.f, 0.f, 0.f);
    float4 res = make_float4(0.f, 0.f, 0.f, 0.f);
    int segs = s0;

    if (s0 < zend) {
        int last = zend - 1;
        int2 eA = esw[s0];
        int2 eB = esw[min(s0 + 1, last)];
        float4 vA = SRCBF16 ? ldrow_bf16(srcB, (uint32)eA.x, lane8)
                            : ldrow_f32 (srcB, (uint32)eA.x, lane8);
        for (int j = s0; j < zend; ++j) {
            float4 vB = SRCBF16 ? ldrow_bf16(srcB, (uint32)eB.x, lane8)
                                : ldrow_f32 (srcB, (uint32)eB.x, lane8);
            int2 eC = esw[min(j + 2, last)];
            float w = __int_as_float(eA.y);
            acc.x += w * vA.x; acc.y += w * vA.y;
            acc.z += w * vA.z; acc.w += w * vA.w;
            int j1 = j + 1;
            if ((j1 == ev.x) | (j1 == ev.y) | (j1 == ev.z)) {
                float inv = __builtin_amdgcn_rcpf((float)(j1 - segs));
                res.x += fmaxf(acc.x * inv, 0.f);
                res.y += fmaxf(acc.y * inv, 0.f);
                res.z += fmaxf(acc.z * inv, 0.f);
                res.w += fmaxf(acc.w * inv, 0.f);
                acc = make_float4(0.f, 0.f, 0.f, 0.f);
                segs = j1;
            }
            eA = eB; eB = eC; vA = vB;
        }
    }
    int ctot = zend - s0;
    if (HASB) {
        int c2 = ev.w - ev.z;
        float4 a2 = make_float4(0.f, 0.f, 0.f, 0.f);
        for (int j = ev.z; j < ev.w; ++j) {
            int2 e = esw[j];
            float w = __int_as_float(e.y);
            float4 v = ldrow_f32(srcB2, (uint32)e.x, lane8);
            a2.x += w * v.x; a2.y += w * v.y; a2.z += w * v.z; a2.w += w * v.w;
        }
        if (c2 > 0) {
            float inv = __builtin_amdgcn_rcpf((float)c2);
            res.x += fmaxf(a2.x * inv, 0.f);
            res.y += fmaxf(a2.y * inv, 0.f);
            res.z += fmaxf(a2.z * inv, 0.f);
            res.w += fmaxf(a2.w * inv, 0.f);
        }
        ctot += c2;
    }

    float4* dp = dst4 + (size_t)r * 8 + lane8;
    float4 dv = *dp;
    if (ctot) {
        dv.x += res.x; dv.y += res.y; dv.z += res.z; dv.w += res.w;
        *dp = dv;
    }

    if (EPI) {
        float4 to = bTs[lane8];
#pragma unroll
        for (int sl = 0; sl < 8; ++sl) {
            float ux = __shfl(dv.x, sl, 8);
            float uy = __shfl(dv.y, sl, 8);
            float uz = __shfl(dv.z, sl, 8);
            float uw = __shfl(dv.w, sl, 8);
            float4 w0 = Ws4[sl * 4 + 0][lane8];
            to.x += ux * w0.x; to.y += ux * w0.y; to.z += ux * w0.z; to.w += ux * w0.w;
            float4 w1 = Ws4[sl * 4 + 1][lane8];
            to.x += uy * w1.x; to.y += uy * w1.y; to.z += uy * w1.z; to.w += uy * w1.w;
            float4 w2 = Ws4[sl * 4 + 2][lane8];
            to.x += uz * w2.x; to.y += uz * w2.y; to.z += uz * w2.z; to.w += uz * w2.w;
            float4 w3 = Ws4[sl * 4 + 3][lane8];
            to.x += uw * w3.x; to.y += uw * w3.y; to.z += uw * w3.z; to.w += uw * w3.w;
        }
        if (EPIBF16) {
            ushort4 h;
            h.x = bf16rn(to.x); h.y = bf16rn(to.y);
            h.z = bf16rn(to.z); h.w = bf16rn(to.w);
            ((ushort4*)dstT)[(size_t)r * 8 + lane8] = h;
        } else {
            ((float4*)dstT)[(size_t)r * 8 + lane8] = to;
        }
    }
}

// ---------------------------------------------------------------------------
// Fallback prop (small workspace): 32 lanes/row, in-kernel matvec, scalar CSR.
template<int NL>
__global__ __launch_bounds__(256) void row_prop_fb(
    float* __restrict__ dst, const char* __restrict__ srcB,
    const int* __restrict__ R, const int2* __restrict__ esw,
    int ro0, int ro1, int ro2, int eo0, int eo1, int eo2,
    const float* __restrict__ W, const float* __restrict__ b, int n) {
    __shared__ float Ws[HDIM * HDIM];
    for (int i = threadIdx.x; i < HDIM * HDIM; i += blockDim.x) Ws[i] = W[i];
    __syncthreads();
    int r = blockIdx.x * (blockDim.x >> 5) + (threadIdx.x >> 5);
    if (r >= n) return;
    int f = threadIdx.x & 31;
    float bf = b[f];
    float res = 0.0f;
    int ctot = 0;
#pragma unroll
    for (int l = 0; l < NL; ++l) {
        int ro = (l == 0) ? ro0 : (l == 1) ? ro1 : ro2;
        int eo = (l == 0) ? eo0 : (l == 1) ? eo1 : eo2;
        int jcur = (r == 0) ? eo : R[ro + r - 1];
        int jend = R[ro + r];
        int c = jend - jcur;
        float acc = 0.0f, t = 0.0f;
        for (int j = jcur; j < jend; ++j) {
            int2 e = esw[j];
            float w = __int_as_float(e.y);
            acc += w * ((const float*)(srcB + (size_t)(uint32)e.x))[f];
            t += w;
        }
        ctot += c;
        float rl = t * bf;
#pragma unroll
        for (int k = 0; k < HDIM; ++k) rl += __shfl(acc, k, 32) * Ws[k * HDIM + f];
        rl /= fmaxf((float)c, 1.0f);
        res += fmaxf(rl, 0.0f);
    }
    if (ctot > 0) dst[(size_t)r * HDIM + f] += res;
}

// ---------------------------------------------------------------------------
extern "C" void kernel_launch(void* const* d_in, const int* in_sizes, int n_in,
                              void* d_out, int out_size, void* d_ws, size_t ws_size,
                              hipStream_t stream) {
    const float* x_user = (const float*)d_in[0];
    const float* x_poi  = (const float*)d_in[1];
    const float* x_cate = (const float*)d_in[2];
    const float* ulw    = (const float*)d_in[3];
    const float* ulb    = (const float*)d_in[4];
    const float* plw    = (const float*)d_in[5];
    const float* plb    = (const float*)d_in[6];
    const float* clw    = (const float*)d_in[7];
    const float* clb    = (const float*)d_in[8];
    const float* W1u_w  = (const float*)d_in[9];   const float* W1u_b  = (const float*)d_in[10];
    const float* W1p_w  = (const float*)d_in[11];  const float* W1p_b  = (const float*)d_in[12];
    const float* W1c_w  = (const float*)d_in[13];  const float* W1c_b  = (const float*)d_in[14];
    const float* W1pp_w = (const float*)d_in[15];  const float* W1pp_b = (const float*)d_in[16];
    const float* W2u_w  = (const float*)d_in[17];  const float* W2u_b  = (const float*)d_in[18];
    const float* W2p_w  = (const float*)d_in[19];  const float* W2p_b  = (const float*)d_in[20];
    const float* W2c_w  = (const float*)d_in[21];  const float* W2c_b  = (const float*)d_in[22];
    const float* W2pp_w = (const float*)d_in[23];  const float* W2pp_b = (const float*)d_in[24];
    const float* cate_emb = (const float*)d_in[25];
    const int* ei_pv        = (const int*)d_in[26];
    const int* ei_mc        = (const int*)d_in[27];
    const int* ei_order     = (const int*)d_in[28];
    const int* ei_rev_pv    = (const int*)d_in[29];
    const int* ei_rev_mc    = (const int*)d_in[30];
    const int* ei_rev_order = (const int*)d_in[31];
    const int* ei_belongs   = (const int*)d_in[32];
    const int* ei_pp        = (const int*)d_in[33];
    const float* ea_pv        = (const float*)d_in[34];
    const float* ea_mc        = (const float*)d_in[35];
    const float* ea_order     = (const float*)d_in[36];
    const float* ea_rev_pv    = (const float*)d_in[37];
    const float* ea_rev_mc    = (const float*)d_in[38];
    const float* ea_rev_order = (const float*)d_in[39];
    const float* ea_pp        = (const float*)d_in[40];

    float* user_h = (float*)d_out;
    float* poi_h  = user_h + (size_t)NU * HDIM;
    float* cate_h = poi_h + (size_t)NPOI * HDIM;

    const int* eis[NLISTS] = {ei_rev_pv, ei_rev_mc, ei_rev_order,
                              ei_pv, ei_mc, ei_order, ei_belongs, ei_pp};
    const float* eas[NLISTS] = {ea_rev_pv, ea_rev_mc, ea_rev_order,
                                ea_pv, ea_mc, ea_order, nullptr, ea_pp};
    const int Es[NLISTS] = {E_UP, E_UP, E_UP, E_UP, E_UP, E_UP, NPOI, E_PP};

    dim3 blk(256);

    // new-path workspace need (bf16 tables)
    size_t need_new = ((size_t)TOT_R4 + 2 * (size_t)TOT_E + 4096) * 4   // R + esw + part
                    + (size_t)NU * HDIM * 2                              // userT bf16
                    + 2 * (size_t)NPOI * HDIM * 2                        // poiTA/B bf16
                    + (size_t)NC * HDIM * 4;                             // cateT f32
    bool pret = (ws_size >= need_new);

    if (pret) {
        int*   R    = (int*)d_ws;                          // 14.4 MB
        int2*  esw  = (int2*)(R + TOT_R4);                 // 33.6 MB
        int*   part = (int*)(esw + TOT_E);                 // 16 KB
        unsigned short* userT  = (unsigned short*)(part + 4096);        // 32 MB
        unsigned short* poiTA  = userT + (size_t)NU * HDIM;             // 12.8 MB
        unsigned short* poiTB  = poiTA + (size_t)NPOI * HDIM;           // 12.8 MB
        float*          cateT  = (float*)(poiTB + (size_t)NPOI * HDIM); // 12.8 KB

        // regions: user-rev [0,4NU) slots{pv,mc,order,pad}; poi-fwdB [4NU,+4NPOI)
        // slots{pv,mc,order,belongs}; poi-pp [4NU+4NPOI,+4NPOI) slot{pp,pad,pad,pad}
        const int BU = 0, BF = 4 * NU, BP = 4 * NU + 4 * NPOI;
        const int Lbase[NLISTS]  = {BU, BU, BU, BF, BF, BF, BF, BP};
        const int Lslot[NLISTS]  = {0, 1, 2, 0, 1, 2, 3, 0};
        // src row bytes: poiTA/userT/poiTB bf16 = 64 B (shift 6); cateT f32 = 128 B (shift 7)
        const int Lshift[NLISTS] = {6, 6, 6, 6, 6, 6, 7, 6};
        const int EO_REV = 0, EO_FWD = 3 * E_UP, EO_PP = 6 * E_UP + NPOI;

        // ---- CSR build (vectorized; all E divisible by 4) ----
        hipLaunchKernelGGL(zero_kernel, dim3(2048), blk, 0, stream, R, TOT_R4);
        for (int l = 0; l < NLISTS; ++l)
            hipLaunchKernelGGL(hist4, dim3((Es[l] / 4 + 255) / 256), blk, 0, stream,
                               eis[l] + Es[l], Es[l], R, Lbase[l], Lslot[l]);
        int nb = (TOT_R4 + SCAN_CHUNK - 1) / SCAN_CHUNK;
        hipLaunchKernelGGL(scan1, dim3(nb), dim3(SCAN_T), 0, stream, R, TOT_R4, part);
        hipLaunchKernelGGL(scan2, dim3(1), dim3(SCAN_T), 0, stream, part, nb);
        hipLaunchKernelGGL(scan3, dim3(nb), dim3(SCAN_T), 0, stream, R, TOT_R4, part);
        for (int l = 0; l < NLISTS; ++l)
            hipLaunchKernelGGL(fill4, dim3((Es[l] / 4 + 255) / 256), blk, 0, stream,
                               eis[l], eas[l], Es[l], R, Lbase[l], Lslot[l],
                               Lshift[l], esw);

        // ---- init node states ----
        hipLaunchKernelGGL(init_nodes, dim3((NU * HDIM + 255) / 256), blk, 0, stream,
                           x_user, 2, ulw, ulb, (const float*)nullptr, user_h, NU);
        hipLaunchKernelGGL(init_nodes, dim3((NPOI * HDIM + 255) / 256), blk, 0, stream,
                           x_poi, 3, plw, plb, (const float*)nullptr, poi_h, NPOI);
        hipLaunchKernelGGL(init_nodes, dim3((NC * HDIM + 255) / 256), blk, 0, stream,
                           x_cate, 1, clw, clb, cate_emb, cate_h, NC);

        dim3 g_u((NU + 31) / 32), g_p((NPOI + 31) / 32);
        dim3 gtp((NPOI * HDIM + 255) / 256), gtc((NC * HDIM + 255) / 256);

        // initial pre-transforms: poiTA = bf16(poi_h@W1p+b); cateT = cate_h@W1c+b
        hipLaunchKernelGGL(transform_bf16_k, gtp, blk, 0, stream, poi_h, W1p_w, W1p_b, poiTA, NPOI);
        hipLaunchKernelGGL(transform_k, gtc, blk, 0, stream, cate_h, W1c_w, W1c_b, cateT, NC);

        // ======== layer 1 ========
        // rev3: user_h += ...; EPI -> userT = bf16(user_h @ W1u + b1u)
        hipLaunchKernelGGL((prop_k<true, false, true, true>), g_u, blk, 0, stream,
                           (float4*)user_h, (const char*)poiTA, (const char*)nullptr,
                           (const int4*)(R + BU), esw, EO_REV,
                           (const float4*)W1u_w, (const float4*)W1u_b, (void*)userT, NU);
        // fwd3+belongs: poi_h += ...; EPI -> poiTB = bf16(poi_h @ W1pp + b1pp)
        hipLaunchKernelGGL((prop_k<true, true, true, true>), g_p, blk, 0, stream,
                           (float4*)poi_h, (const char*)userT, (const char*)cateT,
                           (const int4*)(R + BF), esw, EO_FWD,
                           (const float4*)W1pp_w, (const float4*)W1pp_b, (void*)poiTB, NPOI);
        // pp: poi_h += ... from poiTB; EPI -> poiTA = bf16(poi_h @ W2p + b2p) (for L2 rev3)
        hipLaunchKernelGGL((prop_k<true, false, true, true>), g_p, blk, 0, stream,
                           (float4*)poi_h, (const char*)poiTB, (const char*)nullptr,
                           (const int4*)(R + BP), esw, EO_PP,
                           (const float4*)W2p_w, (const float4*)W2p_b, (void*)poiTA, NPOI);

        // ======== layer 2 ========
        hipLaunchKernelGGL(transform_k, gtc, blk, 0, stream, cate_h, W2c_w, W2c_b, cateT, NC);
        hipLaunchKernelGGL((prop_k<true, false, true, true>), g_u, blk, 0, stream,
                           (float4*)user_h, (const char*)poiTA, (const char*)nullptr,
                           (const int4*)(R + BU), esw, EO_REV,
                           (const float4*)W2u_w, (const float4*)W2u_b, (void*)userT, NU);
        hipLaunchKernelGGL((prop_k<true, true, true, true>), g_p, blk, 0, stream,
                           (float4*)poi_h, (const char*)userT, (const char*)cateT,
                           (const int4*)(R + BF), esw, EO_FWD,
                           (const float4*)W2pp_w, (const float4*)W2pp_b, (void*)poiTB, NPOI);
        hipLaunchKernelGGL((prop_k<true, false, false, false>), g_p, blk, 0, stream,
                           (float4*)poi_h, (const char*)poiTB, (const char*)nullptr,
                           (const int4*)(R + BP), esw, EO_PP,
                           (const float4*)nullptr, (const float4*)nullptr, (void*)nullptr, NPOI);
    } else {
        // ---- fallback: scalar CSR layout, 32-lane props, in-kernel matvec ----
        int*   R    = (int*)d_ws;
        int2*  esw  = (int2*)(R + TOT_R1);
        int*   part = (int*)(esw + TOT_E);
        float* snap = (float*)(part + 4096);

        const int ns[NLISTS] = {NU, NU, NU, NPOI, NPOI, NPOI, NPOI, NPOI};
        int eoff[NLISTS], roff[NLISTS];
        { int eo = 0, ro = 0;
          for (int l = 0; l < NLISTS; ++l) { eoff[l] = eo; roff[l] = ro; eo += Es[l]; ro += ns[l]; } }

        hipLaunchKernelGGL(zero_kernel, dim3(2048), blk, 0, stream, R, TOT_R1);
        for (int l = 0; l < NLISTS; ++l)
            hipLaunchKernelGGL(hist1, dim3((Es[l] + 255) / 256), blk, 0, stream,
                               eis[l] + Es[l], Es[l], R, roff[l], 1, 0);
        int nb = (TOT_R1 + SCAN_CHUNK - 1) / SCAN_CHUNK;
        hipLaunchKernelGGL(scan1, dim3(nb), dim3(SCAN_T), 0, stream, R, TOT_R1, part);
        hipLaunchKernelGGL(scan2, dim3(1), dim3(SCAN_T), 0, stream, part, nb);
        hipLaunchKernelGGL(scan3, dim3(nb), dim3(SCAN_T), 0, stream, R, TOT_R1, part);
        for (int l = 0; l < NLISTS; ++l)
            hipLaunchKernelGGL(fill1, dim3((Es[l] + 255) / 256), blk, 0, stream,
                               eis[l], eas[l], Es[l], R, roff[l], 1, 0, 7, esw);

        hipLaunchKernelGGL(init_nodes, dim3((NU * HDIM + 255) / 256), blk, 0, stream,
                           x_user, 2, ulw, ulb, (const float*)nullptr, user_h, NU);
        hipLaunchKernelGGL(init_nodes, dim3((NPOI * HDIM + 255) / 256), blk, 0, stream,
                           x_poi, 3, plw, plb, (const float*)nullptr, poi_h, NPOI);
        hipLaunchKernelGGL(init_nodes, dim3((NC * HDIM + 255) / 256), blk, 0, stream,
                           x_cate, 1, clw, clb, cate_emb, cate_h, NC);

        dim3 gu((NU + 7) / 8), gp((NPOI + 7) / 8);
        int n4 = NPOI * HDIM / 4;

        for (int layer = 0; layer < 2; ++layer) {
            const float* Wp  = layer ? W2p_w  : W1p_w;   const float* bp  = layer ? W2p_b  : W1p_b;
            const float* Wu  = layer ? W2u_w  : W1u_w;   const float* bu  = layer ? W2u_b  : W1u_b;
            const float* Wc  = layer ? W2c_w  : W1c_w;   const float* bc  = layer ? W2c_b  : W1c_b;
            const float* Wpp = layer ? W2pp_w : W1pp_w;  const float* bpp = layer ? W2pp_b : W1pp_b;

            hipLaunchKernelGGL((row_prop_fb<3>), gu, blk, 0, stream,
                               user_h, (const char*)poi_h, R, esw,
                               roff[0], roff[1], roff[2], eoff[0], eoff[1], eoff[2],
                               Wp, bp, NU);
            hipLaunchKernelGGL((row_prop_fb<3>), gp, blk, 0, stream,
                               poi_h, (const char*)user_h, R, esw,
                               roff[3], roff[4], roff[5], eoff[3], eoff[4], eoff[5],
                               Wu, bu, NPOI);
            hipLaunchKernelGGL((row_prop_fb<1>), gp, blk, 0, stream,
                               poi_h, (const char*)cate_h, R, esw,
                               roff[6], 0, 0, eoff[6], 0, 0, Wc, bc, NPOI);
            hipLaunchKernelGGL(copy4, dim3(4096), blk, 0, stream,
                               (const float4*)poi_h, (float4*)snap, n4);
            hipLaunchKernelGGL((row_prop_fb<1>), gp, blk, 0, stream,
                               poi_h, (const char*)snap, R, esw,
                               roff[7], 0, 0, eoff[7], 0, 0, Wpp, bpp, NPOI);
        }
    }
}

// Round 8
// 622.596 us; speedup vs baseline: 8.2371x; 1.4664x over previous
//
#include <hip/hip_runtime.h>

#define HDIM 32

typedef unsigned int uint32;

static constexpr int NU   = 500000;
static constexpr int NPOI = 200000;
static constexpr int NC   = 100;
static constexpr int E_UP = 500000;
static constexpr int E_PP = 1000000;

static constexpr int NLISTS = 8;
static constexpr int TOT_E  = 6 * E_UP + NPOI + E_PP;     // 4,200,000
static constexpr int TOT_R4 = 4 * NU + 8 * NPOI;          // 3,600,000 slots (4/row)
static constexpr int TOT_R1 = 3 * NU + 5 * NPOI;          // fallback scalar layout

static constexpr int BSH  = 13;                            // bucket = 8192 slots
static constexpr int NB   = (TOT_R4 + 8191) / 8192;        // 440 buckets
static constexpr int BCH  = 8192;                          // edges per bin chunk

// ---------------------------------------------------------------------------
__global__ void zero_kernel(int* __restrict__ p, int n) {
    int i = blockIdx.x * blockDim.x + threadIdx.x;
    int stride = gridDim.x * blockDim.x;
    for (; i < n; i += stride) p[i] = 0;
}

__global__ void copyi(const int* __restrict__ a, int* __restrict__ b, int n) {
    int i = blockIdx.x * blockDim.x + threadIdx.x;
    if (i < n) b[i] = a[i];
}

// ---------------------------------------------------------------------------
__global__ void init_nodes(const float* __restrict__ x, int fin,
                           const float* __restrict__ W, const float* __restrict__ b,
                           const float* __restrict__ emb,
                           float* __restrict__ h, int n) {
    int idx = blockIdx.x * blockDim.x + threadIdx.x;
    if (idx >= n * HDIM) return;
    int i = idx >> 5, f = idx & 31;
    float r = b[f];
    for (int k = 0; k < fin; ++k) r += x[i * fin + k] * W[k * HDIM + f];
    r = fmaxf(r, 0.0f);
    if (emb) r += emb[idx];
    h[idx] = r;
}

// ---------------------------------------------------------------------------
// ===== binned CSR build (pret path) =====
// list params; wg -> (list, chunk) via coff
struct BL {
    const int* ei[NLISTS];
    const float* ea[NLISTS];
    int E[NLISTS];
    int lbase[NLISTS];
    int lslot[NLISTS];
    int shift[NLISTS];
    int coff[NLISTS];
};

// coarse per-bucket counts (LDS-aggregated, then one atomic per bucket)
__global__ __launch_bounds__(256) void bin_count(BL P, int* __restrict__ BB) {
    __shared__ int cnt[256];
    int w = blockIdx.x;
    int l = 0;
    while (l < NLISTS - 1 && w >= P.coff[l + 1]) ++l;
    int e0 = (w - P.coff[l]) * BCH;
    int E = P.E[l];
    const int* dstp = P.ei[l] + E;
    int lbase = P.lbase[l], lslot = P.lslot[l];
    int cbase = lbase >> BSH;
    cnt[threadIdx.x] = 0;
    __syncthreads();
    int e1 = min(e0 + BCH, E);
    for (int e = e0 + threadIdx.x; e < e1; e += 256) {
        int slot = lbase + dstp[e] * 4 + lslot;
        atomicAdd(&cnt[(slot >> BSH) - cbase], 1);
    }
    __syncthreads();
    int c = cnt[threadIdx.x];
    if (c > 0) atomicAdd(&BB[cbase + threadIdx.x], c);
}

// place records into bucket staging: contiguous per-wg runs (XCD-local lines)
__global__ __launch_bounds__(256) void bin_place(BL P, int* __restrict__ Gcur,
                                                 int2* __restrict__ S2,
                                                 int* __restrict__ D) {
    __shared__ int cnt[256];
    __shared__ int cur[256];
    int w = blockIdx.x;
    int l = 0;
    while (l < NLISTS - 1 && w >= P.coff[l + 1]) ++l;
    int e0 = (w - P.coff[l]) * BCH;
    int E = P.E[l];
    const int* srcp = P.ei[l];
    const int* dstp = P.ei[l] + E;
    const float* eap = P.ea[l];
    int lbase = P.lbase[l], lslot = P.lslot[l], shift = P.shift[l];
    int cbase = lbase >> BSH;
    cnt[threadIdx.x] = 0;
    __syncthreads();
    int e1 = min(e0 + BCH, E);
    for (int e = e0 + threadIdx.x; e < e1; e += 256) {
        int slot = lbase + dstp[e] * 4 + lslot;
        atomicAdd(&cnt[(slot >> BSH) - cbase], 1);
    }
    __syncthreads();
    int c = cnt[threadIdx.x];
    if (c > 0) cur[threadIdx.x] = atomicAdd(&Gcur[cbase + threadIdx.x], c);
    __syncthreads();
    for (int e = e0 + threadIdx.x; e < e1; e += 256) {
        int slot = lbase + dstp[e] * 4 + lslot;
        int li = (slot >> BSH) - cbase;
        int g = atomicAdd(&cur[li], 1);
        float wg = eap ? eap[e] : 1.0f;
        S2[g] = make_int2(srcp[e] << shift, __float_as_int(wg));
        D[g] = slot;
    }
}

// fine pass: one wg per bucket. LDS slot-hist + scan -> coalesced R write,
// then place records into the bucket's final esw window (single-XCD L2).
__global__ __launch_bounds__(256) void csr_place(const int* __restrict__ BB,
                                                 const int2* __restrict__ S2,
                                                 const int* __restrict__ D,
                                                 int* __restrict__ R,
                                                 int2* __restrict__ esw) {
    __shared__ int cnt[8192];
    __shared__ int wpart[256];
    int b = blockIdx.x;
    int s0 = b << BSH;
    int ns = min(8192, TOT_R4 - s0);
    int j0 = BB[b], j1 = BB[b + 1];
    for (int i = threadIdx.x; i < 8192; i += 256) cnt[i] = 0;
    __syncthreads();
    for (int j = j0 + threadIdx.x; j < j1; j += 256)
        atomicAdd(&cnt[D[j] - s0], 1);
    __syncthreads();
    // exclusive scan of cnt[0..8192)
    int v[32]; int s = 0;
    int base = threadIdx.x * 32;
#pragma unroll
    for (int k = 0; k < 32; ++k) { v[k] = cnt[base + k]; s += v[k]; }
    wpart[threadIdx.x] = s;
    __syncthreads();
    for (int off = 1; off < 256; off <<= 1) {
        int t = (threadIdx.x >= off) ? wpart[threadIdx.x - off] : 0;
        __syncthreads(); wpart[threadIdx.x] += t; __syncthreads();
    }
    int run = wpart[threadIdx.x] - s;
#pragma unroll
    for (int k = 0; k < 32; ++k) { cnt[base + k] = run; run += v[k]; }
    __syncthreads();
    for (int i = threadIdx.x; i < ns; i += 256) R[s0 + i] = j0 + cnt[i];
    __syncthreads();
    for (int j = j0 + threadIdx.x; j < j1; j += 256) {
        int sl = D[j];
        int p = j0 + atomicAdd(&cnt[sl - s0], 1);
        esw[p] = S2[j];
    }
}

// ---------------------------------------------------------------------------
// ===== fallback CSR build (scalar layout) =====
__global__ void hist1(const int* __restrict__ ei_dst, int E, int* __restrict__ R,
                      int base, int stride, int slot) {
    int e = blockIdx.x * blockDim.x + threadIdx.x;
    if (e < E) atomicAdd(&R[base + ei_dst[e] * stride + slot], 1);
}

#define SCAN_T 256
#define SCAN_ELEMS 4
#define SCAN_CHUNK (SCAN_T * SCAN_ELEMS)

__global__ void scan1(int* __restrict__ R, int N, int* __restrict__ part) {
    __shared__ int lds[SCAN_T];
    int base = blockIdx.x * SCAN_CHUNK + threadIdx.x * SCAN_ELEMS;
    int v[SCAN_ELEMS]; int s = 0;
#pragma unroll
    for (int k = 0; k < SCAN_ELEMS; ++k) { int i = base + k; v[k] = (i < N) ? R[i] : 0; s += v[k]; }
    lds[threadIdx.x] = s; __syncthreads();
    for (int off = 1; off < SCAN_T; off <<= 1) {
        int t = (threadIdx.x >= off) ? lds[threadIdx.x - off] : 0;
        __syncthreads(); lds[threadIdx.x] += t; __syncthreads();
    }
    int incl = lds[threadIdx.x];
    int total = lds[SCAN_T - 1];
    int run = incl - s;
#pragma unroll
    for (int k = 0; k < SCAN_ELEMS; ++k) { int i = base + k; if (i < N) R[i] = run; run += v[k]; }
    if (threadIdx.x == 0) part[blockIdx.x] = total;
}

__global__ void scan2(int* __restrict__ part, int nb) {
    __shared__ int lds[SCAN_T];
    __shared__ int carry;
    if (threadIdx.x == 0) carry = 0;
    __syncthreads();
    for (int base = 0; base < nb; base += SCAN_T) {
        int i = base + threadIdx.x;
        int v = (i < nb) ? part[i] : 0;
        lds[threadIdx.x] = v; __syncthreads();
        for (int off = 1; off < SCAN_T; off <<= 1) {
            int t = (threadIdx.x >= off) ? lds[threadIdx.x - off] : 0;
            __syncthreads(); lds[threadIdx.x] += t; __syncthreads();
        }
        int incl = lds[threadIdx.x]; int tot = lds[SCAN_T - 1];
        if (i < nb) part[i] = carry + incl - v;
        __syncthreads();
        if (threadIdx.x == 0) carry += tot;
        __syncthreads();
    }
}

__global__ void scan3(int* __restrict__ R, int N, const int* __restrict__ part) {
    int base = blockIdx.x * SCAN_CHUNK + threadIdx.x * SCAN_ELEMS;
    int add = part[blockIdx.x];
#pragma unroll
    for (int k = 0; k < SCAN_ELEMS; ++k) { int i = base + k; if (i < N) R[i] += add; }
}

__global__ void fill1(const int* __restrict__ ei, const float* __restrict__ ea,
                      int E, int* __restrict__ R, int base, int stride, int slot,
                      int shift, int2* __restrict__ esw) {
    int e = blockIdx.x * blockDim.x + threadIdx.x;
    if (e >= E) return;
    int d = ei[E + e];
    int pos = atomicAdd(&R[base + d * stride + slot], 1);
    float w = ea ? ea[e] : 1.0f;
    esw[pos] = make_int2(ei[e] << shift, __float_as_int(w));
}

// ---------------------------------------------------------------------------
__device__ inline unsigned short bf16rn(float f) {
    uint32 u = __float_as_uint(f);
    return (unsigned short)((u + 0x7fffu + ((u >> 16) & 1u)) >> 16);
}

__global__ __launch_bounds__(256) void transform_k(const float* __restrict__ src,
                                                   const float* __restrict__ W,
                                                   const float* __restrict__ b,
                                                   float* __restrict__ out, int n) {
    int idx = blockIdx.x * blockDim.x + threadIdx.x;
    if (idx >= n * HDIM) return;
    int f = idx & 31;
    float Wc[HDIM];
#pragma unroll
    for (int k = 0; k < HDIM; ++k) Wc[k] = W[k * HDIM + f];
    float x = src[idx];
    float r = b[f];
#pragma unroll
    for (int k = 0; k < HDIM; ++k) r += __shfl(x, k, 32) * Wc[k];
    out[idx] = r;
}

__global__ __launch_bounds__(256) void transform_bf16_k(const float* __restrict__ src,
                                                        const float* __restrict__ W,
                                                        const float* __restrict__ b,
                                                        unsigned short* __restrict__ out,
                                                        int n) {
    int idx = blockIdx.x * blockDim.x + threadIdx.x;
    if (idx >= n * HDIM) return;
    int f = idx & 31;
    float Wc[HDIM];
#pragma unroll
    for (int k = 0; k < HDIM; ++k) Wc[k] = W[k * HDIM + f];
    float x = src[idx];
    float r = b[f];
#pragma unroll
    for (int k = 0; k < HDIM; ++k) r += __shfl(x, k, 32) * Wc[k];
    out[idx] = bf16rn(r);
}

// ---------------------------------------------------------------------------
__global__ void copy4(const float4* __restrict__ src, float4* __restrict__ dst, int n4) {
    int i = blockIdx.x * blockDim.x + threadIdx.x;
    int stride = gridDim.x * blockDim.x;
    for (; i < n4; i += stride) dst[i] = src[i];
}

// ---------------------------------------------------------------------------
__device__ inline float4 ldrow_f32(const char* base, uint32 off, int lane8) {
    return ((const float4*)(base + off))[lane8];
}
__device__ inline float4 ldrow_bf16(const char* base, uint32 off, int lane8) {
    uint2 q = ((const uint2*)(base + off))[lane8];
    float4 v;
    v.x = __uint_as_float(q.x << 16);
    v.y = __uint_as_float(q.x & 0xffff0000u);
    v.z = __uint_as_float(q.y << 16);
    v.w = __uint_as_float(q.y & 0xffff0000u);
    return v;
}

// ---------------------------------------------------------------------------
// Merged-segment prop, START-semantics CSR: R4[r] = {s0,s1,s2,s3} are the
// slot STARTS of row r (contiguous layout => slot l's end == slot l+1's
// start). NSEG main segments span [ev.x, zend) with boundaries ev.y/(ev.z/
// ev.w); HASB belongs segment = [ev.w, R4[r+1].x). Depth-2 software pipeline.
// EPI: fused epilogue transform of the updated dst row into dstT.
template<int NSEG, bool SRCBF16, bool HASB, bool EPI, bool EPIBF16>
__global__ __launch_bounds__(256) void prop_k(
    float4* __restrict__ dst4,
    const char* __restrict__ srcB,      // main gather table
    const char* __restrict__ srcB2,     // belongs table (f32), HASB only
    const int4* __restrict__ R4,        // region base (starts)
    const int2* __restrict__ esw,
    const float4* __restrict__ WT4, const float4* __restrict__ bT4,
    void* __restrict__ dstT, int n)
{
    __shared__ float4 Ws4[HDIM][8];
    __shared__ float4 bTs[8];
    if (EPI) {
        int t = threadIdx.x;
        { int k = t >> 3, j = t & 7; Ws4[k][j] = WT4[k * 8 + j]; }
        if (t < 8) bTs[t] = bT4[t];
        __syncthreads();
    }
    int grp = threadIdx.x >> 3, lane8 = threadIdx.x & 7;
    int r = blockIdx.x * 32 + grp;
    if (r >= n) return;

    int4 ev = R4[r];
    int s0 = ev.x;
    int zend = (NSEG == 3) ? ev.w : ev.y;

    float4 acc = make_float4(0.f, 0.f, 0.f, 0.f);
    float4 res = make_float4(0.f, 0.f, 0.f, 0.f);
    int segs = s0;

    if (s0 < zend) {
        int last = zend - 1;
        int2 eA = esw[s0];
        int2 eB = esw[min(s0 + 1, last)];
        float4 vA = SRCBF16 ? ldrow_bf16(srcB, (uint32)eA.x, lane8)
                            : ldrow_f32 (srcB, (uint32)eA.x, lane8);
        for (int j = s0; j < zend; ++j) {
            float4 vB = SRCBF16 ? ldrow_bf16(srcB, (uint32)eB.x, lane8)
                                : ldrow_f32 (srcB, (uint32)eB.x, lane8);
            int2 eC = esw[min(j + 2, last)];
            float w = __int_as_float(eA.y);
            acc.x += w * vA.x; acc.y += w * vA.y;
            acc.z += w * vA.z; acc.w += w * vA.w;
            int j1 = j + 1;
            bool fin = (j1 == ev.y) || (NSEG == 3 && ((j1 == ev.z) | (j1 == ev.w)));
            if (fin) {
                float inv = __builtin_amdgcn_rcpf((float)(j1 - segs));
                res.x += fmaxf(acc.x * inv, 0.f);
                res.y += fmaxf(acc.y * inv, 0.f);
                res.z += fmaxf(acc.z * inv, 0.f);
                res.w += fmaxf(acc.w * inv, 0.f);
                acc = make_float4(0.f, 0.f, 0.f, 0.f);
                segs = j1;
            }
            eA = eB; eB = eC; vA = vB;
        }
    }
    int ctot = zend - s0;
    if (HASB) {
        int nx = R4[r + 1].x;              // next row's first start = belongs end
        int c2 = nx - ev.w;
        float4 a2 = make_float4(0.f, 0.f, 0.f, 0.f);
        for (int j = ev.w; j < nx; ++j) {
            int2 e = esw[j];
            float w = __int_as_float(e.y);
            float4 v = ldrow_f32(srcB2, (uint32)e.x, lane8);
            a2.x += w * v.x; a2.y += w * v.y; a2.z += w * v.z; a2.w += w * v.w;
        }
        if (c2 > 0) {
            float inv = __builtin_amdgcn_rcpf((float)c2);
            res.x += fmaxf(a2.x * inv, 0.f);
            res.y += fmaxf(a2.y * inv, 0.f);
            res.z += fmaxf(a2.z * inv, 0.f);
            res.w += fmaxf(a2.w * inv, 0.f);
        }
        ctot += c2;
    }

    float4* dp = dst4 + (size_t)r * 8 + lane8;
    float4 dv = *dp;
    if (ctot) {
        dv.x += res.x; dv.y += res.y; dv.z += res.z; dv.w += res.w;
        *dp = dv;
    }

    if (EPI) {
        float4 to = bTs[lane8];
#pragma unroll
        for (int sl = 0; sl < 8; ++sl) {
            float ux = __shfl(dv.x, sl, 8);
            float uy = __shfl(dv.y, sl, 8);
            float uz = __shfl(dv.z, sl, 8);
            float uw = __shfl(dv.w, sl, 8);
            float4 w0 = Ws4[sl * 4 + 0][lane8];
            to.x += ux * w0.x; to.y += ux * w0.y; to.z += ux * w0.z; to.w += ux * w0.w;
            float4 w1 = Ws4[sl * 4 + 1][lane8];
            to.x += uy * w1.x; to.y += uy * w1.y; to.z += uy * w1.z; to.w += uy * w1.w;
            float4 w2 = Ws4[sl * 4 + 2][lane8];
            to.x += uz * w2.x; to.y += uz * w2.y; to.z += uz * w2.z; to.w += uz * w2.w;
            float4 w3 = Ws4[sl * 4 + 3][lane8];
            to.x += uw * w3.x; to.y += uw * w3.y; to.z += uw * w3.z; to.w += uw * w3.w;
        }
        if (EPIBF16) {
            ushort4 h;
            h.x = bf16rn(to.x); h.y = bf16rn(to.y);
            h.z = bf16rn(to.z); h.w = bf16rn(to.w);
            ((ushort4*)dstT)[(size_t)r * 8 + lane8] = h;
        } else {
            ((float4*)dstT)[(size_t)r * 8 + lane8] = to;
        }
    }
}

// ---------------------------------------------------------------------------
// Fallback prop (small workspace): 32 lanes/row, in-kernel matvec, scalar CSR
// with END semantics.
template<int NL>
__global__ __launch_bounds__(256) void row_prop_fb(
    float* __restrict__ dst, const char* __restrict__ srcB,
    const int* __restrict__ R, const int2* __restrict__ esw,
    int ro0, int ro1, int ro2, int eo0, int eo1, int eo2,
    const float* __restrict__ W, const float* __restrict__ b, int n) {
    __shared__ float Ws[HDIM * HDIM];
    for (int i = threadIdx.x; i < HDIM * HDIM; i += blockDim.x) Ws[i] = W[i];
    __syncthreads();
    int r = blockIdx.x * (blockDim.x >> 5) + (threadIdx.x >> 5);
    if (r >= n) return;
    int f = threadIdx.x & 31;
    float bf = b[f];
    float res = 0.0f;
    int ctot = 0;
#pragma unroll
    for (int l = 0; l < NL; ++l) {
        int ro = (l == 0) ? ro0 : (l == 1) ? ro1 : ro2;
        int eo = (l == 0) ? eo0 : (l == 1) ? eo1 : eo2;
        int jcur = (r == 0) ? eo : R[ro + r - 1];
        int jend = R[ro + r];
        int c = jend - jcur;
        float acc = 0.0f, t = 0.0f;
        for (int j = jcur; j < jend; ++j) {
            int2 e = esw[j];
            float w = __int_as_float(e.y);
            acc += w * ((const float*)(srcB + (size_t)(uint32)e.x))[f];
            t += w;
        }
        ctot += c;
        float rl = t * bf;
#pragma unroll
        for (int k = 0; k < HDIM; ++k) rl += __shfl(acc, k, 32) * Ws[k * HDIM + f];
        rl /= fmaxf((float)c, 1.0f);
        res += fmaxf(rl, 0.0f);
    }
    if (ctot > 0) dst[(size_t)r * HDIM + f] += res;
}

// ---------------------------------------------------------------------------
extern "C" void kernel_launch(void* const* d_in, const int* in_sizes, int n_in,
                              void* d_out, int out_size, void* d_ws, size_t ws_size,
                              hipStream_t stream) {
    const float* x_user = (const float*)d_in[0];
    const float* x_poi  = (const float*)d_in[1];
    const float* x_cate = (const float*)d_in[2];
    const float* ulw    = (const float*)d_in[3];
    const float* ulb    = (const float*)d_in[4];
    const float* plw    = (const float*)d_in[5];
    const float* plb    = (const float*)d_in[6];
    const float* clw    = (const float*)d_in[7];
    const float* clb    = (const float*)d_in[8];
    const float* W1u_w  = (const float*)d_in[9];   const float* W1u_b  = (const float*)d_in[10];
    const float* W1p_w  = (const float*)d_in[11];  const float* W1p_b  = (const float*)d_in[12];
    const float* W1c_w  = (const float*)d_in[13];  const float* W1c_b  = (const float*)d_in[14];
    const float* W1pp_w = (const float*)d_in[15];  const float* W1pp_b = (const float*)d_in[16];
    const float* W2u_w  = (const float*)d_in[17];  const float* W2u_b  = (const float*)d_in[18];
    const float* W2p_w  = (const float*)d_in[19];  const float* W2p_b  = (const float*)d_in[20];
    const float* W2c_w  = (const float*)d_in[21];  const float* W2c_b  = (const float*)d_in[22];
    const float* W2pp_w = (const float*)d_in[23];  const float* W2pp_b = (const float*)d_in[24];
    const float* cate_emb = (const float*)d_in[25];
    const int* ei_pv        = (const int*)d_in[26];
    const int* ei_mc        = (const int*)d_in[27];
    const int* ei_order     = (const int*)d_in[28];
    const int* ei_rev_pv    = (const int*)d_in[29];
    const int* ei_rev_mc    = (const int*)d_in[30];
    const int* ei_rev_order = (const int*)d_in[31];
    const int* ei_belongs   = (const int*)d_in[32];
    const int* ei_pp        = (const int*)d_in[33];
    const float* ea_pv        = (const float*)d_in[34];
    const float* ea_mc        = (const float*)d_in[35];
    const float* ea_order     = (const float*)d_in[36];
    const float* ea_rev_pv    = (const float*)d_in[37];
    const float* ea_rev_mc    = (const float*)d_in[38];
    const float* ea_rev_order = (const float*)d_in[39];
    const float* ea_pp        = (const float*)d_in[40];

    float* user_h = (float*)d_out;
    float* poi_h  = user_h + (size_t)NU * HDIM;
    float* cate_h = poi_h + (size_t)NPOI * HDIM;

    const int* eis[NLISTS] = {ei_rev_pv, ei_rev_mc, ei_rev_order,
                              ei_pv, ei_mc, ei_order, ei_belongs, ei_pp};
    const float* eas[NLISTS] = {ea_rev_pv, ea_rev_mc, ea_rev_order,
                                ea_pv, ea_mc, ea_order, nullptr, ea_pp};
    const int Es[NLISTS] = {E_UP, E_UP, E_UP, E_UP, E_UP, E_UP, NPOI, E_PP};

    dim3 blk(256);

    // pret-path workspace need
    size_t szR  = (size_t)(TOT_R4 + 4) * 4;
    size_t szE  = (size_t)TOT_E * 8;
    size_t szBG = 4096;                                     // BB(441)+Gcur(440)+pad
    size_t szT  = (size_t)NU * 64 + 2 * (size_t)NPOI * 64;  // 57.6 MB (>= staging 50.4)
    size_t szC  = (size_t)NC * HDIM * 4;
    size_t need_new = szR + szE + szBG + szT + szC + 256;
    bool pret = (ws_size >= need_new);

    if (pret) {
        int*  R    = (int*)d_ws;                            // (TOT_R4+4) ints
        int2* esw  = (int2*)(R + TOT_R4 + 4);               // TOT_E
        int*  BB   = (int*)(esw + TOT_E);                   // 441
        int*  Gcur = BB + 441;                              // 440
        char* Tbase = (char*)(((size_t)(Gcur + 440) + 255) & ~(size_t)255);
        unsigned short* userT = (unsigned short*)Tbase;               // 32 MB
        unsigned short* poiTA = userT + (size_t)NU * HDIM;            // 12.8 MB
        unsigned short* poiTB = poiTA + (size_t)NPOI * HDIM;          // 12.8 MB
        int2* S2 = (int2*)Tbase;                                      // alias: 33.6 MB
        int*  D  = (int*)(S2 + TOT_E);                                // alias: 16.8 MB
        float* cateT = (float*)(Tbase + szT);                         // 12.8 KB

        // regions: user-rev [0,4NU) slots{pv,mc,order,pad}; poi-fwd [4NU,+4NPOI)
        // slots{pv,mc,order,belongs}; poi-pp [4NU+4NPOI,+4NPOI) slots{pp,pad...}
        const int BU = 0, BF = 4 * NU, BP = 4 * NU + 4 * NPOI;
        BL P;
        const int Lbase[NLISTS]  = {BU, BU, BU, BF, BF, BF, BF, BP};
        const int Lslot[NLISTS]  = {0, 1, 2, 0, 1, 2, 3, 0};
        const int Lshift[NLISTS] = {6, 6, 6, 6, 6, 6, 7, 6};  // bf16 rows 64B, cateT 128B
        int co = 0;
        for (int l = 0; l < NLISTS; ++l) {
            P.ei[l] = eis[l]; P.ea[l] = eas[l]; P.E[l] = Es[l];
            P.lbase[l] = Lbase[l]; P.lslot[l] = Lslot[l]; P.shift[l] = Lshift[l];
            P.coff[l] = co;
            co += (Es[l] + BCH - 1) / BCH;
        }
        int nwg = co;

        // ---- binned CSR build ----
        hipLaunchKernelGGL(zero_kernel, dim3(4), blk, 0, stream, BB, 881);
        hipLaunchKernelGGL(bin_count, dim3(nwg), blk, 0, stream, P, BB);
        hipLaunchKernelGGL(scan2, dim3(1), dim3(SCAN_T), 0, stream, BB, 441);
        hipLaunchKernelGGL(copyi, dim3(2), blk, 0, stream, BB, Gcur, 440);
        hipLaunchKernelGGL(bin_place, dim3(nwg), blk, 0, stream, P, Gcur, S2, D);
        hipLaunchKernelGGL(csr_place, dim3(NB), blk, 0, stream, BB, S2, D, R, esw);

        // ---- init node states ----
        hipLaunchKernelGGL(init_nodes, dim3((NU * HDIM + 255) / 256), blk, 0, stream,
                           x_user, 2, ulw, ulb, (const float*)nullptr, user_h, NU);
        hipLaunchKernelGGL(init_nodes, dim3((NPOI * HDIM + 255) / 256), blk, 0, stream,
                           x_poi, 3, plw, plb, (const float*)nullptr, poi_h, NPOI);
        hipLaunchKernelGGL(init_nodes, dim3((NC * HDIM + 255) / 256), blk, 0, stream,
                           x_cate, 1, clw, clb, cate_emb, cate_h, NC);

        dim3 g_u((NU + 31) / 32), g_p((NPOI + 31) / 32);
        dim3 gtp((NPOI * HDIM + 255) / 256), gtc((NC * HDIM + 255) / 256);

        // initial pre-transforms
        hipLaunchKernelGGL(transform_bf16_k, gtp, blk, 0, stream, poi_h, W1p_w, W1p_b, poiTA, NPOI);
        hipLaunchKernelGGL(transform_k, gtc, blk, 0, stream, cate_h, W1c_w, W1c_b, cateT, NC);

        // ======== layer 1 ========
        hipLaunchKernelGGL((prop_k<3, true, false, true, true>), g_u, blk, 0, stream,
                           (float4*)user_h, (const char*)poiTA, (const char*)nullptr,
                           (const int4*)(R + BU), esw,
                           (const float4*)W1u_w, (const float4*)W1u_b, (void*)userT, NU);
        hipLaunchKernelGGL((prop_k<3, true, true, true, true>), g_p, blk, 0, stream,
                           (float4*)poi_h, (const char*)userT, (const char*)cateT,
                           (const int4*)(R + BF), esw,
                           (const float4*)W1pp_w, (const float4*)W1pp_b, (void*)poiTB, NPOI);
        hipLaunchKernelGGL((prop_k<1, true, false, true, true>), g_p, blk, 0, stream,
                           (float4*)poi_h, (const char*)poiTB, (const char*)nullptr,
                           (const int4*)(R + BP), esw,
                           (const float4*)W2p_w, (const float4*)W2p_b, (void*)poiTA, NPOI);

        // ======== layer 2 ========
        hipLaunchKernelGGL(transform_k, gtc, blk, 0, stream, cate_h, W2c_w, W2c_b, cateT, NC);
        hipLaunchKernelGGL((prop_k<3, true, false, true, true>), g_u, blk, 0, stream,
                           (float4*)user_h, (const char*)poiTA, (const char*)nullptr,
                           (const int4*)(R + BU), esw,
                           (const float4*)W2u_w, (const float4*)W2u_b, (void*)userT, NU);
        hipLaunchKernelGGL((prop_k<3, true, true, true, true>), g_p, blk, 0, stream,
                           (float4*)poi_h, (const char*)userT, (const char*)cateT,
                           (const int4*)(R + BF), esw,
                           (const float4*)W2pp_w, (const float4*)W2pp_b, (void*)poiTB, NPOI);
        hipLaunchKernelGGL((prop_k<1, true, false, false, false>), g_p, blk, 0, stream,
                           (float4*)poi_h, (const char*)poiTB, (const char*)nullptr,
                           (const int4*)(R + BP), esw,
                           (const float4*)nullptr, (const float4*)nullptr, (void*)nullptr, NPOI);
    } else {
        // ---- fallback: scalar CSR layout, 32-lane props, in-kernel matvec ----
        int*   R    = (int*)d_ws;
        int2*  esw  = (int2*)(R + TOT_R1);
        int*   part = (int*)(esw + TOT_E);
        float* snap = (float*)(part + 4096);

        const int ns[NLISTS] = {NU, NU, NU, NPOI, NPOI, NPOI, NPOI, NPOI};
        int eoff[NLISTS], roff[NLISTS];
        { int eo = 0, ro = 0;
          for (int l = 0; l < NLISTS; ++l) { eoff[l] = eo; roff[l] = ro; eo += Es[l]; ro += ns[l]; } }

        hipLaunchKernelGGL(zero_kernel, dim3(2048), blk, 0, stream, R, TOT_R1);
        for (int l = 0; l < NLISTS; ++l)
            hipLaunchKernelGGL(hist1, dim3((Es[l] + 255) / 256), blk, 0, stream,
                               eis[l] + Es[l], Es[l], R, roff[l], 1, 0);
        int nb = (TOT_R1 + SCAN_CHUNK - 1) / SCAN_CHUNK;
        hipLaunchKernelGGL(scan1, dim3(nb), dim3(SCAN_T), 0, stream, R, TOT_R1, part);
        hipLaunchKernelGGL(scan2, dim3(1), dim3(SCAN_T), 0, stream, part, nb);
        hipLaunchKernelGGL(scan3, dim3(nb), dim3(SCAN_T), 0, stream, R, TOT_R1, part);
        for (int l = 0; l < NLISTS; ++l)
            hipLaunchKernelGGL(fill1, dim3((Es[l] + 255) / 256), blk, 0, stream,
                               eis[l], eas[l], Es[l], R, roff[l], 1, 0, 7, esw);

        hipLaunchKernelGGL(init_nodes, dim3((NU * HDIM + 255) / 256), blk, 0, stream,
                           x_user, 2, ulw, ulb, (const float*)nullptr, user_h, NU);
        hipLaunchKernelGGL(init_nodes, dim3((NPOI * HDIM + 255) / 256), blk, 0, stream,
                           x_poi, 3, plw, plb, (const float*)nullptr, poi_h, NPOI);
        hipLaunchKernelGGL(init_nodes, dim3((NC * HDIM + 255) / 256), blk, 0, stream,
                           x_cate, 1, clw, clb, cate_emb, cate_h, NC);

        dim3 gu((NU + 7) / 8), gp((NPOI + 7) / 8);
        int n4 = NPOI * HDIM / 4;

        for (int layer = 0; layer < 2; ++layer) {
            const float* Wp  = layer ? W2p_w  : W1p_w;   const float* bp  = layer ? W2p_b  : W1p_b;
            const float* Wu  = layer ? W2u_w  : W1u_w;   const float* bu  = layer ? W2u_b  : W1u_b;
            const float* Wc  = layer ? W2c_w  : W1c_w;   const float* bc  = layer ? W2c_b  : W1c_b;
            const float* Wpp = layer ? W2pp_w : W1pp_w;  const float* bpp = layer ? W2pp_b : W1pp_b;

            hipLaunchKernelGGL((row_prop_fb<3>), gu, blk, 0, stream,
                               user_h, (const char*)poi_h, R, esw,
                               roff[0], roff[1], roff[2], eoff[0], eoff[1], eoff[2],
                               Wp, bp, NU);
            hipLaunchKernelGGL((row_prop_fb<3>), gp, blk, 0, stream,
                               poi_h, (const char*)user_h, R, esw,
                               roff[3], roff[4], roff[5], eoff[3], eoff[4], eoff[5],
                               Wu, bu, NPOI);
            hipLaunchKernelGGL((row_prop_fb<1>), gp, blk, 0, stream,
                               poi_h, (const char*)cate_h, R, esw,
                               roff[6], 0, 0, eoff[6], 0, 0, Wc, bc, NPOI);
            hipLaunchKernelGGL(copy4, dim3(4096), blk, 0, stream,
                               (const float4*)poi_h, (float4*)snap, n4);
            hipLaunchKernelGGL((row_prop_fb<1>), gp, blk, 0, stream,
                               poi_h, (const char*)snap, R, esw,
                               roff[7], 0, 0, eoff[7], 0, 0, Wpp, bpp, NPOI);
        }
    }
}

// Round 9
// 599.137 us; speedup vs baseline: 8.5596x; 1.0392x over previous
//
#include <hip/hip_runtime.h>

#define HDIM 32

typedef unsigned int uint32;

static constexpr int NU   = 500000;
static constexpr int NPOI = 200000;
static constexpr int NC   = 100;
static constexpr int E_UP = 500000;
static constexpr int E_PP = 1000000;

static constexpr int NLISTS = 8;
static constexpr int TOT_E  = 6 * E_UP + NPOI + E_PP;     // 4,200,000
static constexpr int TOT_R4 = 4 * NU + 8 * NPOI;          // 3,600,000 slots (4/row)
static constexpr int TOT_R1 = 3 * NU + 5 * NPOI;          // fallback scalar layout

static constexpr int BSH  = 12;                            // bucket = 4096 slots
static constexpr int BSZ  = 1 << BSH;
static constexpr int NB   = (TOT_R4 + BSZ - 1) / BSZ;      // 879 buckets
static constexpr int CNTN = 512;                           // max buckets per region
static constexpr int BCH  = 2048;                          // edges per bin chunk

// ---------------------------------------------------------------------------
__global__ void zero_kernel(int* __restrict__ p, int n) {
    int i = blockIdx.x * blockDim.x + threadIdx.x;
    int stride = gridDim.x * blockDim.x;
    for (; i < n; i += stride) p[i] = 0;
}

__global__ void copyi(const int* __restrict__ a, int* __restrict__ b, int n) {
    int i = blockIdx.x * blockDim.x + threadIdx.x;
    if (i < n) b[i] = a[i];
}

// ---------------------------------------------------------------------------
__global__ void init_nodes(const float* __restrict__ x, int fin,
                           const float* __restrict__ W, const float* __restrict__ b,
                           const float* __restrict__ emb,
                           float* __restrict__ h, int n) {
    int idx = blockIdx.x * blockDim.x + threadIdx.x;
    if (idx >= n * HDIM) return;
    int i = idx >> 5, f = idx & 31;
    float r = b[f];
    for (int k = 0; k < fin; ++k) r += x[i * fin + k] * W[k * HDIM + f];
    r = fmaxf(r, 0.0f);
    if (emb) r += emb[idx];
    h[idx] = r;
}

// ---------------------------------------------------------------------------
// ===== binned CSR build (pret path) =====
struct BL {
    const int* ei[NLISTS];
    const float* ea[NLISTS];
    int E[NLISTS];
    int lbase[NLISTS];
    int lslot[NLISTS];
    int shift[NLISTS];
    int coff[NLISTS];
};

// coarse per-bucket counts (LDS-aggregated, then one atomic per bucket)
__global__ __launch_bounds__(256) void bin_count(BL P, int* __restrict__ BB) {
    __shared__ int cnt[CNTN];
    int w = blockIdx.x;
    int l = 0;
    while (l < NLISTS - 1 && w >= P.coff[l + 1]) ++l;
    int e0 = (w - P.coff[l]) * BCH;
    int E = P.E[l];
    const int* dstp = P.ei[l] + E;
    int lbase = P.lbase[l], lslot = P.lslot[l];
    int cbase = lbase >> BSH;
    for (int i = threadIdx.x; i < CNTN; i += 256) cnt[i] = 0;
    __syncthreads();
    int e1 = min(e0 + BCH, E);
    for (int e = e0 + threadIdx.x; e < e1; e += 256) {
        int slot = lbase + dstp[e] * 4 + lslot;
        atomicAdd(&cnt[(slot >> BSH) - cbase], 1);
    }
    __syncthreads();
    for (int i = threadIdx.x; i < CNTN; i += 256) {
        int c = cnt[i];
        if (c > 0) atomicAdd(&BB[cbase + i], c);
    }
}

// single-pass placement: register-cached edges; the counting atomicAdd's
// return value IS the within-(wg,bucket) rank -> no second LDS-atomic pass.
// Runs are contiguous per wg per bucket -> write lines fill XCD-locally.
__global__ __launch_bounds__(256) void bin_place(BL P, int* __restrict__ Gcur,
                                                 int2* __restrict__ S2,
                                                 int* __restrict__ D) {
    __shared__ int cnt[CNTN];
    __shared__ int cur[CNTN];
    int w = blockIdx.x;
    int l = 0;
    while (l < NLISTS - 1 && w >= P.coff[l + 1]) ++l;
    int e0 = (w - P.coff[l]) * BCH;
    int E = P.E[l];
    const int* srcp = P.ei[l];
    const int* dstp = P.ei[l] + E;
    const float* eap = P.ea[l];
    int lbase = P.lbase[l], lslot = P.lslot[l], shift = P.shift[l];
    int cbase = lbase >> BSH;
    for (int i = threadIdx.x; i < CNTN; i += 256) cnt[i] = 0;
    __syncthreads();
    int e1 = min(e0 + BCH, E);

    int slot_[8], my_[8], sw_[8], wb_[8];
    bool ok_[8];
#pragma unroll
    for (int k = 0; k < 8; ++k) {
        int e = e0 + k * 256 + threadIdx.x;
        ok_[k] = (e < e1);
        if (ok_[k]) {
            slot_[k] = lbase + dstp[e] * 4 + lslot;
            sw_[k] = srcp[e] << shift;
            wb_[k] = eap ? __float_as_int(eap[e]) : __float_as_int(1.0f);
            my_[k] = atomicAdd(&cnt[(slot_[k] >> BSH) - cbase], 1);
        }
    }
    __syncthreads();
    for (int i = threadIdx.x; i < CNTN; i += 256) {
        int c = cnt[i];
        cur[i] = (c > 0) ? atomicAdd(&Gcur[cbase + i], c) : 0;
    }
    __syncthreads();
#pragma unroll
    for (int k = 0; k < 8; ++k) {
        if (ok_[k]) {
            int g = cur[(slot_[k] >> BSH) - cbase] + my_[k];
            S2[g] = make_int2(sw_[k], wb_[k]);
            D[g] = slot_[k];
        }
    }
}

// fine pass: one wg per bucket. LDS slot-hist + scan -> coalesced R write,
// then place records into the bucket's final esw window (single-XCD L2).
__global__ __launch_bounds__(256) void csr_place(const int* __restrict__ BB,
                                                 const int2* __restrict__ S2,
                                                 const int* __restrict__ D,
                                                 int* __restrict__ R,
                                                 int2* __restrict__ esw) {
    __shared__ int cnt[BSZ];
    __shared__ int wpart[256];
    int b = blockIdx.x;
    int s0 = b << BSH;
    int ns = min(BSZ, TOT_R4 - s0);
    int j0 = BB[b], j1 = BB[b + 1];
    for (int i = threadIdx.x; i < BSZ; i += 256) cnt[i] = 0;
    __syncthreads();
    for (int j = j0 + threadIdx.x; j < j1; j += 256)
        atomicAdd(&cnt[D[j] - s0], 1);
    __syncthreads();
    // exclusive scan of cnt[0..BSZ)
    int v[16]; int s = 0;
    int base = threadIdx.x * 16;
#pragma unroll
    for (int k = 0; k < 16; ++k) { v[k] = cnt[base + k]; s += v[k]; }
    wpart[threadIdx.x] = s;
    __syncthreads();
    for (int off = 1; off < 256; off <<= 1) {
        int t = (threadIdx.x >= off) ? wpart[threadIdx.x - off] : 0;
        __syncthreads(); wpart[threadIdx.x] += t; __syncthreads();
    }
    int run = wpart[threadIdx.x] - s;
#pragma unroll
    for (int k = 0; k < 16; ++k) { cnt[base + k] = run; run += v[k]; }
    __syncthreads();
    for (int i = threadIdx.x; i < ns; i += 256) R[s0 + i] = j0 + cnt[i];
    __syncthreads();
    for (int j = j0 + threadIdx.x; j < j1; j += 256) {
        int sl = D[j];
        int p = j0 + atomicAdd(&cnt[sl - s0], 1);
        esw[p] = S2[j];
    }
}

// ---------------------------------------------------------------------------
// ===== fallback CSR build (scalar layout) =====
__global__ void hist1(const int* __restrict__ ei_dst, int E, int* __restrict__ R,
                      int base, int stride, int slot) {
    int e = blockIdx.x * blockDim.x + threadIdx.x;
    if (e < E) atomicAdd(&R[base + ei_dst[e] * stride + slot], 1);
}

#define SCAN_T 256
#define SCAN_ELEMS 4
#define SCAN_CHUNK (SCAN_T * SCAN_ELEMS)

__global__ void scan1(int* __restrict__ R, int N, int* __restrict__ part) {
    __shared__ int lds[SCAN_T];
    int base = blockIdx.x * SCAN_CHUNK + threadIdx.x * SCAN_ELEMS;
    int v[SCAN_ELEMS]; int s = 0;
#pragma unroll
    for (int k = 0; k < SCAN_ELEMS; ++k) { int i = base + k; v[k] = (i < N) ? R[i] : 0; s += v[k]; }
    lds[threadIdx.x] = s; __syncthreads();
    for (int off = 1; off < SCAN_T; off <<= 1) {
        int t = (threadIdx.x >= off) ? lds[threadIdx.x - off] : 0;
        __syncthreads(); lds[threadIdx.x] += t; __syncthreads();
    }
    int incl = lds[threadIdx.x];
    int total = lds[SCAN_T - 1];
    int run = incl - s;
#pragma unroll
    for (int k = 0; k < SCAN_ELEMS; ++k) { int i = base + k; if (i < N) R[i] = run; run += v[k]; }
    if (threadIdx.x == 0) part[blockIdx.x] = total;
}

__global__ void scan2(int* __restrict__ part, int nb) {
    __shared__ int lds[SCAN_T];
    __shared__ int carry;
    if (threadIdx.x == 0) carry = 0;
    __syncthreads();
    for (int base = 0; base < nb; base += SCAN_T) {
        int i = base + threadIdx.x;
        int v = (i < nb) ? part[i] : 0;
        lds[threadIdx.x] = v; __syncthreads();
        for (int off = 1; off < SCAN_T; off <<= 1) {
            int t = (threadIdx.x >= off) ? lds[threadIdx.x - off] : 0;
            __syncthreads(); lds[threadIdx.x] += t; __syncthreads();
        }
        int incl = lds[threadIdx.x]; int tot = lds[SCAN_T - 1];
        if (i < nb) part[i] = carry + incl - v;
        __syncthreads();
        if (threadIdx.x == 0) carry += tot;
        __syncthreads();
    }
}

__global__ void scan3(int* __restrict__ R, int N, const int* __restrict__ part) {
    int base = blockIdx.x * SCAN_CHUNK + threadIdx.x * SCAN_ELEMS;
    int add = part[blockIdx.x];
#pragma unroll
    for (int k = 0; k < SCAN_ELEMS; ++k) { int i = base + k; if (i < N) R[i] += add; }
}

__global__ void fill1(const int* __restrict__ ei, const float* __restrict__ ea,
                      int E, int* __restrict__ R, int base, int stride, int slot,
                      int shift, int2* __restrict__ esw) {
    int e = blockIdx.x * blockDim.x + threadIdx.x;
    if (e >= E) return;
    int d = ei[E + e];
    int pos = atomicAdd(&R[base + d * stride + slot], 1);
    float w = ea ? ea[e] : 1.0f;
    esw[pos] = make_int2(ei[e] << shift, __float_as_int(w));
}

// ---------------------------------------------------------------------------
__device__ inline unsigned short bf16rn(float f) {
    uint32 u = __float_as_uint(f);
    return (unsigned short)((u + 0x7fffu + ((u >> 16) & 1u)) >> 16);
}

__global__ __launch_bounds__(256) void transform_k(const float* __restrict__ src,
                                                   const float* __restrict__ W,
                                                   const float* __restrict__ b,
                                                   float* __restrict__ out, int n) {
    int idx = blockIdx.x * blockDim.x + threadIdx.x;
    if (idx >= n * HDIM) return;
    int f = idx & 31;
    float Wc[HDIM];
#pragma unroll
    for (int k = 0; k < HDIM; ++k) Wc[k] = W[k * HDIM + f];
    float x = src[idx];
    float r = b[f];
#pragma unroll
    for (int k = 0; k < HDIM; ++k) r += __shfl(x, k, 32) * Wc[k];
    out[idx] = r;
}

__global__ __launch_bounds__(256) void transform_bf16_k(const float* __restrict__ src,
                                                        const float* __restrict__ W,
                                                        const float* __restrict__ b,
                                                        unsigned short* __restrict__ out,
                                                        int n) {
    int idx = blockIdx.x * blockDim.x + threadIdx.x;
    if (idx >= n * HDIM) return;
    int f = idx & 31;
    float Wc[HDIM];
#pragma unroll
    for (int k = 0; k < HDIM; ++k) Wc[k] = W[k * HDIM + f];
    float x = src[idx];
    float r = b[f];
#pragma unroll
    for (int k = 0; k < HDIM; ++k) r += __shfl(x, k, 32) * Wc[k];
    out[idx] = bf16rn(r);
}

// ---------------------------------------------------------------------------
__global__ void copy4(const float4* __restrict__ src, float4* __restrict__ dst, int n4) {
    int i = blockIdx.x * blockDim.x + threadIdx.x;
    int stride = gridDim.x * blockDim.x;
    for (; i < n4; i += stride) dst[i] = src[i];
}

// ---------------------------------------------------------------------------
__device__ inline float4 ldrow_f32(const char* base, uint32 off, int lane8) {
    return ((const float4*)(base + off))[lane8];
}
__device__ inline float4 ldrow_bf16(const char* base, uint32 off, int lane8) {
    uint2 q = ((const uint2*)(base + off))[lane8];
    float4 v;
    v.x = __uint_as_float(q.x << 16);
    v.y = __uint_as_float(q.x & 0xffff0000u);
    v.z = __uint_as_float(q.y << 16);
    v.w = __uint_as_float(q.y & 0xffff0000u);
    return v;
}

// ---------------------------------------------------------------------------
// Merged-segment prop, START-semantics CSR: R4[r] = {s0,s1,s2,s3} = slot
// starts of row r. NSEG main segments span [ev.x, zend); HASB belongs
// segment = [ev.w, R4[r+1].x). Depth-2 software pipeline. EPI: fused
// epilogue transform of the updated dst row into dstT.
template<int NSEG, bool SRCBF16, bool HASB, bool EPI, bool EPIBF16>
__global__ __launch_bounds__(256) void prop_k(
    float4* __restrict__ dst4,
    const char* __restrict__ srcB,
    const char* __restrict__ srcB2,
    const int4* __restrict__ R4,
    const int2* __restrict__ esw,
    const float4* __restrict__ WT4, const float4* __restrict__ bT4,
    void* __restrict__ dstT, int n)
{
    __shared__ float4 Ws4[HDIM][8];
    __shared__ float4 bTs[8];
    if (EPI) {
        int t = threadIdx.x;
        { int k = t >> 3, j = t & 7; Ws4[k][j] = WT4[k * 8 + j]; }
        if (t < 8) bTs[t] = bT4[t];
        __syncthreads();
    }
    int grp = threadIdx.x >> 3, lane8 = threadIdx.x & 7;
    int r = blockIdx.x * 32 + grp;
    if (r >= n) return;

    int4 ev = R4[r];
    int s0 = ev.x;
    int zend = (NSEG == 3) ? ev.w : ev.y;

    float4 acc = make_float4(0.f, 0.f, 0.f, 0.f);
    float4 res = make_float4(0.f, 0.f, 0.f, 0.f);
    int segs = s0;

    if (s0 < zend) {
        int last = zend - 1;
        int2 eA = esw[s0];
        int2 eB = esw[min(s0 + 1, last)];
        float4 vA = SRCBF16 ? ldrow_bf16(srcB, (uint32)eA.x, lane8)
                            : ldrow_f32 (srcB, (uint32)eA.x, lane8);
        for (int j = s0; j < zend; ++j) {
            float4 vB = SRCBF16 ? ldrow_bf16(srcB, (uint32)eB.x, lane8)
                                : ldrow_f32 (srcB, (uint32)eB.x, lane8);
            int2 eC = esw[min(j + 2, last)];
            float w = __int_as_float(eA.y);
            acc.x += w * vA.x; acc.y += w * vA.y;
            acc.z += w * vA.z; acc.w += w * vA.w;
            int j1 = j + 1;
            bool fin = (j1 == ev.y) || (NSEG == 3 && ((j1 == ev.z) | (j1 == ev.w)));
            if (fin) {
                float inv = __builtin_amdgcn_rcpf((float)(j1 - segs));
                res.x += fmaxf(acc.x * inv, 0.f);
                res.y += fmaxf(acc.y * inv, 0.f);
                res.z += fmaxf(acc.z * inv, 0.f);
                res.w += fmaxf(acc.w * inv, 0.f);
                acc = make_float4(0.f, 0.f, 0.f, 0.f);
                segs = j1;
            }
            eA = eB; eB = eC; vA = vB;
        }
    }
    int ctot = zend - s0;
    if (HASB) {
        int nx = R4[r + 1].x;
        int c2 = nx - ev.w;
        float4 a2 = make_float4(0.f, 0.f, 0.f, 0.f);
        for (int j = ev.w; j < nx; ++j) {
            int2 e = esw[j];
            float w = __int_as_float(e.y);
            float4 v = ldrow_f32(srcB2, (uint32)e.x, lane8);
            a2.x += w * v.x; a2.y += w * v.y; a2.z += w * v.z; a2.w += w * v.w;
        }
        if (c2 > 0) {
            float inv = __builtin_amdgcn_rcpf((float)c2);
            res.x += fmaxf(a2.x * inv, 0.f);
            res.y += fmaxf(a2.y * inv, 0.f);
            res.z += fmaxf(a2.z * inv, 0.f);
            res.w += fmaxf(a2.w * inv, 0.f);
        }
        ctot += c2;
    }

    float4* dp = dst4 + (size_t)r * 8 + lane8;
    float4 dv = *dp;
    if (ctot) {
        dv.x += res.x; dv.y += res.y; dv.z += res.z; dv.w += res.w;
        *dp = dv;
    }

    if (EPI) {
        float4 to = bTs[lane8];
#pragma unroll
        for (int sl = 0; sl < 8; ++sl) {
            float ux = __shfl(dv.x, sl, 8);
            float uy = __shfl(dv.y, sl, 8);
            float uz = __shfl(dv.z, sl, 8);
            float uw = __shfl(dv.w, sl, 8);
            float4 w0 = Ws4[sl * 4 + 0][lane8];
            to.x += ux * w0.x; to.y += ux * w0.y; to.z += ux * w0.z; to.w += ux * w0.w;
            float4 w1 = Ws4[sl * 4 + 1][lane8];
            to.x += uy * w1.x; to.y += uy * w1.y; to.z += uy * w1.z; to.w += uy * w1.w;
            float4 w2 = Ws4[sl * 4 + 2][lane8];
            to.x += uz * w2.x; to.y += uz * w2.y; to.z += uz * w2.z; to.w += uz * w2.w;
            float4 w3 = Ws4[sl * 4 + 3][lane8];
            to.x += uw * w3.x; to.y += uw * w3.y; to.z += uw * w3.z; to.w += uw * w3.w;
        }
        if (EPIBF16) {
            ushort4 h;
            h.x = bf16rn(to.x); h.y = bf16rn(to.y);
            h.z = bf16rn(to.z); h.w = bf16rn(to.w);
            ((ushort4*)dstT)[(size_t)r * 8 + lane8] = h;
        } else {
            ((float4*)dstT)[(size_t)r * 8 + lane8] = to;
        }
    }
}

// ---------------------------------------------------------------------------
// Fallback prop (small workspace): 32 lanes/row, in-kernel matvec, scalar CSR
// with END semantics.
template<int NL>
__global__ __launch_bounds__(256) void row_prop_fb(
    float* __restrict__ dst, const char* __restrict__ srcB,
    const int* __restrict__ R, const int2* __restrict__ esw,
    int ro0, int ro1, int ro2, int eo0, int eo1, int eo2,
    const float* __restrict__ W, const float* __restrict__ b, int n) {
    __shared__ float Ws[HDIM * HDIM];
    for (int i = threadIdx.x; i < HDIM * HDIM; i += blockDim.x) Ws[i] = W[i];
    __syncthreads();
    int r = blockIdx.x * (blockDim.x >> 5) + (threadIdx.x >> 5);
    if (r >= n) return;
    int f = threadIdx.x & 31;
    float bf = b[f];
    float res = 0.0f;
    int ctot = 0;
#pragma unroll
    for (int l = 0; l < NL; ++l) {
        int ro = (l == 0) ? ro0 : (l == 1) ? ro1 : ro2;
        int eo = (l == 0) ? eo0 : (l == 1) ? eo1 : eo2;
        int jcur = (r == 0) ? eo : R[ro + r - 1];
        int jend = R[ro + r];
        int c = jend - jcur;
        float acc = 0.0f, t = 0.0f;
        for (int j = jcur; j < jend; ++j) {
            int2 e = esw[j];
            float w = __int_as_float(e.y);
            acc += w * ((const float*)(srcB + (size_t)(uint32)e.x))[f];
            t += w;
        }
        ctot += c;
        float rl = t * bf;
#pragma unroll
        for (int k = 0; k < HDIM; ++k) rl += __shfl(acc, k, 32) * Ws[k * HDIM + f];
        rl /= fmaxf((float)c, 1.0f);
        res += fmaxf(rl, 0.0f);
    }
    if (ctot > 0) dst[(size_t)r * HDIM + f] += res;
}

// ---------------------------------------------------------------------------
extern "C" void kernel_launch(void* const* d_in, const int* in_sizes, int n_in,
                              void* d_out, int out_size, void* d_ws, size_t ws_size,
                              hipStream_t stream) {
    const float* x_user = (const float*)d_in[0];
    const float* x_poi  = (const float*)d_in[1];
    const float* x_cate = (const float*)d_in[2];
    const float* ulw    = (const float*)d_in[3];
    const float* ulb    = (const float*)d_in[4];
    const float* plw    = (const float*)d_in[5];
    const float* plb    = (const float*)d_in[6];
    const float* clw    = (const float*)d_in[7];
    const float* clb    = (const float*)d_in[8];
    const float* W1u_w  = (const float*)d_in[9];   const float* W1u_b  = (const float*)d_in[10];
    const float* W1p_w  = (const float*)d_in[11];  const float* W1p_b  = (const float*)d_in[12];
    const float* W1c_w  = (const float*)d_in[13];  const float* W1c_b  = (const float*)d_in[14];
    const float* W1pp_w = (const float*)d_in[15];  const float* W1pp_b = (const float*)d_in[16];
    const float* W2u_w  = (const float*)d_in[17];  const float* W2u_b  = (const float*)d_in[18];
    const float* W2p_w  = (const float*)d_in[19];  const float* W2p_b  = (const float*)d_in[20];
    const float* W2c_w  = (const float*)d_in[21];  const float* W2c_b  = (const float*)d_in[22];
    const float* W2pp_w = (const float*)d_in[23];  const float* W2pp_b = (const float*)d_in[24];
    const float* cate_emb = (const float*)d_in[25];
    const int* ei_pv        = (const int*)d_in[26];
    const int* ei_mc        = (const int*)d_in[27];
    const int* ei_order     = (const int*)d_in[28];
    const int* ei_rev_pv    = (const int*)d_in[29];
    const int* ei_rev_mc    = (const int*)d_in[30];
    const int* ei_rev_order = (const int*)d_in[31];
    const int* ei_belongs   = (const int*)d_in[32];
    const int* ei_pp        = (const int*)d_in[33];
    const float* ea_pv        = (const float*)d_in[34];
    const float* ea_mc        = (const float*)d_in[35];
    const float* ea_order     = (const float*)d_in[36];
    const float* ea_rev_pv    = (const float*)d_in[37];
    const float* ea_rev_mc    = (const float*)d_in[38];
    const float* ea_rev_order = (const float*)d_in[39];
    const float* ea_pp        = (const float*)d_in[40];

    float* user_h = (float*)d_out;
    float* poi_h  = user_h + (size_t)NU * HDIM;
    float* cate_h = poi_h + (size_t)NPOI * HDIM;

    const int* eis[NLISTS] = {ei_rev_pv, ei_rev_mc, ei_rev_order,
                              ei_pv, ei_mc, ei_order, ei_belongs, ei_pp};
    const float* eas[NLISTS] = {ea_rev_pv, ea_rev_mc, ea_rev_order,
                                ea_pv, ea_mc, ea_order, nullptr, ea_pp};
    const int Es[NLISTS] = {E_UP, E_UP, E_UP, E_UP, E_UP, E_UP, NPOI, E_PP};

    dim3 blk(256);

    // pret-path workspace need
    size_t szR  = (size_t)(TOT_R4 + 4) * 4;
    size_t szE  = (size_t)TOT_E * 8;
    size_t szBG = 16384;                                    // BB(NB+1)+Gcur(NB)+pad
    size_t szT  = (size_t)NU * 64 + 2 * (size_t)NPOI * 64;  // 57.6 MB (>= staging 50.4)
    size_t szC  = (size_t)NC * HDIM * 4;
    size_t need_new = szR + szE + szBG + szT + szC + 256;
    bool pret = (ws_size >= need_new);

    if (pret) {
        int*  R    = (int*)d_ws;                            // (TOT_R4+4) ints
        int2* esw  = (int2*)(R + TOT_R4 + 4);               // TOT_E
        int*  BB   = (int*)(esw + TOT_E);                   // NB+1
        int*  Gcur = BB + (NB + 1);                         // NB
        char* Tbase = (char*)(((size_t)(Gcur + NB) + 255) & ~(size_t)255);
        unsigned short* userT = (unsigned short*)Tbase;               // 32 MB
        unsigned short* poiTA = userT + (size_t)NU * HDIM;            // 12.8 MB
        unsigned short* poiTB = poiTA + (size_t)NPOI * HDIM;          // 12.8 MB
        int2* S2 = (int2*)Tbase;                                      // alias: 33.6 MB
        int*  D  = (int*)(S2 + TOT_E);                                // alias: 16.8 MB
        float* cateT = (float*)(Tbase + szT);                         // 12.8 KB

        // regions: user-rev [0,4NU) slots{pv,mc,order,pad}; poi-fwd [4NU,+4NPOI)
        // slots{pv,mc,order,belongs}; poi-pp [4NU+4NPOI,+4NPOI) slots{pp,pad...}
        const int BU = 0, BF = 4 * NU, BP = 4 * NU + 4 * NPOI;
        BL P;
        const int Lbase[NLISTS]  = {BU, BU, BU, BF, BF, BF, BF, BP};
        const int Lslot[NLISTS]  = {0, 1, 2, 0, 1, 2, 3, 0};
        const int Lshift[NLISTS] = {6, 6, 6, 6, 6, 6, 7, 6};  // bf16 rows 64B, cateT 128B
        int co = 0;
        for (int l = 0; l < NLISTS; ++l) {
            P.ei[l] = eis[l]; P.ea[l] = eas[l]; P.E[l] = Es[l];
            P.lbase[l] = Lbase[l]; P.lslot[l] = Lslot[l]; P.shift[l] = Lshift[l];
            P.coff[l] = co;
            co += (Es[l] + BCH - 1) / BCH;
        }
        int nwg = co;

        // ---- binned CSR build ----
        hipLaunchKernelGGL(zero_kernel, dim3(8), blk, 0, stream, BB, 2 * NB + 1);
        hipLaunchKernelGGL(bin_count, dim3(nwg), blk, 0, stream, P, BB);
        hipLaunchKernelGGL(scan2, dim3(1), dim3(SCAN_T), 0, stream, BB, NB + 1);
        hipLaunchKernelGGL(copyi, dim3((NB + 255) / 256), blk, 0, stream, BB, Gcur, NB);
        hipLaunchKernelGGL(bin_place, dim3(nwg), blk, 0, stream, P, Gcur, S2, D);
        hipLaunchKernelGGL(csr_place, dim3(NB), blk, 0, stream, BB, S2, D, R, esw);

        // ---- init node states ----
        hipLaunchKernelGGL(init_nodes, dim3((NU * HDIM + 255) / 256), blk, 0, stream,
                           x_user, 2, ulw, ulb, (const float*)nullptr, user_h, NU);
        hipLaunchKernelGGL(init_nodes, dim3((NPOI * HDIM + 255) / 256), blk, 0, stream,
                           x_poi, 3, plw, plb, (const float*)nullptr, poi_h, NPOI);
        hipLaunchKernelGGL(init_nodes, dim3((NC * HDIM + 255) / 256), blk, 0, stream,
                           x_cate, 1, clw, clb, cate_emb, cate_h, NC);

        dim3 g_u((NU + 31) / 32), g_p((NPOI + 31) / 32);
        dim3 gtp((NPOI * HDIM + 255) / 256), gtc((NC * HDIM + 255) / 256);

        // initial pre-transforms
        hipLaunchKernelGGL(transform_bf16_k, gtp, blk, 0, stream, poi_h, W1p_w, W1p_b, poiTA, NPOI);
        hipLaunchKernelGGL(transform_k, gtc, blk, 0, stream, cate_h, W1c_w, W1c_b, cateT, NC);

        // ======== layer 1 ========
        hipLaunchKernelGGL((prop_k<3, true, false, true, true>), g_u, blk, 0, stream,
                           (float4*)user_h, (const char*)poiTA, (const char*)nullptr,
                           (const int4*)(R + BU), esw,
                           (const float4*)W1u_w, (const float4*)W1u_b, (void*)userT, NU);
        hipLaunchKernelGGL((prop_k<3, true, true, true, true>), g_p, blk, 0, stream,
                           (float4*)poi_h, (const char*)userT, (const char*)cateT,
                           (const int4*)(R + BF), esw,
                           (const float4*)W1pp_w, (const float4*)W1pp_b, (void*)poiTB, NPOI);
        hipLaunchKernelGGL((prop_k<1, true, false, true, true>), g_p, blk, 0, stream,
                           (float4*)poi_h, (const char*)poiTB, (const char*)nullptr,
                           (const int4*)(R + BP), esw,
                           (const float4*)W2p_w, (const float4*)W2p_b, (void*)poiTA, NPOI);

        // ======== layer 2 ========
        hipLaunchKernelGGL(transform_k, gtc, blk, 0, stream, cate_h, W2c_w, W2c_b, cateT, NC);
        hipLaunchKernelGGL((prop_k<3, true, false, true, true>), g_u, blk, 0, stream,
                           (float4*)user_h, (const char*)poiTA, (const char*)nullptr,
                           (const int4*)(R + BU), esw,
                           (const float4*)W2u_w, (const float4*)W2u_b, (void*)userT, NU);
        hipLaunchKernelGGL((prop_k<3, true, true, true, true>), g_p, blk, 0, stream,
                           (float4*)poi_h, (const char*)userT, (const char*)cateT,
                           (const int4*)(R + BF), esw,
                           (const float4*)W2pp_w, (const float4*)W2pp_b, (void*)poiTB, NPOI);
        hipLaunchKernelGGL((prop_k<1, true, false, false, false>), g_p, blk, 0, stream,
                           (float4*)poi_h, (const char*)poiTB, (const char*)nullptr,
                           (const int4*)(R + BP), esw,
                           (const float4*)nullptr, (const float4*)nullptr, (void*)nullptr, NPOI);
    } else {
        // ---- fallback: scalar CSR layout, 32-lane props, in-kernel matvec ----
        int*   R    = (int*)d_ws;
        int2*  esw  = (int2*)(R + TOT_R1);
        int*   part = (int*)(esw + TOT_E);
        float* snap = (float*)(part + 4096);

        const int ns[NLISTS] = {NU, NU, NU, NPOI, NPOI, NPOI, NPOI, NPOI};
        int eoff[NLISTS], roff[NLISTS];
        { int eo = 0, ro = 0;
          for (int l = 0; l < NLISTS; ++l) { eoff[l] = eo; roff[l] = ro; eo += Es[l]; ro += ns[l]; } }

        hipLaunchKernelGGL(zero_kernel, dim3(2048), blk, 0, stream, R, TOT_R1);
        for (int l = 0; l < NLISTS; ++l)
            hipLaunchKernelGGL(hist1, dim3((Es[l] + 255) / 256), blk, 0, stream,
                               eis[l] + Es[l], Es[l], R, roff[l], 1, 0);
        int nb = (TOT_R1 + SCAN_CHUNK - 1) / SCAN_CHUNK;
        hipLaunchKernelGGL(scan1, dim3(nb), dim3(SCAN_T), 0, stream, R, TOT_R1, part);
        hipLaunchKernelGGL(scan2, dim3(1), dim3(SCAN_T), 0, stream, part, nb);
        hipLaunchKernelGGL(scan3, dim3(nb), dim3(SCAN_T), 0, stream, R, TOT_R1, part);
        for (int l = 0; l < NLISTS; ++l)
            hipLaunchKernelGGL(fill1, dim3((Es[l] + 255) / 256), blk, 0, stream,
                               eis[l], eas[l], Es[l], R, roff[l], 1, 0, 7, esw);

        hipLaunchKernelGGL(init_nodes, dim3((NU * HDIM + 255) / 256), blk, 0, stream,
                           x_user, 2, ulw, ulb, (const float*)nullptr, user_h, NU);
        hipLaunchKernelGGL(init_nodes, dim3((NPOI * HDIM + 255) / 256), blk, 0, stream,
                           x_poi, 3, plw, plb, (const float*)nullptr, poi_h, NPOI);
        hipLaunchKernelGGL(init_nodes, dim3((NC * HDIM + 255) / 256), blk, 0, stream,
                           x_cate, 1, clw, clb, cate_emb, cate_h, NC);

        dim3 gu((NU + 7) / 8), gp((NPOI + 7) / 8);
        int n4 = NPOI * HDIM / 4;

        for (int layer = 0; layer < 2; ++layer) {
            const float* Wp  = layer ? W2p_w  : W1p_w;   const float* bp  = layer ? W2p_b  : W1p_b;
            const float* Wu  = layer ? W2u_w  : W1u_w;   const float* bu  = layer ? W2u_b  : W1u_b;
            const float* Wc  = layer ? W2c_w  : W1c_w;   const float* bc  = layer ? W2c_b  : W1c_b;
            const float* Wpp = layer ? W2pp_w : W1pp_w;  const float* bpp = layer ? W2pp_b : W1pp_b;

            hipLaunchKernelGGL((row_prop_fb<3>), gu, blk, 0, stream,
                               user_h, (const char*)poi_h, R, esw,
                               roff[0], roff[1], roff[2], eoff[0], eoff[1], eoff[2],
                               Wp, bp, NU);
            hipLaunchKernelGGL((row_prop_fb<3>), gp, blk, 0, stream,
                               poi_h, (const char*)user_h, R, esw,
                               roff[3], roff[4], roff[5], eoff[3], eoff[4], eoff[5],
                               Wu, bu, NPOI);
            hipLaunchKernelGGL((row_prop_fb<1>), gp, blk, 0, stream,
                               poi_h, (const char*)cate_h, R, esw,
                               roff[6], 0, 0, eoff[6], 0, 0, Wc, bc, NPOI);
            hipLaunchKernelGGL(copy4, dim3(4096), blk, 0, stream,
                               (const float4*)poi_h, (float4*)snap, n4);
            hipLaunchKernelGGL((row_prop_fb<1>), gp, blk, 0, stream,
                               poi_h, (const char*)snap, R, esw,
                               roff[7], 0, 0, eoff[7], 0, 0, Wpp, bpp, NPOI);
        }
    }
}

// Round 10
// 509.959 us; speedup vs baseline: 10.0564x; 1.1749x over previous
//
#include <hip/hip_runtime.h>

#define HDIM 32

typedef unsigned int uint32;

static constexpr int NU   = 500000;
static constexpr int NPOI = 200000;
static constexpr int NC   = 100;
static constexpr int E_UP = 500000;
static constexpr int E_PP = 1000000;

static constexpr int NLISTS = 8;
static constexpr int TOT_E  = 6 * E_UP + NPOI + E_PP;     // 4,200,000
static constexpr int TOT_R4 = 4 * NU + 8 * NPOI;          // 3,600,000 slots (4/row)
static constexpr int TOT_R1 = 3 * NU + 5 * NPOI;          // fallback scalar layout

static constexpr int BSH  = 12;                            // bucket = 4096 slots
static constexpr int BSZ  = 1 << BSH;
static constexpr int NB   = (TOT_R4 + BSZ - 1) / BSZ;      // 879 buckets
static constexpr int CNTN = 512;                           // max buckets per region
static constexpr int BCH  = 2048;                          // edges per bin chunk

static constexpr int BU_ = 0;
static constexpr int BF_ = 4 * NU;                         // 2,000,000
static constexpr int BP_ = 4 * NU + 4 * NPOI;              // 2,800,000

// ---------------------------------------------------------------------------
__global__ void zero_kernel(int* __restrict__ p, int n) {
    int i = blockIdx.x * blockDim.x + threadIdx.x;
    int stride = gridDim.x * blockDim.x;
    for (; i < n; i += stride) p[i] = 0;
}

__global__ void copyi(const int* __restrict__ a, int* __restrict__ b, int n) {
    int i = blockIdx.x * blockDim.x + threadIdx.x;
    if (i < n) b[i] = a[i];
}

// ---------------------------------------------------------------------------
__global__ void init_nodes(const float* __restrict__ x, int fin,
                           const float* __restrict__ W, const float* __restrict__ b,
                           const float* __restrict__ emb,
                           float* __restrict__ h, int n) {
    int idx = blockIdx.x * blockDim.x + threadIdx.x;
    if (idx >= n * HDIM) return;
    int i = idx >> 5, f = idx & 31;
    float r = b[f];
    for (int k = 0; k < fin; ++k) r += x[i * fin + k] * W[k * HDIM + f];
    r = fmaxf(r, 0.0f);
    if (emb) r += emb[idx];
    h[idx] = r;
}

// ---------------------------------------------------------------------------
// ===== binned CSR build (pret path) =====
struct BL {
    const int* ei[NLISTS];
    const float* ea[NLISTS];
    int E[NLISTS];
    int lbase[NLISTS];
    int lslot[NLISTS];
    int coff[NLISTS];
};

// coarse per-bucket counts (LDS-aggregated, then one atomic per bucket)
__global__ __launch_bounds__(256) void bin_count(BL P, int* __restrict__ BB) {
    __shared__ int cnt[CNTN];
    int w = blockIdx.x;
    int l = 0;
    while (l < NLISTS - 1 && w >= P.coff[l + 1]) ++l;
    int e0 = (w - P.coff[l]) * BCH;
    int E = P.E[l];
    const int* dstp = P.ei[l] + E;
    int lbase = P.lbase[l], lslot = P.lslot[l];
    int cbase = lbase >> BSH;
    for (int i = threadIdx.x; i < CNTN; i += 256) cnt[i] = 0;
    __syncthreads();
    int e1 = min(e0 + BCH, E);
    for (int e = e0 + threadIdx.x; e < e1; e += 256) {
        int slot = lbase + dstp[e] * 4 + lslot;
        atomicAdd(&cnt[(slot >> BSH) - cbase], 1);
    }
    __syncthreads();
    for (int i = threadIdx.x; i < CNTN; i += 256) {
        int c = cnt[i];
        if (c > 0) atomicAdd(&BB[cbase + i], c);
    }
}

// single-pass placement with PACKED records: S2 = {src<<12 | slot_in_bucket,
// weight}. Bucket id is implied by staging position. The counting atomic's
// return value is the within-(wg,bucket) rank -> single LDS-atomic pass.
__global__ __launch_bounds__(256) void bin_place(BL P, int* __restrict__ Gcur,
                                                 int2* __restrict__ S2) {
    __shared__ int cnt[CNTN];
    __shared__ int cur[CNTN];
    int w = blockIdx.x;
    int l = 0;
    while (l < NLISTS - 1 && w >= P.coff[l + 1]) ++l;
    int e0 = (w - P.coff[l]) * BCH;
    int E = P.E[l];
    const int* srcp = P.ei[l];
    const int* dstp = P.ei[l] + E;
    const float* eap = P.ea[l];
    int lbase = P.lbase[l], lslot = P.lslot[l];
    int cbase = lbase >> BSH;
    for (int i = threadIdx.x; i < CNTN; i += 256) cnt[i] = 0;
    __syncthreads();
    int e1 = min(e0 + BCH, E);

    int pk_[8], my_[8], wb_[8], li_[8];
    bool ok_[8];
#pragma unroll
    for (int k = 0; k < 8; ++k) {
        int e = e0 + k * 256 + threadIdx.x;
        ok_[k] = (e < e1);
        if (ok_[k]) {
            int slot = lbase + dstp[e] * 4 + lslot;
            li_[k] = (slot >> BSH) - cbase;
            pk_[k] = (srcp[e] << BSH) | (slot & (BSZ - 1));
            wb_[k] = eap ? __float_as_int(eap[e]) : __float_as_int(1.0f);
            my_[k] = atomicAdd(&cnt[li_[k]], 1);
        }
    }
    __syncthreads();
    for (int i = threadIdx.x; i < CNTN; i += 256) {
        int c = cnt[i];
        cur[i] = (c > 0) ? atomicAdd(&Gcur[cbase + i], c) : 0;
    }
    __syncthreads();
#pragma unroll
    for (int k = 0; k < 8; ++k) {
        if (ok_[k]) {
            int g = cur[li_[k]] + my_[k];
            S2[g] = make_int2(pk_[k], wb_[k]);
        }
    }
}

// fine pass: one wg per bucket. LDS slot-hist + scan -> coalesced R write
// (START semantics), then place records into the bucket's esw window.
// Per-slot byte-shift: belongs slots (fwd region, slot%4==3) are f32 rows
// (shift 7); all other tables are bf16 rows (shift 6).
__global__ __launch_bounds__(256) void csr_place(const int* __restrict__ BB,
                                                 const int2* __restrict__ S2,
                                                 int* __restrict__ R,
                                                 int2* __restrict__ esw) {
    __shared__ int cnt[BSZ];
    __shared__ int wpart[256];
    int b = blockIdx.x;
    int s0 = b << BSH;
    int ns = min(BSZ, TOT_R4 - s0);
    int j0 = BB[b], j1 = BB[b + 1];
    for (int i = threadIdx.x; i < BSZ; i += 256) cnt[i] = 0;
    __syncthreads();
    for (int j = j0 + threadIdx.x; j < j1; j += 256)
        atomicAdd(&cnt[S2[j].x & (BSZ - 1)], 1);
    __syncthreads();
    int v[16]; int s = 0;
    int base = threadIdx.x * 16;
#pragma unroll
    for (int k = 0; k < 16; ++k) { v[k] = cnt[base + k]; s += v[k]; }
    wpart[threadIdx.x] = s;
    __syncthreads();
    for (int off = 1; off < 256; off <<= 1) {
        int t = (threadIdx.x >= off) ? wpart[threadIdx.x - off] : 0;
        __syncthreads(); wpart[threadIdx.x] += t; __syncthreads();
    }
    int run = wpart[threadIdx.x] - s;
#pragma unroll
    for (int k = 0; k < 16; ++k) { cnt[base + k] = run; run += v[k]; }
    __syncthreads();
    for (int i = threadIdx.x; i < ns; i += 256) R[s0 + i] = j0 + cnt[i];
    __syncthreads();
    for (int j = j0 + threadIdx.x; j < j1; j += 256) {
        int2 rec = S2[j];
        int ls = rec.x & (BSZ - 1);
        uint32 src = (uint32)rec.x >> BSH;
        int slot = s0 + ls;
        int shift = (slot >= BF_ && slot < BP_ && (slot & 3) == 3) ? 7 : 6;
        int p = j0 + atomicAdd(&cnt[ls], 1);
        esw[p] = make_int2((int)(src << shift), rec.y);
    }
}

// ---------------------------------------------------------------------------
// ===== fallback CSR build (scalar layout) =====
__global__ void hist1(const int* __restrict__ ei_dst, int E, int* __restrict__ R,
                      int base, int stride, int slot) {
    int e = blockIdx.x * blockDim.x + threadIdx.x;
    if (e < E) atomicAdd(&R[base + ei_dst[e] * stride + slot], 1);
}

#define SCAN_T 256
#define SCAN_ELEMS 4
#define SCAN_CHUNK (SCAN_T * SCAN_ELEMS)

__global__ void scan1(int* __restrict__ R, int N, int* __restrict__ part) {
    __shared__ int lds[SCAN_T];
    int base = blockIdx.x * SCAN_CHUNK + threadIdx.x * SCAN_ELEMS;
    int v[SCAN_ELEMS]; int s = 0;
#pragma unroll
    for (int k = 0; k < SCAN_ELEMS; ++k) { int i = base + k; v[k] = (i < N) ? R[i] : 0; s += v[k]; }
    lds[threadIdx.x] = s; __syncthreads();
    for (int off = 1; off < SCAN_T; off <<= 1) {
        int t = (threadIdx.x >= off) ? lds[threadIdx.x - off] : 0;
        __syncthreads(); lds[threadIdx.x] += t; __syncthreads();
    }
    int incl = lds[threadIdx.x];
    int total = lds[SCAN_T - 1];
    int run = incl - s;
#pragma unroll
    for (int k = 0; k < SCAN_ELEMS; ++k) { int i = base + k; if (i < N) R[i] = run; run += v[k]; }
    if (threadIdx.x == 0) part[blockIdx.x] = total;
}

__global__ void scan2(int* __restrict__ part, int nb) {
    __shared__ int lds[SCAN_T];
    __shared__ int carry;
    if (threadIdx.x == 0) carry = 0;
    __syncthreads();
    for (int base = 0; base < nb; base += SCAN_T) {
        int i = base + threadIdx.x;
        int v = (i < nb) ? part[i] : 0;
        lds[threadIdx.x] = v; __syncthreads();
        for (int off = 1; off < SCAN_T; off <<= 1) {
            int t = (threadIdx.x >= off) ? lds[threadIdx.x - off] : 0;
            __syncthreads(); lds[threadIdx.x] += t; __syncthreads();
        }
        int incl = lds[threadIdx.x]; int tot = lds[SCAN_T - 1];
        if (i < nb) part[i] = carry + incl - v;
        __syncthreads();
        if (threadIdx.x == 0) carry += tot;
        __syncthreads();
    }
}

__global__ void scan3(int* __restrict__ R, int N, const int* __restrict__ part) {
    int base = blockIdx.x * SCAN_CHUNK + threadIdx.x * SCAN_ELEMS;
    int add = part[blockIdx.x];
#pragma unroll
    for (int k = 0; k < SCAN_ELEMS; ++k) { int i = base + k; if (i < N) R[i] += add; }
}

__global__ void fill1(const int* __restrict__ ei, const float* __restrict__ ea,
                      int E, int* __restrict__ R, int base, int stride, int slot,
                      int shift, int2* __restrict__ esw) {
    int e = blockIdx.x * blockDim.x + threadIdx.x;
    if (e >= E) return;
    int d = ei[E + e];
    int pos = atomicAdd(&R[base + d * stride + slot], 1);
    float w = ea ? ea[e] : 1.0f;
    esw[pos] = make_int2(ei[e] << shift, __float_as_int(w));
}

// ---------------------------------------------------------------------------
__device__ inline unsigned short bf16rn(float f) {
    uint32 u = __float_as_uint(f);
    return (unsigned short)((u + 0x7fffu + ((u >> 16) & 1u)) >> 16);
}

__global__ __launch_bounds__(256) void transform_k(const float* __restrict__ src,
                                                   const float* __restrict__ W,
                                                   const float* __restrict__ b,
                                                   float* __restrict__ out, int n) {
    int idx = blockIdx.x * blockDim.x + threadIdx.x;
    if (idx >= n * HDIM) return;
    int f = idx & 31;
    float Wc[HDIM];
#pragma unroll
    for (int k = 0; k < HDIM; ++k) Wc[k] = W[k * HDIM + f];
    float x = src[idx];
    float r = b[f];
#pragma unroll
    for (int k = 0; k < HDIM; ++k) r += __shfl(x, k, 32) * Wc[k];
    out[idx] = r;
}

// fused init+transform: out = bf16( relu(x@Wi+bi) @ W + b )
__global__ __launch_bounds__(256) void transform_init_bf16(
    const float* __restrict__ x, int fin,
    const float* __restrict__ Wi, const float* __restrict__ bi,
    const float* __restrict__ W, const float* __restrict__ b,
    unsigned short* __restrict__ out, int n) {
    int idx = blockIdx.x * blockDim.x + threadIdx.x;
    if (idx >= n * HDIM) return;
    int i = idx >> 5, f = idx & 31;
    float h = bi[f];
    for (int k = 0; k < fin; ++k) h += x[i * fin + k] * Wi[k * HDIM + f];
    h = fmaxf(h, 0.0f);
    float Wc[HDIM];
#pragma unroll
    for (int k = 0; k < HDIM; ++k) Wc[k] = W[k * HDIM + f];
    float r = b[f];
#pragma unroll
    for (int k = 0; k < HDIM; ++k) r += __shfl(h, k, 32) * Wc[k];
    out[idx] = bf16rn(r);
}

// ---------------------------------------------------------------------------
__global__ void copy4(const float4* __restrict__ src, float4* __restrict__ dst, int n4) {
    int i = blockIdx.x * blockDim.x + threadIdx.x;
    int stride = gridDim.x * blockDim.x;
    for (; i < n4; i += stride) dst[i] = src[i];
}

// ---------------------------------------------------------------------------
__device__ inline float4 ldrow_f32(const char* base, uint32 off, int lane8) {
    return ((const float4*)(base + off))[lane8];
}
__device__ inline float4 ldrow_bf16(const char* base, uint32 off, int lane8) {
    uint2 q = ((const uint2*)(base + off))[lane8];
    float4 v;
    v.x = __uint_as_float(q.x << 16);
    v.y = __uint_as_float(q.x & 0xffff0000u);
    v.z = __uint_as_float(q.y << 16);
    v.w = __uint_as_float(q.y & 0xffff0000u);
    return v;
}

// ---------------------------------------------------------------------------
// Merged-segment prop, START-semantics CSR. FIN>0: dst row init computed
// inline from xin@Wi+bi (relu) instead of reading dst (layer-1 only) — the
// row is ALWAYS written. EPI: fused epilogue transform into dstT.
template<int NSEG, bool SRCBF16, bool HASB, bool EPI, bool EPIBF16, int FIN>
__global__ __launch_bounds__(256) void prop_k(
    float4* __restrict__ dst4,
    const char* __restrict__ srcB,
    const char* __restrict__ srcB2,
    const int4* __restrict__ R4,
    const int2* __restrict__ esw,
    const float4* __restrict__ WT4, const float4* __restrict__ bT4,
    void* __restrict__ dstT,
    const float* __restrict__ xin, const float* __restrict__ Wi,
    const float* __restrict__ bi, int n)
{
    __shared__ float4 Ws4[HDIM][8];
    __shared__ float4 bTs[8];
    __shared__ float Wis[3 * HDIM];
    __shared__ float bis[HDIM];
    if (EPI) {
        int t = threadIdx.x;
        { int k = t >> 3, j = t & 7; Ws4[k][j] = WT4[k * 8 + j]; }
        if (t < 8) bTs[t] = bT4[t];
    }
    if (FIN > 0) {
        if (threadIdx.x < FIN * HDIM) Wis[threadIdx.x] = Wi[threadIdx.x];
        if (threadIdx.x < HDIM) bis[threadIdx.x] = bi[threadIdx.x];
    }
    if (EPI || FIN > 0) __syncthreads();

    int grp = threadIdx.x >> 3, lane8 = threadIdx.x & 7;
    int r = blockIdx.x * 32 + grp;
    if (r >= n) return;

    int4 ev = R4[r];
    int s0 = ev.x;
    int zend = (NSEG == 3) ? ev.w : ev.y;

    float4 acc = make_float4(0.f, 0.f, 0.f, 0.f);
    float4 res = make_float4(0.f, 0.f, 0.f, 0.f);
    int segs = s0;

    if (s0 < zend) {
        int last = zend - 1;
        int2 eA = esw[s0];
        int2 eB = esw[min(s0 + 1, last)];
        float4 vA = SRCBF16 ? ldrow_bf16(srcB, (uint32)eA.x, lane8)
                            : ldrow_f32 (srcB, (uint32)eA.x, lane8);
        for (int j = s0; j < zend; ++j) {
            float4 vB = SRCBF16 ? ldrow_bf16(srcB, (uint32)eB.x, lane8)
                                : ldrow_f32 (srcB, (uint32)eB.x, lane8);
            int2 eC = esw[min(j + 2, last)];
            float w = __int_as_float(eA.y);
            acc.x += w * vA.x; acc.y += w * vA.y;
            acc.z += w * vA.z; acc.w += w * vA.w;
            int j1 = j + 1;
            bool fin = (j1 == ev.y) || (NSEG == 3 && ((j1 == ev.z) | (j1 == ev.w)));
            if (fin) {
                float inv = __builtin_amdgcn_rcpf((float)(j1 - segs));
                res.x += fmaxf(acc.x * inv, 0.f);
                res.y += fmaxf(acc.y * inv, 0.f);
                res.z += fmaxf(acc.z * inv, 0.f);
                res.w += fmaxf(acc.w * inv, 0.f);
                acc = make_float4(0.f, 0.f, 0.f, 0.f);
                segs = j1;
            }
            eA = eB; eB = eC; vA = vB;
        }
    }
    int ctot = zend - s0;
    if (HASB) {
        int nx = R4[r + 1].x;
        int c2 = nx - ev.w;
        float4 a2 = make_float4(0.f, 0.f, 0.f, 0.f);
        for (int j = ev.w; j < nx; ++j) {
            int2 e = esw[j];
            float w = __int_as_float(e.y);
            float4 v = ldrow_f32(srcB2, (uint32)e.x, lane8);
            a2.x += w * v.x; a2.y += w * v.y; a2.z += w * v.z; a2.w += w * v.w;
        }
        if (c2 > 0) {
            float inv = __builtin_amdgcn_rcpf((float)c2);
            res.x += fmaxf(a2.x * inv, 0.f);
            res.y += fmaxf(a2.y * inv, 0.f);
            res.z += fmaxf(a2.z * inv, 0.f);
            res.w += fmaxf(a2.w * inv, 0.f);
        }
        ctot += c2;
    }

    float4* dp = dst4 + (size_t)r * 8 + lane8;
    float4 dv;
    if (FIN > 0) {
        float xr[FIN > 0 ? FIN : 1];
#pragma unroll
        for (int k = 0; k < FIN; ++k) xr[k] = xin[(size_t)r * FIN + k];
        int f0 = lane8 * 4;
        dv.x = bis[f0]; dv.y = bis[f0 + 1]; dv.z = bis[f0 + 2]; dv.w = bis[f0 + 3];
#pragma unroll
        for (int k = 0; k < FIN; ++k) {
            dv.x += xr[k] * Wis[k * HDIM + f0];
            dv.y += xr[k] * Wis[k * HDIM + f0 + 1];
            dv.z += xr[k] * Wis[k * HDIM + f0 + 2];
            dv.w += xr[k] * Wis[k * HDIM + f0 + 3];
        }
        dv.x = fmaxf(dv.x, 0.f); dv.y = fmaxf(dv.y, 0.f);
        dv.z = fmaxf(dv.z, 0.f); dv.w = fmaxf(dv.w, 0.f);
    } else {
        dv = *dp;
    }
    if (ctot) {
        dv.x += res.x; dv.y += res.y; dv.z += res.z; dv.w += res.w;
    }
    if (FIN > 0 || ctot) *dp = dv;

    if (EPI) {
        float4 to = bTs[lane8];
#pragma unroll
        for (int sl = 0; sl < 8; ++sl) {
            float ux = __shfl(dv.x, sl, 8);
            float uy = __shfl(dv.y, sl, 8);
            float uz = __shfl(dv.z, sl, 8);
            float uw = __shfl(dv.w, sl, 8);
            float4 w0 = Ws4[sl * 4 + 0][lane8];
            to.x += ux * w0.x; to.y += ux * w0.y; to.z += ux * w0.z; to.w += ux * w0.w;
            float4 w1 = Ws4[sl * 4 + 1][lane8];
            to.x += uy * w1.x; to.y += uy * w1.y; to.z += uy * w1.z; to.w += uy * w1.w;
            float4 w2 = Ws4[sl * 4 + 2][lane8];
            to.x += uz * w2.x; to.y += uz * w2.y; to.z += uz * w2.z; to.w += uz * w2.w;
            float4 w3 = Ws4[sl * 4 + 3][lane8];
            to.x += uw * w3.x; to.y += uw * w3.y; to.z += uw * w3.z; to.w += uw * w3.w;
        }
        if (EPIBF16) {
            ushort4 h;
            h.x = bf16rn(to.x); h.y = bf16rn(to.y);
            h.z = bf16rn(to.z); h.w = bf16rn(to.w);
            ((ushort4*)dstT)[(size_t)r * 8 + lane8] = h;
        } else {
            ((float4*)dstT)[(size_t)r * 8 + lane8] = to;
        }
    }
}

// ---------------------------------------------------------------------------
// Fallback prop (small workspace): 32 lanes/row, in-kernel matvec, scalar CSR
// with END semantics.
template<int NL>
__global__ __launch_bounds__(256) void row_prop_fb(
    float* __restrict__ dst, const char* __restrict__ srcB,
    const int* __restrict__ R, const int2* __restrict__ esw,
    int ro0, int ro1, int ro2, int eo0, int eo1, int eo2,
    const float* __restrict__ W, const float* __restrict__ b, int n) {
    __shared__ float Ws[HDIM * HDIM];
    for (int i = threadIdx.x; i < HDIM * HDIM; i += blockDim.x) Ws[i] = W[i];
    __syncthreads();
    int r = blockIdx.x * (blockDim.x >> 5) + (threadIdx.x >> 5);
    if (r >= n) return;
    int f = threadIdx.x & 31;
    float bf = b[f];
    float res = 0.0f;
    int ctot = 0;
#pragma unroll
    for (int l = 0; l < NL; ++l) {
        int ro = (l == 0) ? ro0 : (l == 1) ? ro1 : ro2;
        int eo = (l == 0) ? eo0 : (l == 1) ? eo1 : eo2;
        int jcur = (r == 0) ? eo : R[ro + r - 1];
        int jend = R[ro + r];
        int c = jend - jcur;
        float acc = 0.0f, t = 0.0f;
        for (int j = jcur; j < jend; ++j) {
            int2 e = esw[j];
            float w = __int_as_float(e.y);
            acc += w * ((const float*)(srcB + (size_t)(uint32)e.x))[f];
            t += w;
        }
        ctot += c;
        float rl = t * bf;
#pragma unroll
        for (int k = 0; k < HDIM; ++k) rl += __shfl(acc, k, 32) * Ws[k * HDIM + f];
        rl /= fmaxf((float)c, 1.0f);
        res += fmaxf(rl, 0.0f);
    }
    if (ctot > 0) dst[(size_t)r * HDIM + f] += res;
}

// ---------------------------------------------------------------------------
extern "C" void kernel_launch(void* const* d_in, const int* in_sizes, int n_in,
                              void* d_out, int out_size, void* d_ws, size_t ws_size,
                              hipStream_t stream) {
    const float* x_user = (const float*)d_in[0];
    const float* x_poi  = (const float*)d_in[1];
    const float* x_cate = (const float*)d_in[2];
    const float* ulw    = (const float*)d_in[3];
    const float* ulb    = (const float*)d_in[4];
    const float* plw    = (const float*)d_in[5];
    const float* plb    = (const float*)d_in[6];
    const float* clw    = (const float*)d_in[7];
    const float* clb    = (const float*)d_in[8];
    const float* W1u_w  = (const float*)d_in[9];   const float* W1u_b  = (const float*)d_in[10];
    const float* W1p_w  = (const float*)d_in[11];  const float* W1p_b  = (const float*)d_in[12];
    const float* W1c_w  = (const float*)d_in[13];  const float* W1c_b  = (const float*)d_in[14];
    const float* W1pp_w = (const float*)d_in[15];  const float* W1pp_b = (const float*)d_in[16];
    const float* W2u_w  = (const float*)d_in[17];  const float* W2u_b  = (const float*)d_in[18];
    const float* W2p_w  = (const float*)d_in[19];  const float* W2p_b  = (const float*)d_in[20];
    const float* W2c_w  = (const float*)d_in[21];  const float* W2c_b  = (const float*)d_in[22];
    const float* W2pp_w = (const float*)d_in[23];  const float* W2pp_b = (const float*)d_in[24];
    const float* cate_emb = (const float*)d_in[25];
    const int* ei_pv        = (const int*)d_in[26];
    const int* ei_mc        = (const int*)d_in[27];
    const int* ei_order     = (const int*)d_in[28];
    const int* ei_rev_pv    = (const int*)d_in[29];
    const int* ei_rev_mc    = (const int*)d_in[30];
    const int* ei_rev_order = (const int*)d_in[31];
    const int* ei_belongs   = (const int*)d_in[32];
    const int* ei_pp        = (const int*)d_in[33];
    const float* ea_pv        = (const float*)d_in[34];
    const float* ea_mc        = (const float*)d_in[35];
    const float* ea_order     = (const float*)d_in[36];
    const float* ea_rev_pv    = (const float*)d_in[37];
    const float* ea_rev_mc    = (const float*)d_in[38];
    const float* ea_rev_order = (const float*)d_in[39];
    const float* ea_pp        = (const float*)d_in[40];

    float* user_h = (float*)d_out;
    float* poi_h  = user_h + (size_t)NU * HDIM;
    float* cate_h = poi_h + (size_t)NPOI * HDIM;

    const int* eis[NLISTS] = {ei_rev_pv, ei_rev_mc, ei_rev_order,
                              ei_pv, ei_mc, ei_order, ei_belongs, ei_pp};
    const float* eas[NLISTS] = {ea_rev_pv, ea_rev_mc, ea_rev_order,
                                ea_pv, ea_mc, ea_order, nullptr, ea_pp};
    const int Es[NLISTS] = {E_UP, E_UP, E_UP, E_UP, E_UP, E_UP, NPOI, E_PP};

    dim3 blk(256);

    // pret-path workspace need (same conservative formula as r8; actual is less)
    size_t szR  = (size_t)(TOT_R4 + 4) * 4;
    size_t szE  = (size_t)TOT_E * 8;
    size_t szBG = 16384;
    size_t szT  = (size_t)NU * 64 + 2 * (size_t)NPOI * 64;
    size_t szC  = (size_t)NC * HDIM * 4;
    size_t need_new = szR + szE + szBG + szT + szC + 256;
    bool pret = (ws_size >= need_new);

    if (pret) {
        int*  R    = (int*)d_ws;                            // (TOT_R4+4) ints
        int2* esw  = (int2*)(R + TOT_R4 + 4);               // TOT_E
        int*  BB   = (int*)(esw + TOT_E);                   // NB+1
        int*  Gcur = BB + (NB + 1);                         // NB
        char* Tbase = (char*)(((size_t)(Gcur + NB) + 255) & ~(size_t)255);
        unsigned short* userT = (unsigned short*)Tbase;               // 32 MB
        unsigned short* poiTA = userT + (size_t)NU * HDIM;            // 12.8 MB
        unsigned short* poiTB = poiTA + (size_t)NPOI * HDIM;          // 12.8 MB
        int2* S2 = (int2*)Tbase;                                      // alias: 33.6 MB
        float* cateT = (float*)(Tbase + szT);                         // 12.8 KB

        const int BU = BU_, BF = BF_, BP = BP_;
        BL P;
        const int Lbase[NLISTS]  = {BU, BU, BU, BF, BF, BF, BF, BP};
        const int Lslot[NLISTS]  = {0, 1, 2, 0, 1, 2, 3, 0};
        int co = 0;
        for (int l = 0; l < NLISTS; ++l) {
            P.ei[l] = eis[l]; P.ea[l] = eas[l]; P.E[l] = Es[l];
            P.lbase[l] = Lbase[l]; P.lslot[l] = Lslot[l];
            P.coff[l] = co;
            co += (Es[l] + BCH - 1) / BCH;
        }
        int nwg = co;

        // ---- binned CSR build ----
        hipLaunchKernelGGL(zero_kernel, dim3(8), blk, 0, stream, BB, 2 * NB + 1);
        hipLaunchKernelGGL(bin_count, dim3(nwg), blk, 0, stream, P, BB);
        hipLaunchKernelGGL(scan2, dim3(1), dim3(SCAN_T), 0, stream, BB, NB + 1);
        hipLaunchKernelGGL(copyi, dim3((NB + 255) / 256), blk, 0, stream, BB, Gcur, NB);
        hipLaunchKernelGGL(bin_place, dim3(nwg), blk, 0, stream, P, Gcur, S2);
        hipLaunchKernelGGL(csr_place, dim3(NB), blk, 0, stream, BB, S2, R, esw);

        // ---- cate init (tiny) ----
        hipLaunchKernelGGL(init_nodes, dim3((NC * HDIM + 255) / 256), blk, 0, stream,
                           x_cate, 1, clw, clb, cate_emb, cate_h, NC);

        dim3 g_u((NU + 31) / 32), g_p((NPOI + 31) / 32);
        dim3 gtp((NPOI * HDIM + 255) / 256), gtc((NC * HDIM + 255) / 256);

        // initial pre-transforms: poiTA = bf16(relu(x_poi@plw+plb)@W1p+b1p)
        hipLaunchKernelGGL(transform_init_bf16, gtp, blk, 0, stream,
                           x_poi, 3, plw, plb, W1p_w, W1p_b, poiTA, NPOI);
        hipLaunchKernelGGL(transform_k, gtc, blk, 0, stream, cate_h, W1c_w, W1c_b, cateT, NC);

        // ======== layer 1 ========
        // rev3 (INIT user inline): user_h = init + res; EPI -> userT(W1u)
        hipLaunchKernelGGL((prop_k<3, true, false, true, true, 2>), g_u, blk, 0, stream,
                           (float4*)user_h, (const char*)poiTA, (const char*)nullptr,
                           (const int4*)(R + BU), esw,
                           (const float4*)W1u_w, (const float4*)W1u_b, (void*)userT,
                           x_user, ulw, ulb, NU);
        // fwd3+belongs (INIT poi inline); EPI -> poiTB(W1pp)
        hipLaunchKernelGGL((prop_k<3, true, true, true, true, 3>), g_p, blk, 0, stream,
                           (float4*)poi_h, (const char*)userT, (const char*)cateT,
                           (const int4*)(R + BF), esw,
                           (const float4*)W1pp_w, (const float4*)W1pp_b, (void*)poiTB,
                           x_poi, plw, plb, NPOI);
        // pp; EPI -> poiTA(W2p) for L2 rev3
        hipLaunchKernelGGL((prop_k<1, true, false, true, true, 0>), g_p, blk, 0, stream,
                           (float4*)poi_h, (const char*)poiTB, (const char*)nullptr,
                           (const int4*)(R + BP), esw,
                           (const float4*)W2p_w, (const float4*)W2p_b, (void*)poiTA,
                           (const float*)nullptr, (const float*)nullptr,
                           (const float*)nullptr, NPOI);

        // ======== layer 2 ========
        hipLaunchKernelGGL(transform_k, gtc, blk, 0, stream, cate_h, W2c_w, W2c_b, cateT, NC);
        hipLaunchKernelGGL((prop_k<3, true, false, true, true, 0>), g_u, blk, 0, stream,
                           (float4*)user_h, (const char*)poiTA, (const char*)nullptr,
                           (const int4*)(R + BU), esw,
                           (const float4*)W2u_w, (const float4*)W2u_b, (void*)userT,
                           (const float*)nullptr, (const float*)nullptr,
                           (const float*)nullptr, NU);
        hipLaunchKernelGGL((prop_k<3, true, true, true, true, 0>), g_p, blk, 0, stream,
                           (float4*)poi_h, (const char*)userT, (const char*)cateT,
                           (const int4*)(R + BF), esw,
                           (const float4*)W2pp_w, (const float4*)W2pp_b, (void*)poiTB,
                           (const float*)nullptr, (const float*)nullptr,
                           (const float*)nullptr, NPOI);
        hipLaunchKernelGGL((prop_k<1, true, false, false, false, 0>), g_p, blk, 0, stream,
                           (float4*)poi_h, (const char*)poiTB, (const char*)nullptr,
                           (const int4*)(R + BP), esw,
                           (const float4*)nullptr, (const float4*)nullptr, (void*)nullptr,
                           (const float*)nullptr, (const float*)nullptr,
                           (const float*)nullptr, NPOI);
    } else {
        // ---- fallback: scalar CSR layout, 32-lane props, in-kernel matvec ----
        int*   R    = (int*)d_ws;
        int2*  esw  = (int2*)(R + TOT_R1);
        int*   part = (int*)(esw + TOT_E);
        float* snap = (float*)(part + 4096);

        const int ns[NLISTS] = {NU, NU, NU, NPOI, NPOI, NPOI, NPOI, NPOI};
        int eoff[NLISTS], roff[NLISTS];
        { int eo = 0, ro = 0;
          for (int l = 0; l < NLISTS; ++l) { eoff[l] = eo; roff[l] = ro; eo += Es[l]; ro += ns[l]; } }

        hipLaunchKernelGGL(zero_kernel, dim3(2048), blk, 0, stream, R, TOT_R1);
        for (int l = 0; l < NLISTS; ++l)
            hipLaunchKernelGGL(hist1, dim3((Es[l] + 255) / 256), blk, 0, stream,
                               eis[l] + Es[l], Es[l], R, roff[l], 1, 0);
        int nb = (TOT_R1 + SCAN_CHUNK - 1) / SCAN_CHUNK;
        hipLaunchKernelGGL(scan1, dim3(nb), dim3(SCAN_T), 0, stream, R, TOT_R1, part);
        hipLaunchKernelGGL(scan2, dim3(1), dim3(SCAN_T), 0, stream, part, nb);
        hipLaunchKernelGGL(scan3, dim3(nb), dim3(SCAN_T), 0, stream, R, TOT_R1, part);
        for (int l = 0; l < NLISTS; ++l)
            hipLaunchKernelGGL(fill1, dim3((Es[l] + 255) / 256), blk, 0, stream,
                               eis[l], eas[l], Es[l], R, roff[l], 1, 0, 7, esw);

        hipLaunchKernelGGL(init_nodes, dim3((NU * HDIM + 255) / 256), blk, 0, stream,
                           x_user, 2, ulw, ulb, (const float*)nullptr, user_h, NU);
        hipLaunchKernelGGL(init_nodes, dim3((NPOI * HDIM + 255) / 256), blk, 0, stream,
                           x_poi, 3, plw, plb, (const float*)nullptr, poi_h, NPOI);
        hipLaunchKernelGGL(init_nodes, dim3((NC * HDIM + 255) / 256), blk, 0, stream,
                           x_cate, 1, clw, clb, cate_emb, cate_h, NC);

        dim3 gu((NU + 7) / 8), gp((NPOI + 7) / 8);
        int n4 = NPOI * HDIM / 4;

        for (int layer = 0; layer < 2; ++layer) {
            const float* Wp  = layer ? W2p_w  : W1p_w;   const float* bp  = layer ? W2p_b  : W1p_b;
            const float* Wu  = layer ? W2u_w  : W1u_w;   const float* bu  = layer ? W2u_b  : W1u_b;
            const float* Wc  = layer ? W2c_w  : W1c_w;   const float* bc  = layer ? W2c_b  : W1c_b;
            const float* Wpp = layer ? W2pp_w : W1pp_w;  const float* bpp = layer ? W2pp_b : W1pp_b;

            hipLaunchKernelGGL((row_prop_fb<3>), gu, blk, 0, stream,
                               user_h, (const char*)poi_h, R, esw,
                               roff[0], roff[1], roff[2], eoff[0], eoff[1], eoff[2],
                               Wp, bp, NU);
            hipLaunchKernelGGL((row_prop_fb<3>), gp, blk, 0, stream,
                               poi_h, (const char*)user_h, R, esw,
                               roff[3], roff[4], roff[5], eoff[3], eoff[4], eoff[5],
                               Wu, bu, NPOI);
            hipLaunchKernelGGL((row_prop_fb<1>), gp, blk, 0, stream,
                               poi_h, (const char*)cate_h, R, esw,
                               roff[6], 0, 0, eoff[6], 0, 0, Wc, bc, NPOI);
            hipLaunchKernelGGL(copy4, dim3(4096), blk, 0, stream,
                               (const float4*)poi_h, (float4*)snap, n4);
            hipLaunchKernelGGL((row_prop_fb<1>), gp, blk, 0, stream,
                               poi_h, (const char*)snap, R, esw,
                               roff[7], 0, 0, eoff[7], 0, 0, Wpp, bpp, NPOI);
        }
    }
}